// Round 1
// baseline (1911.598 us; speedup 1.0000x reference)
//
#include <hip/hip_runtime.h>
#include <hip/hip_bf16.h>
#include <math.h>

#define BB 2
#define LL 4096
#define DD 1024
#define HH 16
#define HDIM 64
#define CC 64
#define NC 64   // LL/CC
#define BH 32   // BB*HH

// ---------------------------------------------------------------------------
// GEMM fp32: C[M,1024] = A[M,1024] @ W[1024,1024].  BM=BN=64, BK=16, 256 thr,
// 4x4 per thread.  Round-0 baseline (will become bf16 MFMA next round).
// ---------------------------------------------------------------------------
__global__ __launch_bounds__(256) void gemm1024_f32(const float* __restrict__ A,
                                                    const float* __restrict__ W,
                                                    float* __restrict__ C) {
    __shared__ float As[16][68];
    __shared__ float Bs[16][68];
    const int tid = threadIdx.x;
    const int tx = tid & 15, ty = tid >> 4;
    const int n0 = blockIdx.x * 64, m0 = blockIdx.y * 64;
    float acc[4][4] = {};
    const int kkl = tid & 15, mm = tid >> 4;   // A-load decomposition
    const int nn = tid & 63, kh = tid >> 6;    // B-load decomposition
    for (int k0 = 0; k0 < 1024; k0 += 16) {
#pragma unroll
        for (int p = 0; p < 4; ++p)
            As[kkl][mm + p * 16] = A[(size_t)(m0 + mm + p * 16) * 1024 + k0 + kkl];
#pragma unroll
        for (int p = 0; p < 4; ++p)
            Bs[kh + p * 4][nn] = W[(size_t)(k0 + kh + p * 4) * 1024 + n0 + nn];
        __syncthreads();
#pragma unroll
        for (int kk = 0; kk < 16; ++kk) {
            float4 av = *(const float4*)&As[kk][ty * 4];
            float4 bv = *(const float4*)&Bs[kk][tx * 4];
            acc[0][0] += av.x * bv.x; acc[0][1] += av.x * bv.y; acc[0][2] += av.x * bv.z; acc[0][3] += av.x * bv.w;
            acc[1][0] += av.y * bv.x; acc[1][1] += av.y * bv.y; acc[1][2] += av.y * bv.z; acc[1][3] += av.y * bv.w;
            acc[2][0] += av.z * bv.x; acc[2][1] += av.z * bv.y; acc[2][2] += av.z * bv.z; acc[2][3] += av.z * bv.w;
            acc[3][0] += av.w * bv.x; acc[3][1] += av.w * bv.y; acc[3][2] += av.w * bv.z; acc[3][3] += av.w * bv.w;
        }
        __syncthreads();
    }
#pragma unroll
    for (int i = 0; i < 4; ++i) {
        float4 r = make_float4(acc[i][0], acc[i][1], acc[i][2], acc[i][3]);
        *(float4*)&C[(size_t)(m0 + ty * 4 + i) * 1024 + n0 + tx * 4] = r;
    }
}

// ---------------------------------------------------------------------------
// beta = sigmoid(x @ Wb) stored [B,H,L]
// ---------------------------------------------------------------------------
__global__ __launch_bounds__(256) void beta_k(const float* __restrict__ X,
                                              const float* __restrict__ Wb,
                                              float* __restrict__ beta) {
    int idx = blockIdx.x * 256 + threadIdx.x;   // 131072 total
    int row = idx >> 4, h = idx & 15;
    const float* xr = X + (size_t)row * DD;
    float s = 0.f;
    for (int k4 = 0; k4 < DD; k4 += 4) {
        float4 xv = *(const float4*)&xr[k4];
        s += xv.x * Wb[(k4 + 0) * HH + h];
        s += xv.y * Wb[(k4 + 1) * HH + h];
        s += xv.z * Wb[(k4 + 2) * HH + h];
        s += xv.w * Wb[(k4 + 3) * HH + h];
    }
    float bv = 1.f / (1.f + expf(-s));
    int b = row >> 12, l = row & (LL - 1);
    beta[((size_t)b * HH + h) * LL + l] = bv;
}

// ---------------------------------------------------------------------------
// causal depthwise conv (K=4) + SiLU (+ optional per-head l2 norm)
// in  : [B,L,D]   out : [B,H,L,HD]
// ---------------------------------------------------------------------------
template <int NORM>
__global__ __launch_bounds__(256) void conv_silu(const float* __restrict__ X,
                                                 const float* __restrict__ cw,
                                                 float* __restrict__ out) {
    const int l = blockIdx.x, b = blockIdx.y;
    const int tid = threadIdx.x;
    const int d0 = tid * 4;
    const float4 w0 = *(const float4*)&cw[(d0 + 0) * 4];
    const float4 w1 = *(const float4*)&cw[(d0 + 1) * 4];
    const float4 w2 = *(const float4*)&cw[(d0 + 2) * 4];
    const float4 w3 = *(const float4*)&cw[(d0 + 3) * 4];
    float a0 = 0, a1 = 0, a2 = 0, a3 = 0;
#pragma unroll
    for (int j = 0; j < 4; ++j) {
        int xr = l - 3 + j;
        if (xr >= 0) {
            float4 xv = *(const float4*)&X[((size_t)b * LL + xr) * DD + d0];
            a0 += xv.x * ((const float*)&w0)[j];
            a1 += xv.y * ((const float*)&w1)[j];
            a2 += xv.z * ((const float*)&w2)[j];
            a3 += xv.w * ((const float*)&w3)[j];
        }
    }
    a0 = a0 / (1.f + expf(-a0));
    a1 = a1 / (1.f + expf(-a1));
    a2 = a2 / (1.f + expf(-a2));
    a3 = a3 / (1.f + expf(-a3));
    if (NORM) {
        float s = a0 * a0 + a1 * a1 + a2 * a2 + a3 * a3;
        s += __shfl_xor(s, 1);
        s += __shfl_xor(s, 2);
        s += __shfl_xor(s, 4);
        s += __shfl_xor(s, 8);
        float sc = rsqrtf(s);
        a0 *= sc; a1 *= sc; a2 *= sc; a3 *= sc;
    }
    const int h = d0 >> 6, hd = d0 & 63;
    float4 r = make_float4(a0, a1, a2, a3);
    *(float4*)&out[(((size_t)b * HH + h) * LL + l) * 64 + hd] = r;
}

// ---------------------------------------------------------------------------
// Phase A (parallel over b,h,chunk): A = strict_tril(diag(beta) K K^T),
// solve (I+A)[W|U] = [beta*K | beta*V] by forward substitution (per-column,
// lane-local, no barriers).  W,U -> global [bh][c][64][64].
// ---------------------------------------------------------------------------
__global__ __launch_bounds__(256) void phaseA(const float* __restrict__ kg,
                                              const float* __restrict__ vg,
                                              const float* __restrict__ betag,
                                              float* __restrict__ Wg,
                                              float* __restrict__ Ug) {
    __shared__ float KtT[64][68];   // [dim][t]
    __shared__ float At[64][68];    // holds V [t][dim] first, then A [t][s]
    __shared__ float WU[64][132];   // cols 0..63 = W, 64..127 = U
    __shared__ float betas[64];
    const int c = blockIdx.x, bh = blockIdx.y;
    const int tid = threadIdx.x;
    const int tx = tid & 15, ty = tid >> 4;
    const size_t base = ((size_t)bh * LL + (size_t)c * 64) * 64;
#pragma unroll
    for (int p = 0; p < 4; ++p) {
        int flat = p * 1024 + tid * 4;
        int r = flat >> 6, col = flat & 63;
        float4 k4 = *(const float4*)&kg[base + flat];
        float4 v4 = *(const float4*)&vg[base + flat];
        KtT[col + 0][r] = k4.x;
        KtT[col + 1][r] = k4.y;
        KtT[col + 2][r] = k4.z;
        KtT[col + 3][r] = k4.w;
        *(float4*)&At[r][col] = v4;
    }
    if (tid < 64) betas[tid] = betag[(size_t)bh * LL + (size_t)c * 64 + tid];
    __syncthreads();
    // rhs: WU[t][j] = beta_t*K[t][j] ; WU[t][64+j] = beta_t*V[t][j]
#pragma unroll
    for (int p = 0; p < 32; ++p) {
        int flat = p * 256 + tid;
        int t = flat >> 7, j = flat & 127;
        WU[t][j] = betas[t] * ((j < 64) ? KtT[j][t] : At[t][j - 64]);
    }
    __syncthreads();   // V reads done; At may now be overwritten with A
    // A[t][s] = beta_t * (k_t . k_s), s<t (outer-product over dim x)
    {
        float acc[4][4] = {};
        for (int x = 0; x < 64; ++x) {
            float4 a = *(const float4*)&KtT[x][ty * 4];
            float4 b = *(const float4*)&KtT[x][tx * 4];
            acc[0][0] += a.x * b.x; acc[0][1] += a.x * b.y; acc[0][2] += a.x * b.z; acc[0][3] += a.x * b.w;
            acc[1][0] += a.y * b.x; acc[1][1] += a.y * b.y; acc[1][2] += a.y * b.z; acc[1][3] += a.y * b.w;
            acc[2][0] += a.z * b.x; acc[2][1] += a.z * b.y; acc[2][2] += a.z * b.z; acc[2][3] += a.z * b.w;
            acc[3][0] += a.w * b.x; acc[3][1] += a.w * b.y; acc[3][2] += a.w * b.z; acc[3][3] += a.w * b.w;
        }
#pragma unroll
        for (int i = 0; i < 4; ++i) {
            int t = ty * 4 + i;
            float bt = betas[t];
            float4 w;
            w.x = (tx * 4 + 0 < t) ? bt * acc[i][0] : 0.f;
            w.y = (tx * 4 + 1 < t) ? bt * acc[i][1] : 0.f;
            w.z = (tx * 4 + 2 < t) ? bt * acc[i][2] : 0.f;
            w.w = (tx * 4 + 3 < t) ? bt * acc[i][3] : 0.f;
            *(float4*)&At[t][tx * 4] = w;
        }
    }
    __syncthreads();
    // forward substitution: each of 128 lanes owns one column (64 W + 64 U)
    if (tid < 128) {
        const int col = tid;
        for (int t = 1; t < 64; ++t) {
            float a = WU[t][col];
            for (int r = 0; r < t; ++r) a -= At[t][r] * WU[r][col];
            WU[t][col] = a;
        }
    }
    __syncthreads();
    const size_t obase = ((size_t)bh * NC + c) * 4096;
#pragma unroll
    for (int p = 0; p < 32; ++p) {
        int flat = p * 256 + tid;
        int t = flat >> 7, j = flat & 127;
        float val = WU[t][j];
        if (j < 64) Wg[obase + (size_t)t * 64 + j] = val;
        else        Ug[obase + (size_t)t * 64 + (j - 64)] = val;
    }
}

// ---------------------------------------------------------------------------
// M = causal(Q K^T) (diag included), per (b,h,chunk) -> global
// ---------------------------------------------------------------------------
__global__ __launch_bounds__(256) void qkT_M(const float* __restrict__ qg,
                                             const float* __restrict__ kg,
                                             float* __restrict__ Mg) {
    __shared__ float QtT[64][68];
    __shared__ float KtT[64][68];
    const int c = blockIdx.x, bh = blockIdx.y;
    const int tid = threadIdx.x;
    const int tx = tid & 15, ty = tid >> 4;
    const size_t base = ((size_t)bh * LL + (size_t)c * 64) * 64;
#pragma unroll
    for (int p = 0; p < 4; ++p) {
        int flat = p * 1024 + tid * 4;
        int r = flat >> 6, col = flat & 63;
        float4 q4 = *(const float4*)&qg[base + flat];
        float4 k4 = *(const float4*)&kg[base + flat];
        QtT[col + 0][r] = q4.x; QtT[col + 1][r] = q4.y; QtT[col + 2][r] = q4.z; QtT[col + 3][r] = q4.w;
        KtT[col + 0][r] = k4.x; KtT[col + 1][r] = k4.y; KtT[col + 2][r] = k4.z; KtT[col + 3][r] = k4.w;
    }
    __syncthreads();
    float acc[4][4] = {};
    for (int x = 0; x < 64; ++x) {
        float4 a = *(const float4*)&QtT[x][ty * 4];
        float4 b = *(const float4*)&KtT[x][tx * 4];
        acc[0][0] += a.x * b.x; acc[0][1] += a.x * b.y; acc[0][2] += a.x * b.z; acc[0][3] += a.x * b.w;
        acc[1][0] += a.y * b.x; acc[1][1] += a.y * b.y; acc[1][2] += a.y * b.z; acc[1][3] += a.y * b.w;
        acc[2][0] += a.z * b.x; acc[2][1] += a.z * b.y; acc[2][2] += a.z * b.z; acc[2][3] += a.z * b.w;
        acc[3][0] += a.w * b.x; acc[3][1] += a.w * b.y; acc[3][2] += a.w * b.z; acc[3][3] += a.w * b.w;
    }
    const size_t obase = ((size_t)bh * NC + c) * 4096;
#pragma unroll
    for (int i = 0; i < 4; ++i) {
        int t = ty * 4 + i;
        float4 w;
        w.x = (tx * 4 + 0 <= t) ? acc[i][0] : 0.f;
        w.y = (tx * 4 + 1 <= t) ? acc[i][1] : 0.f;
        w.z = (tx * 4 + 2 <= t) ? acc[i][2] : 0.f;
        w.w = (tx * 4 + 3 <= t) ? acc[i][3] : 0.f;
        *(float4*)&Mg[obase + (size_t)t * 64 + tx * 4] = w;
    }
}

// ---------------------------------------------------------------------------
// Phase B (sequential over chunks, one block per (b,h)):
//   Delta = U - W*S ; O = Q*S + M*Delta ; S += K^T*Delta
// o written [B,L,H*HD] = [B,L,D]
// ---------------------------------------------------------------------------
__global__ __launch_bounds__(256) void phaseB(const float* __restrict__ Wg,
                                              const float* __restrict__ Ug,
                                              const float* __restrict__ Mg,
                                              const float* __restrict__ qg,
                                              const float* __restrict__ kg,
                                              float* __restrict__ og) {
    __shared__ float S[64][68];
    __shared__ float Wt[64][68];
    __shared__ float Mt[64][68];
    __shared__ float Qt[64][68];
    __shared__ float KtT[64][68];  // [dk][t]
    __shared__ float Dt[64][68];
    const int bh = blockIdx.x;
    const int b = bh >> 4, h = bh & 15;
    const int tid = threadIdx.x;
    const int tx = tid & 15, ty = tid >> 4;
#pragma unroll
    for (int p = 0; p < 16; ++p) {
        int f = p * 256 + tid;
        S[f >> 6][f & 63] = 0.f;
    }
    __syncthreads();
    for (int c = 0; c < NC; ++c) {
        const size_t tbase = ((size_t)bh * NC + c) * 4096;
        const size_t qkbase = ((size_t)bh * LL + (size_t)c * 64) * 64;
#pragma unroll
        for (int p = 0; p < 4; ++p) {
            int flat = p * 1024 + tid * 4;
            int r = flat >> 6, col = flat & 63;
            *(float4*)&Wt[r][col] = *(const float4*)&Wg[tbase + flat];
            *(float4*)&Mt[r][col] = *(const float4*)&Mg[tbase + flat];
            *(float4*)&Qt[r][col] = *(const float4*)&qg[qkbase + flat];
            float4 k4 = *(const float4*)&kg[qkbase + flat];
            KtT[col + 0][r] = k4.x;
            KtT[col + 1][r] = k4.y;
            KtT[col + 2][r] = k4.z;
            KtT[col + 3][r] = k4.w;
        }
        __syncthreads();
        // Delta = U - W*S
        {
            float acc[4][4] = {};
            for (int kk = 0; kk < 64; kk += 4) {
                float4 b0 = *(const float4*)&S[kk + 0][tx * 4];
                float4 b1 = *(const float4*)&S[kk + 1][tx * 4];
                float4 b2 = *(const float4*)&S[kk + 2][tx * 4];
                float4 b3 = *(const float4*)&S[kk + 3][tx * 4];
#pragma unroll
                for (int i = 0; i < 4; ++i) {
                    float4 a = *(const float4*)&Wt[ty * 4 + i][kk];
                    acc[i][0] += a.x * b0.x + a.y * b1.x + a.z * b2.x + a.w * b3.x;
                    acc[i][1] += a.x * b0.y + a.y * b1.y + a.z * b2.y + a.w * b3.y;
                    acc[i][2] += a.x * b0.z + a.y * b1.z + a.z * b2.z + a.w * b3.z;
                    acc[i][3] += a.x * b0.w + a.y * b1.w + a.z * b2.w + a.w * b3.w;
                }
            }
#pragma unroll
            for (int i = 0; i < 4; ++i) {
                float4 u4 = *(const float4*)&Ug[tbase + (size_t)(ty * 4 + i) * 64 + tx * 4];
                float4 dv = make_float4(u4.x - acc[i][0], u4.y - acc[i][1],
                                        u4.z - acc[i][2], u4.w - acc[i][3]);
                *(float4*)&Dt[ty * 4 + i][tx * 4] = dv;
            }
        }
        __syncthreads();
        // O = Q*S + M*Delta  (uses pre-update S)
        {
            float acc[4][4] = {};
            for (int kk = 0; kk < 64; kk += 4) {
                float4 b0 = *(const float4*)&S[kk + 0][tx * 4];
                float4 b1 = *(const float4*)&S[kk + 1][tx * 4];
                float4 b2 = *(const float4*)&S[kk + 2][tx * 4];
                float4 b3 = *(const float4*)&S[kk + 3][tx * 4];
                float4 d0 = *(const float4*)&Dt[kk + 0][tx * 4];
                float4 d1 = *(const float4*)&Dt[kk + 1][tx * 4];
                float4 d2 = *(const float4*)&Dt[kk + 2][tx * 4];
                float4 d3 = *(const float4*)&Dt[kk + 3][tx * 4];
#pragma unroll
                for (int i = 0; i < 4; ++i) {
                    float4 a = *(const float4*)&Qt[ty * 4 + i][kk];
                    float4 m = *(const float4*)&Mt[ty * 4 + i][kk];
                    acc[i][0] += a.x * b0.x + a.y * b1.x + a.z * b2.x + a.w * b3.x
                               + m.x * d0.x + m.y * d1.x + m.z * d2.x + m.w * d3.x;
                    acc[i][1] += a.x * b0.y + a.y * b1.y + a.z * b2.y + a.w * b3.y
                               + m.x * d0.y + m.y * d1.y + m.z * d2.y + m.w * d3.y;
                    acc[i][2] += a.x * b0.z + a.y * b1.z + a.z * b2.z + a.w * b3.z
                               + m.x * d0.z + m.y * d1.z + m.z * d2.z + m.w * d3.z;
                    acc[i][3] += a.x * b0.w + a.y * b1.w + a.z * b2.w + a.w * b3.w
                               + m.x * d0.w + m.y * d1.w + m.z * d2.w + m.w * d3.w;
                }
            }
#pragma unroll
            for (int i = 0; i < 4; ++i) {
                int l = c * 64 + ty * 4 + i;
                float4 r = make_float4(acc[i][0], acc[i][1], acc[i][2], acc[i][3]);
                *(float4*)&og[((size_t)b * LL + l) * DD + h * 64 + tx * 4] = r;
            }
        }
        __syncthreads();
        // S += K^T * Delta
        {
            float acc[4][4] = {};
            for (int t = 0; t < 64; t += 4) {
                float4 b0 = *(const float4*)&Dt[t + 0][tx * 4];
                float4 b1 = *(const float4*)&Dt[t + 1][tx * 4];
                float4 b2 = *(const float4*)&Dt[t + 2][tx * 4];
                float4 b3 = *(const float4*)&Dt[t + 3][tx * 4];
#pragma unroll
                for (int i = 0; i < 4; ++i) {
                    float4 a = *(const float4*)&KtT[ty * 4 + i][t];
                    acc[i][0] += a.x * b0.x + a.y * b1.x + a.z * b2.x + a.w * b3.x;
                    acc[i][1] += a.x * b0.y + a.y * b1.y + a.z * b2.y + a.w * b3.y;
                    acc[i][2] += a.x * b0.z + a.y * b1.z + a.z * b2.z + a.w * b3.z;
                    acc[i][3] += a.x * b0.w + a.y * b1.w + a.z * b2.w + a.w * b3.w;
                }
            }
#pragma unroll
            for (int i = 0; i < 4; ++i) {
                float4 s4 = *(const float4*)&S[ty * 4 + i][tx * 4];
                s4.x += acc[i][0]; s4.y += acc[i][1]; s4.z += acc[i][2]; s4.w += acc[i][3];
                *(float4*)&S[ty * 4 + i][tx * 4] = s4;
            }
        }
        __syncthreads();
    }
}

// ---------------------------------------------------------------------------
// per-head RMSNorm in place on [B,L,D] (heads = contiguous 64-chunks)
// ---------------------------------------------------------------------------
__global__ __launch_bounds__(256) void rmsnorm_k(float* __restrict__ o,
                                                 const float* __restrict__ nw) {
    const int l = blockIdx.x, b = blockIdx.y;
    const int tid = threadIdx.x, d0 = tid * 4;
    float4 v = *(float4*)&o[((size_t)b * LL + l) * DD + d0];
    float s = v.x * v.x + v.y * v.y + v.z * v.z + v.w * v.w;
    s += __shfl_xor(s, 1);
    s += __shfl_xor(s, 2);
    s += __shfl_xor(s, 4);
    s += __shfl_xor(s, 8);
    float rms = rsqrtf(s * (1.f / 64.f) + 1e-5f);
    const float4 w = *(const float4*)&nw[d0 & 63];
    v.x *= rms * w.x; v.y *= rms * w.y; v.z *= rms * w.z; v.w *= rms * w.w;
    *(float4*)&o[((size_t)b * LL + l) * DD + d0] = v;
}

// ---------------------------------------------------------------------------
extern "C" void kernel_launch(void* const* d_in, const int* in_sizes, int n_in,
                              void* d_out, int out_size, void* d_ws, size_t ws_size,
                              hipStream_t stream) {
    const float* x  = (const float*)d_in[0];
    const float* Wq = (const float*)d_in[1];
    const float* Wk = (const float*)d_in[2];
    const float* Wv = (const float*)d_in[3];
    const float* Wb = (const float*)d_in[4];
    const float* cq = (const float*)d_in[5];
    const float* ck = (const float*)d_in[6];
    const float* cv = (const float*)d_in[7];
    const float* nw = (const float*)d_in[8];
    const float* Wo = (const float*)d_in[9];
    float* out = (float*)d_out;
    float* ws = (float*)d_ws;

    const size_t SZ = (size_t)BB * LL * DD;   // 8388608
    float* xq   = ws;            // x@Wq, later reused as Wg
    float* xk   = ws + SZ;       // x@Wk, later reused as Ug
    float* xv   = ws + 2 * SZ;   // x@Wv, later reused as Mg
    float* q    = ws + 3 * SZ;
    float* k    = ws + 4 * SZ;
    float* v    = ws + 5 * SZ;   // later reused as o
    float* beta = ws + 6 * SZ;   // BH*LL floats
    float* Wg = xq;
    float* Ug = xk;
    float* Mg = xv;
    float* og = v;

    dim3 blk(256);
    dim3 gg(16, 128);
    gemm1024_f32<<<gg, blk, 0, stream>>>(x, Wq, xq);
    gemm1024_f32<<<gg, blk, 0, stream>>>(x, Wk, xk);
    gemm1024_f32<<<gg, blk, 0, stream>>>(x, Wv, xv);
    beta_k<<<dim3(512), blk, 0, stream>>>(x, Wb, beta);
    conv_silu<1><<<dim3(LL, BB), blk, 0, stream>>>(xq, cq, q);
    conv_silu<1><<<dim3(LL, BB), blk, 0, stream>>>(xk, ck, k);
    conv_silu<0><<<dim3(LL, BB), blk, 0, stream>>>(xv, cv, v);
    phaseA<<<dim3(NC, BH), blk, 0, stream>>>(k, v, beta, Wg, Ug);
    qkT_M<<<dim3(NC, BH), blk, 0, stream>>>(q, k, Mg);
    phaseB<<<dim3(BH), blk, 0, stream>>>(Wg, Ug, Mg, q, k, og);
    rmsnorm_k<<<dim3(LL, BB), blk, 0, stream>>>(og, nw);
    gemm1024_f32<<<gg, blk, 0, stream>>>(og, Wo, out);
}

// Round 2
// 795.027 us; speedup vs baseline: 2.4044x; 2.4044x over previous
//
#include <hip/hip_runtime.h>
#include <hip/hip_bf16.h>
#include <math.h>

#define BB 2
#define LL 4096
#define DD 1024
#define HH 16
#define HDIM 64
#define CC 64
#define NC 64   // LL/CC
#define BH 32   // BB*HH
#define VS 4    // phaseB v-split
#define VC 16   // v-cols per phaseB block

typedef __attribute__((ext_vector_type(8))) short short8;
typedef __attribute__((ext_vector_type(4))) float f32x4;

__device__ __forceinline__ unsigned short f2bf(float f) {
    unsigned int u = __float_as_uint(f);
    unsigned int r = (u + 0x7fffu + ((u >> 16) & 1u)) >> 16;
    return (unsigned short)r;
}

__device__ __forceinline__ void gld_lds16(const void* g, void* l) {
    __builtin_amdgcn_global_load_lds(
        (const __attribute__((address_space(1))) void*)g,
        (__attribute__((address_space(3))) void*)l, 16, 0, 0);
}

// ---------------------------------------------------------------------------
// fp32 -> bf16 cast (8 elems/thread)
// ---------------------------------------------------------------------------
__global__ __launch_bounds__(256) void cast_bf16_k(const float* __restrict__ in,
                                                   unsigned short* __restrict__ out) {
    int i = (blockIdx.x * 256 + threadIdx.x) * 8;
    float4 a = *(const float4*)&in[i];
    float4 b = *(const float4*)&in[i + 4];
    uint4 o;
    o.x = (unsigned)f2bf(a.x) | ((unsigned)f2bf(a.y) << 16);
    o.y = (unsigned)f2bf(a.z) | ((unsigned)f2bf(a.w) << 16);
    o.z = (unsigned)f2bf(b.x) | ((unsigned)f2bf(b.y) << 16);
    o.w = (unsigned)f2bf(b.z) | ((unsigned)f2bf(b.w) << 16);
    *(uint4*)&out[i] = o;
}

// ---------------------------------------------------------------------------
// W [K=1024][N=1024] fp32 -> WT [N][K] bf16 (transpose-cast, 32x32 LDS tiles)
// ---------------------------------------------------------------------------
__global__ __launch_bounds__(256) void transW_k(const float* __restrict__ W,
                                                unsigned short* __restrict__ WT) {
    __shared__ float t[32][33];
    const int bx = blockIdx.x * 32, by = blockIdx.y * 32;
#pragma unroll
    for (int p = 0; p < 4; ++p) {
        int idx = p * 256 + threadIdx.x;
        int r = idx >> 5, cc = idx & 31;
        t[r][cc] = W[(size_t)(by + r) * 1024 + bx + cc];
    }
    __syncthreads();
#pragma unroll
    for (int p = 0; p < 4; ++p) {
        int idx = p * 256 + threadIdx.x;
        int r = idx >> 5, cc = idx & 31;
        WT[(size_t)(bx + r) * 1024 + by + cc] = f2bf(t[cc][r]);
    }
}

// ---------------------------------------------------------------------------
// bf16 MFMA GEMM: C[8192,1024] fp32 = A[8192,1024]bf16 @ BT[1024,1024]bf16^T
// m97 structure: 128x128 tile, BK=32, 4 waves (2x2), global_load_lds 16B.
// ---------------------------------------------------------------------------
__global__ __launch_bounds__(256) void gemm_bf16(const unsigned short* __restrict__ A,
                                                 const unsigned short* __restrict__ BT,
                                                 float* __restrict__ C) {
    __shared__ __align__(16) short As[128 * 32];
    __shared__ __align__(16) short Bs[128 * 32];
    const int tid = threadIdx.x;
    const int lane = tid & 63, w = tid >> 6;
    const int wr = w >> 1, wc = w & 1;
    const int m0 = blockIdx.y * 128, n0 = blockIdx.x * 128;
    const int ln15 = lane & 15, kg8 = (lane >> 4) * 8;
    f32x4 acc[4][4] = {};
    const int erow = tid >> 2;            // 0..63
    const int ecol = (tid & 3) * 8;       // 0,8,16,24
    for (int k0 = 0; k0 < 1024; k0 += 32) {
#pragma unroll
        for (int r = 0; r < 2; ++r) {
            gld_lds16(A  + (size_t)(m0 + erow + r * 64) * 1024 + k0 + ecol,
                      (short*)As + r * 2048 + tid * 8);
            gld_lds16(BT + (size_t)(n0 + erow + r * 64) * 1024 + k0 + ecol,
                      (short*)Bs + r * 2048 + tid * 8);
        }
        __syncthreads();
        short8 af[4], bf[4];
#pragma unroll
        for (int i = 0; i < 4; ++i)
            af[i] = *(const short8*)&As[(wr * 64 + i * 16 + ln15) * 32 + kg8];
#pragma unroll
        for (int j = 0; j < 4; ++j)
            bf[j] = *(const short8*)&Bs[(wc * 64 + j * 16 + ln15) * 32 + kg8];
#pragma unroll
        for (int i = 0; i < 4; ++i)
#pragma unroll
            for (int j = 0; j < 4; ++j)
                acc[i][j] = __builtin_amdgcn_mfma_f32_16x16x32_bf16(af[i], bf[j], acc[i][j], 0, 0, 0);
        __syncthreads();
    }
    const int crow0 = m0 + wr * 64 + (lane >> 4) * 4;
    const int ccol0 = n0 + wc * 64 + ln15;
#pragma unroll
    for (int i = 0; i < 4; ++i)
#pragma unroll
        for (int j = 0; j < 4; ++j)
#pragma unroll
            for (int r = 0; r < 4; ++r)
                C[(size_t)(crow0 + i * 16 + r) * 1024 + ccol0 + j * 16] = acc[i][j][r];
}

// ---------------------------------------------------------------------------
// beta = sigmoid(x @ Wb) stored [B,H,L]
// ---------------------------------------------------------------------------
__global__ __launch_bounds__(256) void beta_k(const float* __restrict__ X,
                                              const float* __restrict__ Wb,
                                              float* __restrict__ beta) {
    int idx = blockIdx.x * 256 + threadIdx.x;
    int row = idx >> 4, h = idx & 15;
    const float* xr = X + (size_t)row * DD;
    float s = 0.f;
    for (int k4 = 0; k4 < DD; k4 += 4) {
        float4 xv = *(const float4*)&xr[k4];
        s += xv.x * Wb[(k4 + 0) * HH + h];
        s += xv.y * Wb[(k4 + 1) * HH + h];
        s += xv.z * Wb[(k4 + 2) * HH + h];
        s += xv.w * Wb[(k4 + 3) * HH + h];
    }
    float bv = 1.f / (1.f + expf(-s));
    int b = row >> 12, l = row & (LL - 1);
    beta[((size_t)b * HH + h) * LL + l] = bv;
}

// ---------------------------------------------------------------------------
// causal depthwise conv (K=4) + SiLU (+ optional per-head l2 norm)
// ---------------------------------------------------------------------------
template <int NORM>
__global__ __launch_bounds__(256) void conv_silu(const float* __restrict__ X,
                                                 const float* __restrict__ cw,
                                                 float* __restrict__ out) {
    const int l = blockIdx.x, b = blockIdx.y;
    const int tid = threadIdx.x;
    const int d0 = tid * 4;
    const float4 w0 = *(const float4*)&cw[(d0 + 0) * 4];
    const float4 w1 = *(const float4*)&cw[(d0 + 1) * 4];
    const float4 w2 = *(const float4*)&cw[(d0 + 2) * 4];
    const float4 w3 = *(const float4*)&cw[(d0 + 3) * 4];
    float a0 = 0, a1 = 0, a2 = 0, a3 = 0;
#pragma unroll
    for (int j = 0; j < 4; ++j) {
        int xr = l - 3 + j;
        if (xr >= 0) {
            float4 xv = *(const float4*)&X[((size_t)b * LL + xr) * DD + d0];
            a0 += xv.x * ((const float*)&w0)[j];
            a1 += xv.y * ((const float*)&w1)[j];
            a2 += xv.z * ((const float*)&w2)[j];
            a3 += xv.w * ((const float*)&w3)[j];
        }
    }
    a0 = a0 / (1.f + expf(-a0));
    a1 = a1 / (1.f + expf(-a1));
    a2 = a2 / (1.f + expf(-a2));
    a3 = a3 / (1.f + expf(-a3));
    if (NORM) {
        float s = a0 * a0 + a1 * a1 + a2 * a2 + a3 * a3;
        s += __shfl_xor(s, 1);
        s += __shfl_xor(s, 2);
        s += __shfl_xor(s, 4);
        s += __shfl_xor(s, 8);
        float sc = rsqrtf(s);
        a0 *= sc; a1 *= sc; a2 *= sc; a3 *= sc;
    }
    const int h = d0 >> 6, hd = d0 & 63;
    float4 r = make_float4(a0, a1, a2, a3);
    *(float4*)&out[(((size_t)b * HH + h) * LL + l) * 64 + hd] = r;
}

// ---------------------------------------------------------------------------
// Phase A: A = strict_tril(diag(beta) K K^T), solve (I+A)[W|U] = [bK|bV]
// ---------------------------------------------------------------------------
__global__ __launch_bounds__(256) void phaseA(const float* __restrict__ kg,
                                              const float* __restrict__ vg,
                                              const float* __restrict__ betag,
                                              float* __restrict__ Wg,
                                              float* __restrict__ Ug) {
    __shared__ float KtT[64][68];
    __shared__ float At[64][68];
    __shared__ float WU[64][132];
    __shared__ float betas[64];
    const int c = blockIdx.x, bh = blockIdx.y;
    const int tid = threadIdx.x;
    const int tx = tid & 15, ty = tid >> 4;
    const size_t base = ((size_t)bh * LL + (size_t)c * 64) * 64;
#pragma unroll
    for (int p = 0; p < 4; ++p) {
        int flat = p * 1024 + tid * 4;
        int r = flat >> 6, col = flat & 63;
        float4 k4 = *(const float4*)&kg[base + flat];
        float4 v4 = *(const float4*)&vg[base + flat];
        KtT[col + 0][r] = k4.x;
        KtT[col + 1][r] = k4.y;
        KtT[col + 2][r] = k4.z;
        KtT[col + 3][r] = k4.w;
        *(float4*)&At[r][col] = v4;
    }
    if (tid < 64) betas[tid] = betag[(size_t)bh * LL + (size_t)c * 64 + tid];
    __syncthreads();
#pragma unroll
    for (int p = 0; p < 32; ++p) {
        int flat = p * 256 + tid;
        int t = flat >> 7, j = flat & 127;
        WU[t][j] = betas[t] * ((j < 64) ? KtT[j][t] : At[t][j - 64]);
    }
    __syncthreads();
    {
        float acc[4][4] = {};
        for (int x = 0; x < 64; ++x) {
            float4 a = *(const float4*)&KtT[x][ty * 4];
            float4 b = *(const float4*)&KtT[x][tx * 4];
            acc[0][0] += a.x * b.x; acc[0][1] += a.x * b.y; acc[0][2] += a.x * b.z; acc[0][3] += a.x * b.w;
            acc[1][0] += a.y * b.x; acc[1][1] += a.y * b.y; acc[1][2] += a.y * b.z; acc[1][3] += a.y * b.w;
            acc[2][0] += a.z * b.x; acc[2][1] += a.z * b.y; acc[2][2] += a.z * b.z; acc[2][3] += a.z * b.w;
            acc[3][0] += a.w * b.x; acc[3][1] += a.w * b.y; acc[3][2] += a.w * b.z; acc[3][3] += a.w * b.w;
        }
#pragma unroll
        for (int i = 0; i < 4; ++i) {
            int t = ty * 4 + i;
            float bt = betas[t];
            float4 w;
            w.x = (tx * 4 + 0 < t) ? bt * acc[i][0] : 0.f;
            w.y = (tx * 4 + 1 < t) ? bt * acc[i][1] : 0.f;
            w.z = (tx * 4 + 2 < t) ? bt * acc[i][2] : 0.f;
            w.w = (tx * 4 + 3 < t) ? bt * acc[i][3] : 0.f;
            *(float4*)&At[t][tx * 4] = w;
        }
    }
    __syncthreads();
    if (tid < 128) {
        const int col = tid;
        for (int t = 1; t < 64; ++t) {
            float a = WU[t][col];
            for (int r = 0; r < t; ++r) a -= At[t][r] * WU[r][col];
            WU[t][col] = a;
        }
    }
    __syncthreads();
    const size_t obase = ((size_t)bh * NC + c) * 4096;
#pragma unroll
    for (int p = 0; p < 32; ++p) {
        int flat = p * 256 + tid;
        int t = flat >> 7, j = flat & 127;
        float val = WU[t][j];
        if (j < 64) Wg[obase + (size_t)t * 64 + j] = val;
        else        Ug[obase + (size_t)t * 64 + (j - 64)] = val;
    }
}

// ---------------------------------------------------------------------------
// M = causal(Q K^T)
// ---------------------------------------------------------------------------
__global__ __launch_bounds__(256) void qkT_M(const float* __restrict__ qg,
                                             const float* __restrict__ kg,
                                             float* __restrict__ Mg) {
    __shared__ float QtT[64][68];
    __shared__ float KtT[64][68];
    const int c = blockIdx.x, bh = blockIdx.y;
    const int tid = threadIdx.x;
    const int tx = tid & 15, ty = tid >> 4;
    const size_t base = ((size_t)bh * LL + (size_t)c * 64) * 64;
#pragma unroll
    for (int p = 0; p < 4; ++p) {
        int flat = p * 1024 + tid * 4;
        int r = flat >> 6, col = flat & 63;
        float4 q4 = *(const float4*)&qg[base + flat];
        float4 k4 = *(const float4*)&kg[base + flat];
        QtT[col + 0][r] = q4.x; QtT[col + 1][r] = q4.y; QtT[col + 2][r] = q4.z; QtT[col + 3][r] = q4.w;
        KtT[col + 0][r] = k4.x; KtT[col + 1][r] = k4.y; KtT[col + 2][r] = k4.z; KtT[col + 3][r] = k4.w;
    }
    __syncthreads();
    float acc[4][4] = {};
    for (int x = 0; x < 64; ++x) {
        float4 a = *(const float4*)&QtT[x][ty * 4];
        float4 b = *(const float4*)&KtT[x][tx * 4];
        acc[0][0] += a.x * b.x; acc[0][1] += a.x * b.y; acc[0][2] += a.x * b.z; acc[0][3] += a.x * b.w;
        acc[1][0] += a.y * b.x; acc[1][1] += a.y * b.y; acc[1][2] += a.y * b.z; acc[1][3] += a.y * b.w;
        acc[2][0] += a.z * b.x; acc[2][1] += a.z * b.y; acc[2][2] += a.z * b.z; acc[2][3] += a.z * b.w;
        acc[3][0] += a.w * b.x; acc[3][1] += a.w * b.y; acc[3][2] += a.w * b.z; acc[3][3] += a.w * b.w;
    }
    const size_t obase = ((size_t)bh * NC + c) * 4096;
#pragma unroll
    for (int i = 0; i < 4; ++i) {
        int t = ty * 4 + i;
        float4 w;
        w.x = (tx * 4 + 0 <= t) ? acc[i][0] : 0.f;
        w.y = (tx * 4 + 1 <= t) ? acc[i][1] : 0.f;
        w.z = (tx * 4 + 2 <= t) ? acc[i][2] : 0.f;
        w.w = (tx * 4 + 3 <= t) ? acc[i][3] : 0.f;
        *(float4*)&Mg[obase + (size_t)t * 64 + tx * 4] = w;
    }
}

// ---------------------------------------------------------------------------
// Phase B v2: v-split across blocks. grid (VS, BH). Each block owns VC=16
// v-columns; S,Delta,U slices in LDS; W/M/Q/KtT broadcast tiles.
//   Delta = U - W*S ; O = Q*S + M*Delta ; S += K^T*Delta
// ---------------------------------------------------------------------------
__global__ __launch_bounds__(256) void phaseB2(const float* __restrict__ Wg,
                                               const float* __restrict__ Ug,
                                               const float* __restrict__ Mg,
                                               const float* __restrict__ qg,
                                               const float* __restrict__ kg,
                                               float* __restrict__ og) {
    __shared__ float Wt[64][68];
    __shared__ float Mt[64][68];
    __shared__ float Qt[64][68];
    __shared__ float KtT[64][69];
    __shared__ float Ss[64][20];
    __shared__ float Ds[64][20];
    __shared__ float Us[64][20];
    const int vs = blockIdx.x, bh = blockIdx.y;
    const int v0 = vs * VC;
    const int b = bh >> 4, h = bh & 15;
    const int tid = threadIdx.x;
    const int tr = tid >> 2;          // 0..63
    const int tc = (tid & 3) * 4;     // 0,4,8,12
#pragma unroll
    for (int p = 0; p < 4; ++p) {
        int f = p * 256 + tid;
        Ss[f >> 4][f & 15] = 0.f;
    }
    __syncthreads();
    for (int c = 0; c < NC; ++c) {
        const size_t tbase = ((size_t)bh * NC + c) * 4096;
        const size_t qkbase = ((size_t)bh * LL + (size_t)c * 64) * 64;
#pragma unroll
        for (int p = 0; p < 4; ++p) {
            int flat = p * 1024 + tid * 4;
            int r = flat >> 6, col = flat & 63;
            *(float4*)&Wt[r][col] = *(const float4*)&Wg[tbase + flat];
            *(float4*)&Mt[r][col] = *(const float4*)&Mg[tbase + flat];
            *(float4*)&Qt[r][col] = *(const float4*)&qg[qkbase + flat];
            float4 k4 = *(const float4*)&kg[qkbase + flat];
            KtT[col + 0][r] = k4.x; KtT[col + 1][r] = k4.y;
            KtT[col + 2][r] = k4.z; KtT[col + 3][r] = k4.w;
        }
        *(float4*)&Us[tr][tc] = *(const float4*)&Ug[tbase + (size_t)tr * 64 + v0 + tc];
        __syncthreads();
        // Delta = U - W*S
        {
            float a0 = 0, a1 = 0, a2 = 0, a3 = 0;
            const float* wrow = &Wt[tr][0];
#pragma unroll 8
            for (int k = 0; k < 64; ++k) {
                float wv = wrow[k];
                float4 s4 = *(const float4*)&Ss[k][tc];
                a0 += wv * s4.x; a1 += wv * s4.y; a2 += wv * s4.z; a3 += wv * s4.w;
            }
            float4 u4 = *(const float4*)&Us[tr][tc];
            float4 dv = make_float4(u4.x - a0, u4.y - a1, u4.z - a2, u4.w - a3);
            *(float4*)&Ds[tr][tc] = dv;
        }
        __syncthreads();
        // O = Q*S + M*Delta   (pre-update S)
        float4 oacc;
        {
            const float* qrow = &Qt[tr][0];
            const float* mrow = &Mt[tr][0];
            float a0 = 0, a1 = 0, a2 = 0, a3 = 0;
#pragma unroll 8
            for (int k = 0; k < 64; ++k) {
                float qv = qrow[k], mv = mrow[k];
                float4 s4 = *(const float4*)&Ss[k][tc];
                float4 d4 = *(const float4*)&Ds[k][tc];
                a0 += qv * s4.x + mv * d4.x;
                a1 += qv * s4.y + mv * d4.y;
                a2 += qv * s4.z + mv * d4.z;
                a3 += qv * s4.w + mv * d4.w;
            }
            oacc = make_float4(a0, a1, a2, a3);
        }
        // S-update accumulator: sacc = K^T * Delta  (row tr = k index)
        float4 sacc;
        {
            const float* krow = &KtT[tr][0];
            float a0 = 0, a1 = 0, a2 = 0, a3 = 0;
#pragma unroll 8
            for (int t = 0; t < 64; ++t) {
                float kv = krow[t];
                float4 d4 = *(const float4*)&Ds[t][tc];
                a0 += kv * d4.x; a1 += kv * d4.y; a2 += kv * d4.z; a3 += kv * d4.w;
            }
            sacc = make_float4(a0, a1, a2, a3);
        }
        {
            int l = c * 64 + tr;
            *(float4*)&og[((size_t)b * LL + l) * DD + h * 64 + v0 + tc] = oacc;
        }
        __syncthreads();
        {
            float4 s4 = *(const float4*)&Ss[tr][tc];
            s4.x += sacc.x; s4.y += sacc.y; s4.z += sacc.z; s4.w += sacc.w;
            *(float4*)&Ss[tr][tc] = s4;
        }
        __syncthreads();
    }
}

// ---------------------------------------------------------------------------
// per-head RMSNorm in place
// ---------------------------------------------------------------------------
__global__ __launch_bounds__(256) void rmsnorm_k(float* __restrict__ o,
                                                 const float* __restrict__ nw) {
    const int l = blockIdx.x, b = blockIdx.y;
    const int tid = threadIdx.x, d0 = tid * 4;
    float4 v = *(float4*)&o[((size_t)b * LL + l) * DD + d0];
    float s = v.x * v.x + v.y * v.y + v.z * v.z + v.w * v.w;
    s += __shfl_xor(s, 1);
    s += __shfl_xor(s, 2);
    s += __shfl_xor(s, 4);
    s += __shfl_xor(s, 8);
    float rms = rsqrtf(s * (1.f / 64.f) + 1e-5f);
    const float4 w = *(const float4*)&nw[d0 & 63];
    v.x *= rms * w.x; v.y *= rms * w.y; v.z *= rms * w.z; v.w *= rms * w.w;
    *(float4*)&o[((size_t)b * LL + l) * DD + d0] = v;
}

// ---------------------------------------------------------------------------
extern "C" void kernel_launch(void* const* d_in, const int* in_sizes, int n_in,
                              void* d_out, int out_size, void* d_ws, size_t ws_size,
                              hipStream_t stream) {
    const float* x  = (const float*)d_in[0];
    const float* Wq = (const float*)d_in[1];
    const float* Wk = (const float*)d_in[2];
    const float* Wv = (const float*)d_in[3];
    const float* Wb = (const float*)d_in[4];
    const float* cq = (const float*)d_in[5];
    const float* ck = (const float*)d_in[6];
    const float* cv = (const float*)d_in[7];
    const float* nw = (const float*)d_in[8];
    const float* Wo = (const float*)d_in[9];
    float* out = (float*)d_out;
    float* ws = (float*)d_ws;

    const size_t SZ = (size_t)BB * LL * DD;   // 8388608
    float* xq   = ws;            // x@Wq -> Wg -> (ob region at end)
    float* xk   = ws + SZ;       // x@Wk -> Ug
    float* xv   = ws + 2 * SZ;   // x@Wv -> Mg
    float* q    = ws + 3 * SZ;   // (xb region first)
    float* k    = ws + 4 * SZ;
    float* v    = ws + 5 * SZ;   // -> og
    float* beta = ws + 6 * SZ;   // BH*LL floats
    unsigned short* xb  = (unsigned short*)q;            // bf16 x (dead before conv_q)
    unsigned short* ob  = (unsigned short*)xq;           // bf16 o (Wg dead by then)
    unsigned short* wqT = (unsigned short*)(beta + (size_t)BH * LL);
    unsigned short* wkT = wqT + (size_t)1024 * 1024;
    unsigned short* wvT = wkT + (size_t)1024 * 1024;
    unsigned short* woT = wvT + (size_t)1024 * 1024;
    float* Wg = xq;
    float* Ug = xk;
    float* Mg = xv;
    float* og = v;

    dim3 blk(256);
    dim3 gt(32, 32);
    dim3 gg(8, 64);   // N/128 x M/128

    cast_bf16_k<<<dim3(4096), blk, 0, stream>>>(x, xb);
    transW_k<<<gt, blk, 0, stream>>>(Wq, wqT);
    transW_k<<<gt, blk, 0, stream>>>(Wk, wkT);
    transW_k<<<gt, blk, 0, stream>>>(Wv, wvT);
    transW_k<<<gt, blk, 0, stream>>>(Wo, woT);
    gemm_bf16<<<gg, blk, 0, stream>>>(xb, wqT, xq);
    gemm_bf16<<<gg, blk, 0, stream>>>(xb, wkT, xk);
    gemm_bf16<<<gg, blk, 0, stream>>>(xb, wvT, xv);
    beta_k<<<dim3(512), blk, 0, stream>>>(x, Wb, beta);
    conv_silu<1><<<dim3(LL, BB), blk, 0, stream>>>(xq, cq, q);
    conv_silu<1><<<dim3(LL, BB), blk, 0, stream>>>(xk, ck, k);
    conv_silu<0><<<dim3(LL, BB), blk, 0, stream>>>(xv, cv, v);
    phaseA<<<dim3(NC, BH), blk, 0, stream>>>(k, v, beta, Wg, Ug);
    qkT_M<<<dim3(NC, BH), blk, 0, stream>>>(q, k, Mg);
    phaseB2<<<dim3(VS, BH), blk, 0, stream>>>(Wg, Ug, Mg, q, k, og);
    rmsnorm_k<<<dim3(LL, BB), blk, 0, stream>>>(og, nw);
    cast_bf16_k<<<dim3(4096), blk, 0, stream>>>(og, ob);
    gemm_bf16<<<gg, blk, 0, stream>>>(ob, woT, out);
}

// Round 3
// 629.095 us; speedup vs baseline: 3.0386x; 1.2638x over previous
//
#include <hip/hip_runtime.h>
#include <hip/hip_bf16.h>
#include <math.h>

#define BB 2
#define LL 4096
#define DD 1024
#define HH 16
#define HDIM 64
#define CC 64
#define NC 64   // LL/CC
#define BH 32   // BB*HH
#define GG 8    // chunk groups
#define GS 8    // chunks per group

typedef __attribute__((ext_vector_type(8))) short short8;
typedef __attribute__((ext_vector_type(4))) float f32x4;

__device__ __forceinline__ unsigned short f2bf(float f) {
    unsigned int u = __float_as_uint(f);
    unsigned int r = (u + 0x7fffu + ((u >> 16) & 1u)) >> 16;
    return (unsigned short)r;
}

__device__ __forceinline__ void gld_lds16(const void* g, void* l) {
    __builtin_amdgcn_global_load_lds(
        (const __attribute__((address_space(1))) void*)g,
        (__attribute__((address_space(3))) void*)l, 16, 0, 0);
}

// ---------------------------------------------------------------------------
// fp32 -> bf16 cast (8 elems/thread)
// ---------------------------------------------------------------------------
__global__ __launch_bounds__(256) void cast_bf16_k(const float* __restrict__ in,
                                                   unsigned short* __restrict__ out) {
    int i = (blockIdx.x * 256 + threadIdx.x) * 8;
    float4 a = *(const float4*)&in[i];
    float4 b = *(const float4*)&in[i + 4];
    uint4 o;
    o.x = (unsigned)f2bf(a.x) | ((unsigned)f2bf(a.y) << 16);
    o.y = (unsigned)f2bf(a.z) | ((unsigned)f2bf(a.w) << 16);
    o.z = (unsigned)f2bf(b.x) | ((unsigned)f2bf(b.y) << 16);
    o.w = (unsigned)f2bf(b.z) | ((unsigned)f2bf(b.w) << 16);
    *(uint4*)&out[i] = o;
}

// ---------------------------------------------------------------------------
// W [K][N] fp32 -> WT [N][K] bf16
// ---------------------------------------------------------------------------
__global__ __launch_bounds__(256) void transW_k(const float* __restrict__ W,
                                                unsigned short* __restrict__ WT) {
    __shared__ float t[32][33];
    const int bx = blockIdx.x * 32, by = blockIdx.y * 32;
#pragma unroll
    for (int p = 0; p < 4; ++p) {
        int idx = p * 256 + threadIdx.x;
        int r = idx >> 5, cc = idx & 31;
        t[r][cc] = W[(size_t)(by + r) * 1024 + bx + cc];
    }
    __syncthreads();
#pragma unroll
    for (int p = 0; p < 4; ++p) {
        int idx = p * 256 + threadIdx.x;
        int r = idx >> 5, cc = idx & 31;
        WT[(size_t)(bx + r) * 1024 + by + cc] = f2bf(t[cc][r]);
    }
}

// ---------------------------------------------------------------------------
// bf16 MFMA GEMM body (m97 structure: 128x128 tile, BK=32, 4 waves)
// ---------------------------------------------------------------------------
__device__ __forceinline__ void gemm_body(const unsigned short* A,
                                          const unsigned short* BT,
                                          float* C, int m0, int n0) {
    __shared__ __align__(16) short As[128 * 32];
    __shared__ __align__(16) short Bs[128 * 32];
    const int tid = threadIdx.x;
    const int lane = tid & 63, w = tid >> 6;
    const int wr = w >> 1, wc = w & 1;
    const int ln15 = lane & 15, kg8 = (lane >> 4) * 8;
    f32x4 acc[4][4] = {};
    const int erow = tid >> 2;
    const int ecol = (tid & 3) * 8;
    for (int k0 = 0; k0 < 1024; k0 += 32) {
#pragma unroll
        for (int r = 0; r < 2; ++r) {
            gld_lds16(A  + (size_t)(m0 + erow + r * 64) * 1024 + k0 + ecol,
                      (short*)As + r * 2048 + tid * 8);
            gld_lds16(BT + (size_t)(n0 + erow + r * 64) * 1024 + k0 + ecol,
                      (short*)Bs + r * 2048 + tid * 8);
        }
        __syncthreads();
        short8 af[4], bf[4];
#pragma unroll
        for (int i = 0; i < 4; ++i)
            af[i] = *(const short8*)&As[(wr * 64 + i * 16 + ln15) * 32 + kg8];
#pragma unroll
        for (int j = 0; j < 4; ++j)
            bf[j] = *(const short8*)&Bs[(wc * 64 + j * 16 + ln15) * 32 + kg8];
#pragma unroll
        for (int i = 0; i < 4; ++i)
#pragma unroll
            for (int j = 0; j < 4; ++j)
                acc[i][j] = __builtin_amdgcn_mfma_f32_16x16x32_bf16(af[i], bf[j], acc[i][j], 0, 0, 0);
        __syncthreads();
    }
    const int crow0 = m0 + wr * 64 + (lane >> 4) * 4;
    const int ccol0 = n0 + wc * 64 + ln15;
#pragma unroll
    for (int i = 0; i < 4; ++i)
#pragma unroll
        for (int j = 0; j < 4; ++j)
#pragma unroll
            for (int r = 0; r < 4; ++r)
                C[(size_t)(crow0 + i * 16 + r) * 1024 + ccol0 + j * 16] = acc[i][j][r];
}

__global__ __launch_bounds__(256) void gemm_bf16(const unsigned short* __restrict__ A,
                                                 const unsigned short* __restrict__ BT,
                                                 float* __restrict__ C) {
    gemm_body(A, BT, C, blockIdx.y * 128, blockIdx.x * 128);
}

// fused q/k/v projection: grid.x = 24, which = bx>>3
__global__ __launch_bounds__(256) void gemm_qkv(const unsigned short* __restrict__ A,
                                                const unsigned short* __restrict__ WT0,
                                                float* __restrict__ C0) {
    const int which = blockIdx.x >> 3;
    const int n0 = (blockIdx.x & 7) * 128;
    const unsigned short* BT = WT0 + (size_t)which * 1048576;
    float* C = C0 + (size_t)which * ((size_t)BB * LL * DD);
    gemm_body(A, BT, C, blockIdx.y * 128, n0);
}

// ---------------------------------------------------------------------------
// beta = sigmoid(x @ Wb) stored [B,H,L]
// ---------------------------------------------------------------------------
__global__ __launch_bounds__(256) void beta_k(const float* __restrict__ X,
                                              const float* __restrict__ Wb,
                                              float* __restrict__ beta) {
    int idx = blockIdx.x * 256 + threadIdx.x;
    int row = idx >> 4, h = idx & 15;
    const float* xr = X + (size_t)row * DD;
    float s = 0.f;
    for (int k4 = 0; k4 < DD; k4 += 4) {
        float4 xv = *(const float4*)&xr[k4];
        s += xv.x * Wb[(k4 + 0) * HH + h];
        s += xv.y * Wb[(k4 + 1) * HH + h];
        s += xv.z * Wb[(k4 + 2) * HH + h];
        s += xv.w * Wb[(k4 + 3) * HH + h];
    }
    float bv = 1.f / (1.f + expf(-s));
    int b = row >> 12, l = row & (LL - 1);
    beta[((size_t)b * HH + h) * LL + l] = bv;
}

// ---------------------------------------------------------------------------
// causal depthwise conv (K=4) + SiLU (+ optional per-head l2 norm)
// ---------------------------------------------------------------------------
template <int NORM>
__global__ __launch_bounds__(256) void conv_silu(const float* __restrict__ X,
                                                 const float* __restrict__ cw,
                                                 float* __restrict__ out) {
    const int l = blockIdx.x, b = blockIdx.y;
    const int tid = threadIdx.x;
    const int d0 = tid * 4;
    const float4 w0 = *(const float4*)&cw[(d0 + 0) * 4];
    const float4 w1 = *(const float4*)&cw[(d0 + 1) * 4];
    const float4 w2 = *(const float4*)&cw[(d0 + 2) * 4];
    const float4 w3 = *(const float4*)&cw[(d0 + 3) * 4];
    float a0 = 0, a1 = 0, a2 = 0, a3 = 0;
#pragma unroll
    for (int j = 0; j < 4; ++j) {
        int xr = l - 3 + j;
        if (xr >= 0) {
            float4 xv = *(const float4*)&X[((size_t)b * LL + xr) * DD + d0];
            a0 += xv.x * ((const float*)&w0)[j];
            a1 += xv.y * ((const float*)&w1)[j];
            a2 += xv.z * ((const float*)&w2)[j];
            a3 += xv.w * ((const float*)&w3)[j];
        }
    }
    a0 = a0 / (1.f + expf(-a0));
    a1 = a1 / (1.f + expf(-a1));
    a2 = a2 / (1.f + expf(-a2));
    a3 = a3 / (1.f + expf(-a3));
    if (NORM) {
        float s = a0 * a0 + a1 * a1 + a2 * a2 + a3 * a3;
        s += __shfl_xor(s, 1);
        s += __shfl_xor(s, 2);
        s += __shfl_xor(s, 4);
        s += __shfl_xor(s, 8);
        float sc = rsqrtf(s);
        a0 *= sc; a1 *= sc; a2 *= sc; a3 *= sc;
    }
    const int h = d0 >> 6, hd = d0 & 63;
    float4 r = make_float4(a0, a1, a2, a3);
    *(float4*)&out[(((size_t)b * HH + h) * LL + l) * 64 + hd] = r;
}

// ---------------------------------------------------------------------------
// Phase A: A = strict_tril(diag(beta) K K^T), solve (I+A)[W|U] = [bK|bV]
// ---------------------------------------------------------------------------
__global__ __launch_bounds__(256) void phaseA(const float* __restrict__ kg,
                                              const float* __restrict__ vg,
                                              const float* __restrict__ betag,
                                              float* __restrict__ Wg,
                                              float* __restrict__ Ug) {
    __shared__ float KtT[64][68];
    __shared__ float At[64][68];
    __shared__ float WU[64][132];
    __shared__ float betas[64];
    const int c = blockIdx.x, bh = blockIdx.y;
    const int tid = threadIdx.x;
    const int tx = tid & 15, ty = tid >> 4;
    const size_t base = ((size_t)bh * LL + (size_t)c * 64) * 64;
#pragma unroll
    for (int p = 0; p < 4; ++p) {
        int flat = p * 1024 + tid * 4;
        int r = flat >> 6, col = flat & 63;
        float4 k4 = *(const float4*)&kg[base + flat];
        float4 v4 = *(const float4*)&vg[base + flat];
        KtT[col + 0][r] = k4.x;
        KtT[col + 1][r] = k4.y;
        KtT[col + 2][r] = k4.z;
        KtT[col + 3][r] = k4.w;
        *(float4*)&At[r][col] = v4;
    }
    if (tid < 64) betas[tid] = betag[(size_t)bh * LL + (size_t)c * 64 + tid];
    __syncthreads();
#pragma unroll
    for (int p = 0; p < 32; ++p) {
        int flat = p * 256 + tid;
        int t = flat >> 7, j = flat & 127;
        WU[t][j] = betas[t] * ((j < 64) ? KtT[j][t] : At[t][j - 64]);
    }
    __syncthreads();
    {
        float acc[4][4] = {};
        for (int x = 0; x < 64; ++x) {
            float4 a = *(const float4*)&KtT[x][ty * 4];
            float4 b = *(const float4*)&KtT[x][tx * 4];
            acc[0][0] += a.x * b.x; acc[0][1] += a.x * b.y; acc[0][2] += a.x * b.z; acc[0][3] += a.x * b.w;
            acc[1][0] += a.y * b.x; acc[1][1] += a.y * b.y; acc[1][2] += a.y * b.z; acc[1][3] += a.y * b.w;
            acc[2][0] += a.z * b.x; acc[2][1] += a.z * b.y; acc[2][2] += a.z * b.z; acc[2][3] += a.z * b.w;
            acc[3][0] += a.w * b.x; acc[3][1] += a.w * b.y; acc[3][2] += a.w * b.z; acc[3][3] += a.w * b.w;
        }
#pragma unroll
        for (int i = 0; i < 4; ++i) {
            int t = ty * 4 + i;
            float bt = betas[t];
            float4 w;
            w.x = (tx * 4 + 0 < t) ? bt * acc[i][0] : 0.f;
            w.y = (tx * 4 + 1 < t) ? bt * acc[i][1] : 0.f;
            w.z = (tx * 4 + 2 < t) ? bt * acc[i][2] : 0.f;
            w.w = (tx * 4 + 3 < t) ? bt * acc[i][3] : 0.f;
            *(float4*)&At[t][tx * 4] = w;
        }
    }
    __syncthreads();
    if (tid < 128) {
        const int col = tid;
        for (int t = 1; t < 64; ++t) {
            float a = WU[t][col];
            for (int r = 0; r < t; ++r) a -= At[t][r] * WU[r][col];
            WU[t][col] = a;
        }
    }
    __syncthreads();
    const size_t obase = ((size_t)bh * NC + c) * 4096;
#pragma unroll
    for (int p = 0; p < 32; ++p) {
        int flat = p * 256 + tid;
        int t = flat >> 7, j = flat & 127;
        float val = WU[t][j];
        if (j < 64) Wg[obase + (size_t)t * 64 + j] = val;
        else        Ug[obase + (size_t)t * 64 + (j - 64)] = val;
    }
}

// ---------------------------------------------------------------------------
// M = causal(Q K^T)
// ---------------------------------------------------------------------------
__global__ __launch_bounds__(256) void qkT_M(const float* __restrict__ qg,
                                             const float* __restrict__ kg,
                                             float* __restrict__ Mg) {
    __shared__ float QtT[64][68];
    __shared__ float KtT[64][68];
    const int c = blockIdx.x, bh = blockIdx.y;
    const int tid = threadIdx.x;
    const int tx = tid & 15, ty = tid >> 4;
    const size_t base = ((size_t)bh * LL + (size_t)c * 64) * 64;
#pragma unroll
    for (int p = 0; p < 4; ++p) {
        int flat = p * 1024 + tid * 4;
        int r = flat >> 6, col = flat & 63;
        float4 q4 = *(const float4*)&qg[base + flat];
        float4 k4 = *(const float4*)&kg[base + flat];
        QtT[col + 0][r] = q4.x; QtT[col + 1][r] = q4.y; QtT[col + 2][r] = q4.z; QtT[col + 3][r] = q4.w;
        KtT[col + 0][r] = k4.x; KtT[col + 1][r] = k4.y; KtT[col + 2][r] = k4.z; KtT[col + 3][r] = k4.w;
    }
    __syncthreads();
    float acc[4][4] = {};
    for (int x = 0; x < 64; ++x) {
        float4 a = *(const float4*)&QtT[x][ty * 4];
        float4 b = *(const float4*)&KtT[x][tx * 4];
        acc[0][0] += a.x * b.x; acc[0][1] += a.x * b.y; acc[0][2] += a.x * b.z; acc[0][3] += a.x * b.w;
        acc[1][0] += a.y * b.x; acc[1][1] += a.y * b.y; acc[1][2] += a.y * b.z; acc[1][3] += a.y * b.w;
        acc[2][0] += a.z * b.x; acc[2][1] += a.z * b.y; acc[2][2] += a.z * b.z; acc[2][3] += a.z * b.w;
        acc[3][0] += a.w * b.x; acc[3][1] += a.w * b.y; acc[3][2] += a.w * b.z; acc[3][3] += a.w * b.w;
    }
    const size_t obase = ((size_t)bh * NC + c) * 4096;
#pragma unroll
    for (int i = 0; i < 4; ++i) {
        int t = ty * 4 + i;
        float4 w;
        w.x = (tx * 4 + 0 <= t) ? acc[i][0] : 0.f;
        w.y = (tx * 4 + 1 <= t) ? acc[i][1] : 0.f;
        w.z = (tx * 4 + 2 <= t) ? acc[i][2] : 0.f;
        w.w = (tx * 4 + 3 <= t) ? acc[i][3] : 0.f;
        *(float4*)&Mg[obase + (size_t)t * 64 + tx * 4] = w;
    }
}

// ---------------------------------------------------------------------------
// S1: per-chunk affine map  P_c = I - K^T W ,  B_c = K^T U   (parallel)
// ---------------------------------------------------------------------------
__global__ __launch_bounds__(256) void phaseS1(const float* __restrict__ kg,
                                               const float* __restrict__ Wg,
                                               const float* __restrict__ Ug,
                                               float* __restrict__ Pall,
                                               float* __restrict__ Ball) {
    __shared__ float Kt[64][68];
    __shared__ float Wt[64][68];
    __shared__ float Ut[64][68];
    const int c = blockIdx.x, bh = blockIdx.y;
    const int tid = threadIdx.x;
    const int tx = tid & 15, ty = tid >> 4;
    const size_t kbase = ((size_t)bh * LL + (size_t)c * 64) * 64;
    const size_t tbase = ((size_t)bh * NC + c) * 4096;
#pragma unroll
    for (int p = 0; p < 4; ++p) {
        int flat = p * 1024 + tid * 4;
        int r = flat >> 6, col = flat & 63;
        *(float4*)&Kt[r][col] = *(const float4*)&kg[kbase + flat];
        *(float4*)&Wt[r][col] = *(const float4*)&Wg[tbase + flat];
        *(float4*)&Ut[r][col] = *(const float4*)&Ug[tbase + flat];
    }
    __syncthreads();
    float aP[4][4] = {}, aB[4][4] = {};
    for (int t = 0; t < 64; ++t) {
        float4 a = *(const float4*)&Kt[t][ty * 4];
        float4 bw = *(const float4*)&Wt[t][tx * 4];
        float4 bu = *(const float4*)&Ut[t][tx * 4];
#pragma unroll
        for (int i = 0; i < 4; ++i) {
            float av = ((const float*)&a)[i];
            aP[i][0] += av * bw.x; aP[i][1] += av * bw.y; aP[i][2] += av * bw.z; aP[i][3] += av * bw.w;
            aB[i][0] += av * bu.x; aB[i][1] += av * bu.y; aB[i][2] += av * bu.z; aB[i][3] += av * bu.w;
        }
    }
#pragma unroll
    for (int i = 0; i < 4; ++i) {
        int row = ty * 4 + i;
        float4 pv, bv;
        pv.x = ((row == tx * 4 + 0) ? 1.f : 0.f) - aP[i][0];
        pv.y = ((row == tx * 4 + 1) ? 1.f : 0.f) - aP[i][1];
        pv.z = ((row == tx * 4 + 2) ? 1.f : 0.f) - aP[i][2];
        pv.w = ((row == tx * 4 + 3) ? 1.f : 0.f) - aP[i][3];
        bv = make_float4(aB[i][0], aB[i][1], aB[i][2], aB[i][3]);
        *(float4*)&Pall[tbase + (size_t)row * 64 + tx * 4] = pv;
        *(float4*)&Ball[tbase + (size_t)row * 64 + tx * 4] = bv;
    }
}

// ---------------------------------------------------------------------------
// compose: per group of 8 chunks, composed map (Pg, Bg).  grid (GG, BH)
//   (P,B) <- (P_c P, P_c B + B_c)
// ---------------------------------------------------------------------------
__global__ __launch_bounds__(256) void composeK(const float* __restrict__ Pall,
                                                const float* __restrict__ Ball,
                                                float* __restrict__ Pg,
                                                float* __restrict__ Bg) {
    __shared__ float cP[64][68];
    __shared__ float cB[64][68];
    __shared__ float nPt[64][68];   // transposed P_c
    __shared__ float nB[64][68];
    const int g = blockIdx.x, bh = blockIdx.y;
    const int tid = threadIdx.x;
    const int tx = tid & 15, ty = tid >> 4;
    const size_t base0 = ((size_t)bh * NC + (size_t)g * GS) * 4096;
#pragma unroll
    for (int p = 0; p < 4; ++p) {
        int flat = p * 1024 + tid * 4;
        int r = flat >> 6, col = flat & 63;
        *(float4*)&cP[r][col] = *(const float4*)&Pall[base0 + flat];
        *(float4*)&cB[r][col] = *(const float4*)&Ball[base0 + flat];
    }
    float aP[4][4], aB[4][4];
    for (int s = 1; s < GS; ++s) {
        __syncthreads();
#pragma unroll
        for (int p = 0; p < 4; ++p) {
            int flat = p * 1024 + tid * 4;
            int r = flat >> 6, col = flat & 63;
            float4 pv = *(const float4*)&Pall[base0 + (size_t)s * 4096 + flat];
            nPt[col + 0][r] = pv.x; nPt[col + 1][r] = pv.y;
            nPt[col + 2][r] = pv.z; nPt[col + 3][r] = pv.w;
            *(float4*)&nB[r][col] = *(const float4*)&Ball[base0 + (size_t)s * 4096 + flat];
        }
        __syncthreads();
#pragma unroll
        for (int i = 0; i < 4; ++i)
#pragma unroll
            for (int j = 0; j < 4; ++j) { aP[i][j] = 0.f; aB[i][j] = 0.f; }
        for (int k = 0; k < 64; ++k) {
            float4 a = *(const float4*)&nPt[k][ty * 4];
            float4 bp = *(const float4*)&cP[k][tx * 4];
            float4 bb = *(const float4*)&cB[k][tx * 4];
#pragma unroll
            for (int i = 0; i < 4; ++i) {
                float av = ((const float*)&a)[i];
                aP[i][0] += av * bp.x; aP[i][1] += av * bp.y; aP[i][2] += av * bp.z; aP[i][3] += av * bp.w;
                aB[i][0] += av * bb.x; aB[i][1] += av * bb.y; aB[i][2] += av * bb.z; aB[i][3] += av * bb.w;
            }
        }
        __syncthreads();
#pragma unroll
        for (int i = 0; i < 4; ++i) {
            float4 nb = *(const float4*)&nB[ty * 4 + i][tx * 4];
            float4 np = make_float4(aP[i][0], aP[i][1], aP[i][2], aP[i][3]);
            float4 nbb = make_float4(aB[i][0] + nb.x, aB[i][1] + nb.y,
                                     aB[i][2] + nb.z, aB[i][3] + nb.w);
            *(float4*)&cP[ty * 4 + i][tx * 4] = np;
            *(float4*)&cB[ty * 4 + i][tx * 4] = nbb;
            if (s == GS - 1) {
                const size_t gbase = ((size_t)bh * GG + g) * 4096;
                *(float4*)&Pg[gbase + (size_t)(ty * 4 + i) * 64 + tx * 4] = np;
                *(float4*)&Bg[gbase + (size_t)(ty * 4 + i) * 64 + tx * 4] = nbb;
            }
        }
    }
}

// ---------------------------------------------------------------------------
// scanG: sequential over 8 groups per bh; writes group-entry states
// S_all[bh][g*GS].  grid (BH)
// ---------------------------------------------------------------------------
__global__ __launch_bounds__(256) void scanG(const float* __restrict__ Pg,
                                             const float* __restrict__ Bg,
                                             float* __restrict__ Sall) {
    __shared__ float Ss[64][68];
    __shared__ float nPt[64][68];
    __shared__ float nB[64][68];
    const int bh = blockIdx.x;
    const int tid = threadIdx.x;
    const int tx = tid & 15, ty = tid >> 4;
#pragma unroll
    for (int p = 0; p < 16; ++p) {
        int f = p * 256 + tid;
        Ss[f >> 6][f & 63] = 0.f;
    }
    for (int g = 0; g < GG; ++g) {
        __syncthreads();
        const size_t sbase = ((size_t)bh * NC + (size_t)g * GS) * 4096;
#pragma unroll
        for (int p = 0; p < 4; ++p) {
            int flat = p * 1024 + tid * 4;
            *(float4*)&Sall[sbase + flat] = *(const float4*)&Ss[flat >> 6][flat & 63];
        }
        if (g == GG - 1) break;
        const size_t gbase = ((size_t)bh * GG + g) * 4096;
#pragma unroll
        for (int p = 0; p < 4; ++p) {
            int flat = p * 1024 + tid * 4;
            int r = flat >> 6, col = flat & 63;
            float4 pv = *(const float4*)&Pg[gbase + flat];
            nPt[col + 0][r] = pv.x; nPt[col + 1][r] = pv.y;
            nPt[col + 2][r] = pv.z; nPt[col + 3][r] = pv.w;
            *(float4*)&nB[r][col] = *(const float4*)&Bg[gbase + flat];
        }
        __syncthreads();
        float aS[4][4] = {};
        for (int k = 0; k < 64; ++k) {
            float4 a = *(const float4*)&nPt[k][ty * 4];
            float4 b = *(const float4*)&Ss[k][tx * 4];
#pragma unroll
            for (int i = 0; i < 4; ++i) {
                float av = ((const float*)&a)[i];
                aS[i][0] += av * b.x; aS[i][1] += av * b.y; aS[i][2] += av * b.z; aS[i][3] += av * b.w;
            }
        }
        __syncthreads();
#pragma unroll
        for (int i = 0; i < 4; ++i) {
            float4 nb = *(const float4*)&nB[ty * 4 + i][tx * 4];
            *(float4*)&Ss[ty * 4 + i][tx * 4] =
                make_float4(aS[i][0] + nb.x, aS[i][1] + nb.y, aS[i][2] + nb.z, aS[i][3] + nb.w);
        }
    }
}

// ---------------------------------------------------------------------------
// rollout: within each group, fill chunk-entry states.  grid (GG, BH)
// ---------------------------------------------------------------------------
__global__ __launch_bounds__(256) void rolloutK(const float* __restrict__ Pall,
                                                const float* __restrict__ Ball,
                                                float* __restrict__ Sall) {
    __shared__ float Ss[64][68];
    __shared__ float nPt[64][68];
    __shared__ float nB[64][68];
    const int g = blockIdx.x, bh = blockIdx.y;
    const int tid = threadIdx.x;
    const int tx = tid & 15, ty = tid >> 4;
    const int c0 = g * GS;
    const size_t base0 = ((size_t)bh * NC + c0) * 4096;
#pragma unroll
    for (int p = 0; p < 4; ++p) {
        int flat = p * 1024 + tid * 4;
        *(float4*)&Ss[(flat >> 6)][flat & 63] = *(const float4*)&Sall[base0 + flat];
    }
    for (int j = 1; j < GS; ++j) {
        __syncthreads();
        const size_t pbase = base0 + (size_t)(j - 1) * 4096;
#pragma unroll
        for (int p = 0; p < 4; ++p) {
            int flat = p * 1024 + tid * 4;
            int r = flat >> 6, col = flat & 63;
            float4 pv = *(const float4*)&Pall[pbase + flat];
            nPt[col + 0][r] = pv.x; nPt[col + 1][r] = pv.y;
            nPt[col + 2][r] = pv.z; nPt[col + 3][r] = pv.w;
            *(float4*)&nB[r][col] = *(const float4*)&Ball[pbase + flat];
        }
        __syncthreads();
        float aS[4][4] = {};
        for (int k = 0; k < 64; ++k) {
            float4 a = *(const float4*)&nPt[k][ty * 4];
            float4 b = *(const float4*)&Ss[k][tx * 4];
#pragma unroll
            for (int i = 0; i < 4; ++i) {
                float av = ((const float*)&a)[i];
                aS[i][0] += av * b.x; aS[i][1] += av * b.y; aS[i][2] += av * b.z; aS[i][3] += av * b.w;
            }
        }
        __syncthreads();
        const size_t sbase = base0 + (size_t)j * 4096;
#pragma unroll
        for (int i = 0; i < 4; ++i) {
            float4 nb = *(const float4*)&nB[ty * 4 + i][tx * 4];
            float4 sv = make_float4(aS[i][0] + nb.x, aS[i][1] + nb.y,
                                    aS[i][2] + nb.z, aS[i][3] + nb.w);
            *(float4*)&Ss[ty * 4 + i][tx * 4] = sv;
            *(float4*)&Sall[sbase + (size_t)(ty * 4 + i) * 64 + tx * 4] = sv;
        }
    }
}

// ---------------------------------------------------------------------------
// phaseO: Delta = U - W S ; O = Q S + M Delta ; fused RMSNorm + bf16 cast.
// grid (NC, BH), fully parallel.
// ---------------------------------------------------------------------------
__global__ __launch_bounds__(256) void phaseO(const float* __restrict__ Wg,
                                              const float* __restrict__ Ug,
                                              const float* __restrict__ Mg,
                                              const float* __restrict__ qg,
                                              const float* __restrict__ Sall,
                                              const float* __restrict__ nw,
                                              unsigned short* __restrict__ ob) {
    __shared__ float T0[64][68];    // W^T, then Delta (row-major)
    __shared__ float QtT[64][68];
    __shared__ float MtT[64][68];
    __shared__ float Ss[64][68];
    const int c = blockIdx.x, bh = blockIdx.y;
    const int b = bh >> 4, h = bh & 15;
    const int tid = threadIdx.x;
    const int tx = tid & 15, ty = tid >> 4;
    const size_t tbase = ((size_t)bh * NC + c) * 4096;
    const size_t qkbase = ((size_t)bh * LL + (size_t)c * 64) * 64;
#pragma unroll
    for (int p = 0; p < 4; ++p) {
        int flat = p * 1024 + tid * 4;
        int r = flat >> 6, col = flat & 63;
        float4 wv = *(const float4*)&Wg[tbase + flat];
        T0[col + 0][r] = wv.x; T0[col + 1][r] = wv.y; T0[col + 2][r] = wv.z; T0[col + 3][r] = wv.w;
        float4 qv = *(const float4*)&qg[qkbase + flat];
        QtT[col + 0][r] = qv.x; QtT[col + 1][r] = qv.y; QtT[col + 2][r] = qv.z; QtT[col + 3][r] = qv.w;
        float4 mv = *(const float4*)&Mg[tbase + flat];
        MtT[col + 0][r] = mv.x; MtT[col + 1][r] = mv.y; MtT[col + 2][r] = mv.z; MtT[col + 3][r] = mv.w;
        *(float4*)&Ss[r][col] = *(const float4*)&Sall[tbase + flat];
    }
    __syncthreads();
    // Delta = U - W*S  (T0 holds W^T)
    float aD[4][4] = {};
    for (int k = 0; k < 64; ++k) {
        float4 a = *(const float4*)&T0[k][ty * 4];
        float4 b4 = *(const float4*)&Ss[k][tx * 4];
#pragma unroll
        for (int i = 0; i < 4; ++i) {
            float av = ((const float*)&a)[i];
            aD[i][0] += av * b4.x; aD[i][1] += av * b4.y; aD[i][2] += av * b4.z; aD[i][3] += av * b4.w;
        }
    }
    __syncthreads();
#pragma unroll
    for (int i = 0; i < 4; ++i) {
        float4 u4 = *(const float4*)&Ug[tbase + (size_t)(ty * 4 + i) * 64 + tx * 4];
        *(float4*)&T0[ty * 4 + i][tx * 4] =
            make_float4(u4.x - aD[i][0], u4.y - aD[i][1], u4.z - aD[i][2], u4.w - aD[i][3]);
    }
    __syncthreads();
    // O = Q*S + M*Delta   (T0 now holds Delta row-major)
    float aO[4][4] = {};
    for (int k = 0; k < 64; ++k) {
        float4 aq = *(const float4*)&QtT[k][ty * 4];
        float4 am = *(const float4*)&MtT[k][ty * 4];
        float4 s4 = *(const float4*)&Ss[k][tx * 4];
        float4 d4 = *(const float4*)&T0[k][tx * 4];
#pragma unroll
        for (int i = 0; i < 4; ++i) {
            float qv = ((const float*)&aq)[i];
            float mv = ((const float*)&am)[i];
            aO[i][0] += qv * s4.x + mv * d4.x;
            aO[i][1] += qv * s4.y + mv * d4.y;
            aO[i][2] += qv * s4.z + mv * d4.z;
            aO[i][3] += qv * s4.w + mv * d4.w;
        }
    }
    // fused per-head RMSNorm + bf16 cast
    const float4 nwv = *(const float4*)&nw[tx * 4];
#pragma unroll
    for (int i = 0; i < 4; ++i) {
        float ss = aO[i][0] * aO[i][0] + aO[i][1] * aO[i][1]
                 + aO[i][2] * aO[i][2] + aO[i][3] * aO[i][3];
        ss += __shfl_xor(ss, 1);
        ss += __shfl_xor(ss, 2);
        ss += __shfl_xor(ss, 4);
        ss += __shfl_xor(ss, 8);
        float rms = rsqrtf(ss * (1.f / 64.f) + 1e-5f);
        unsigned short o0 = f2bf(aO[i][0] * rms * nwv.x);
        unsigned short o1 = f2bf(aO[i][1] * rms * nwv.y);
        unsigned short o2 = f2bf(aO[i][2] * rms * nwv.z);
        unsigned short o3 = f2bf(aO[i][3] * rms * nwv.w);
        uint2 wv;
        wv.x = (unsigned)o0 | ((unsigned)o1 << 16);
        wv.y = (unsigned)o2 | ((unsigned)o3 << 16);
        size_t row = (size_t)b * LL + (size_t)c * 64 + ty * 4 + i;
        *(uint2*)&ob[row * DD + h * 64 + tx * 4] = wv;
    }
}

// ---------------------------------------------------------------------------
extern "C" void kernel_launch(void* const* d_in, const int* in_sizes, int n_in,
                              void* d_out, int out_size, void* d_ws, size_t ws_size,
                              hipStream_t stream) {
    const float* x  = (const float*)d_in[0];
    const float* Wq = (const float*)d_in[1];
    const float* Wk = (const float*)d_in[2];
    const float* Wv = (const float*)d_in[3];
    const float* Wb = (const float*)d_in[4];
    const float* cq = (const float*)d_in[5];
    const float* ck = (const float*)d_in[6];
    const float* cv = (const float*)d_in[7];
    const float* nw = (const float*)d_in[8];
    const float* Wo = (const float*)d_in[9];
    float* out = (float*)d_out;
    float* ws = (float*)d_ws;

    const size_t SZ = (size_t)BB * LL * DD;   // 8388608
    float* xq   = ws;            // -> Wg
    float* xk   = ws + SZ;       // -> Ug
    float* xv   = ws + 2 * SZ;   // -> Mg
    float* q    = ws + 3 * SZ;   // xb first, then q
    float* k    = ws + 4 * SZ;   // -> S_all
    float* v    = ws + 5 * SZ;   // -> B_all -> ob
    float* beta = ws + 6 * SZ;                       // 131072 floats
    unsigned short* wqT = (unsigned short*)(beta + (size_t)BH * LL);  // 4M shorts
    float* Pall = (float*)(wqT) + 2097152;           // SZ floats
    float* PgB  = Pall + SZ;                         // 1M floats
    float* BgB  = PgB + 1048576;                     // 1M floats

    unsigned short* xb = (unsigned short*)q;
    unsigned short* ob = (unsigned short*)v;
    unsigned short* woT = wqT + (size_t)3 * 1048576;
    float* Wg = xq;
    float* Ug = xk;
    float* Mg = xv;
    float* Ball = v;
    float* Sall = k;

    dim3 blk(256);
    dim3 gt(32, 32);

    cast_bf16_k<<<dim3(4096), blk, 0, stream>>>(x, xb);
    transW_k<<<gt, blk, 0, stream>>>(Wq, wqT);
    transW_k<<<gt, blk, 0, stream>>>(Wk, wqT + 1048576);
    transW_k<<<gt, blk, 0, stream>>>(Wv, wqT + 2097152);
    transW_k<<<gt, blk, 0, stream>>>(Wo, woT);
    gemm_qkv<<<dim3(24, 64), blk, 0, stream>>>(xb, wqT, xq);
    beta_k<<<dim3(512), blk, 0, stream>>>(x, Wb, beta);
    conv_silu<1><<<dim3(LL, BB), blk, 0, stream>>>(xq, cq, q);
    conv_silu<1><<<dim3(LL, BB), blk, 0, stream>>>(xk, ck, k);
    conv_silu<0><<<dim3(LL, BB), blk, 0, stream>>>(xv, cv, v);
    phaseA<<<dim3(NC, BH), blk, 0, stream>>>(k, v, beta, Wg, Ug);
    qkT_M<<<dim3(NC, BH), blk, 0, stream>>>(q, k, Mg);
    phaseS1<<<dim3(NC, BH), blk, 0, stream>>>(k, Wg, Ug, Pall, Ball);
    composeK<<<dim3(GG, BH), blk, 0, stream>>>(Pall, Ball, PgB, BgB);
    scanG<<<dim3(BH), blk, 0, stream>>>(PgB, BgB, Sall);
    rolloutK<<<dim3(GG, BH), blk, 0, stream>>>(Pall, Ball, Sall);
    phaseO<<<dim3(NC, BH), blk, 0, stream>>>(Wg, Ug, Mg, q, Sall, nw, ob);
    gemm_bf16<<<dim3(8, 64), blk, 0, stream>>>(ob, woT, out);
}

// Round 4
// 486.282 us; speedup vs baseline: 3.9310x; 1.2937x over previous
//
#include <hip/hip_runtime.h>
#include <hip/hip_bf16.h>
#include <math.h>

#define BB 2
#define LL 4096
#define DD 1024
#define HH 16
#define HDIM 64
#define CC 64
#define NC 64   // LL/CC
#define BH 32   // BB*HH
#define GG 8    // chunk groups
#define GS 8    // chunks per group

typedef __attribute__((ext_vector_type(8))) short short8;
typedef __attribute__((ext_vector_type(4))) float f32x4;

__device__ __forceinline__ unsigned short f2bf(float f) {
    unsigned int u = __float_as_uint(f);
    unsigned int r = (u + 0x7fffu + ((u >> 16) & 1u)) >> 16;
    return (unsigned short)r;
}

__device__ __forceinline__ void gld_lds16(const void* g, void* l) {
    __builtin_amdgcn_global_load_lds(
        (const __attribute__((address_space(1))) void*)g,
        (__attribute__((address_space(3))) void*)l, 16, 0, 0);
}

// swizzled float index into a [64][64] tile: 16B chunk XOR'd with (row>>2).
// Gram-style reads (16 different rows at same col-chunk) become conflict-free.
__device__ __forceinline__ int swz(int r, int c) {
    return (r << 6) + ((((c >> 2) ^ (r >> 2)) & 15) << 2) + (c & 3);
}

// ---------------------------------------------------------------------------
// fp32 -> bf16 cast
// ---------------------------------------------------------------------------
__global__ __launch_bounds__(256) void cast_bf16_k(const float* __restrict__ in,
                                                   unsigned short* __restrict__ out) {
    int i = (blockIdx.x * 256 + threadIdx.x) * 8;
    float4 a = *(const float4*)&in[i];
    float4 b = *(const float4*)&in[i + 4];
    uint4 o;
    o.x = (unsigned)f2bf(a.x) | ((unsigned)f2bf(a.y) << 16);
    o.y = (unsigned)f2bf(a.z) | ((unsigned)f2bf(a.w) << 16);
    o.z = (unsigned)f2bf(b.x) | ((unsigned)f2bf(b.y) << 16);
    o.w = (unsigned)f2bf(b.z) | ((unsigned)f2bf(b.w) << 16);
    *(uint4*)&out[i] = o;
}

// ---------------------------------------------------------------------------
// W [K][N] fp32 -> WT [N][K] bf16
// ---------------------------------------------------------------------------
__global__ __launch_bounds__(256) void transW_k(const float* __restrict__ W,
                                                unsigned short* __restrict__ WT) {
    __shared__ float t[32][33];
    const int bx = blockIdx.x * 32, by = blockIdx.y * 32;
#pragma unroll
    for (int p = 0; p < 4; ++p) {
        int idx = p * 256 + threadIdx.x;
        int r = idx >> 5, cc = idx & 31;
        t[r][cc] = W[(size_t)(by + r) * 1024 + bx + cc];
    }
    __syncthreads();
#pragma unroll
    for (int p = 0; p < 4; ++p) {
        int idx = p * 256 + threadIdx.x;
        int r = idx >> 5, cc = idx & 31;
        WT[(size_t)(bx + r) * 1024 + by + cc] = f2bf(t[cc][r]);
    }
}

// ---------------------------------------------------------------------------
// bf16 MFMA GEMM body (m97 structure)
// ---------------------------------------------------------------------------
__device__ __forceinline__ void gemm_body(const unsigned short* A,
                                          const unsigned short* BT,
                                          float* C, int m0, int n0) {
    __shared__ __align__(16) short As[128 * 32];
    __shared__ __align__(16) short Bs[128 * 32];
    const int tid = threadIdx.x;
    const int lane = tid & 63, w = tid >> 6;
    const int wr = w >> 1, wc = w & 1;
    const int ln15 = lane & 15, kg8 = (lane >> 4) * 8;
    f32x4 acc[4][4] = {};
    const int erow = tid >> 2;
    const int ecol = (tid & 3) * 8;
    for (int k0 = 0; k0 < 1024; k0 += 32) {
#pragma unroll
        for (int r = 0; r < 2; ++r) {
            gld_lds16(A  + (size_t)(m0 + erow + r * 64) * 1024 + k0 + ecol,
                      (short*)As + r * 2048 + tid * 8);
            gld_lds16(BT + (size_t)(n0 + erow + r * 64) * 1024 + k0 + ecol,
                      (short*)Bs + r * 2048 + tid * 8);
        }
        __syncthreads();
        short8 af[4], bf[4];
#pragma unroll
        for (int i = 0; i < 4; ++i)
            af[i] = *(const short8*)&As[(wr * 64 + i * 16 + ln15) * 32 + kg8];
#pragma unroll
        for (int j = 0; j < 4; ++j)
            bf[j] = *(const short8*)&Bs[(wc * 64 + j * 16 + ln15) * 32 + kg8];
#pragma unroll
        for (int i = 0; i < 4; ++i)
#pragma unroll
            for (int j = 0; j < 4; ++j)
                acc[i][j] = __builtin_amdgcn_mfma_f32_16x16x32_bf16(af[i], bf[j], acc[i][j], 0, 0, 0);
        __syncthreads();
    }
    const int crow0 = m0 + wr * 64 + (lane >> 4) * 4;
    const int ccol0 = n0 + wc * 64 + ln15;
#pragma unroll
    for (int i = 0; i < 4; ++i)
#pragma unroll
        for (int j = 0; j < 4; ++j)
#pragma unroll
            for (int r = 0; r < 4; ++r)
                C[(size_t)(crow0 + i * 16 + r) * 1024 + ccol0 + j * 16] = acc[i][j][r];
}

__global__ __launch_bounds__(256) void gemm_bf16(const unsigned short* __restrict__ A,
                                                 const unsigned short* __restrict__ BT,
                                                 float* __restrict__ C) {
    gemm_body(A, BT, C, blockIdx.y * 128, blockIdx.x * 128);
}

__global__ __launch_bounds__(256) void gemm_qkv(const unsigned short* __restrict__ A,
                                                const unsigned short* __restrict__ WT0,
                                                float* __restrict__ C0) {
    const int which = blockIdx.x >> 3;
    const int n0 = (blockIdx.x & 7) * 128;
    const unsigned short* BT = WT0 + (size_t)which * 1048576;
    float* C = C0 + (size_t)which * ((size_t)BB * LL * DD);
    gemm_body(A, BT, C, blockIdx.y * 128, n0);
}

// ---------------------------------------------------------------------------
// beta = sigmoid(x @ Wb) stored [B,H,L]
// ---------------------------------------------------------------------------
__global__ __launch_bounds__(256) void beta_k(const float* __restrict__ X,
                                              const float* __restrict__ Wb,
                                              float* __restrict__ beta) {
    int idx = blockIdx.x * 256 + threadIdx.x;
    int row = idx >> 4, h = idx & 15;
    const float* xr = X + (size_t)row * DD;
    float s = 0.f;
    for (int k4 = 0; k4 < DD; k4 += 4) {
        float4 xv = *(const float4*)&xr[k4];
        s += xv.x * Wb[(k4 + 0) * HH + h];
        s += xv.y * Wb[(k4 + 1) * HH + h];
        s += xv.z * Wb[(k4 + 2) * HH + h];
        s += xv.w * Wb[(k4 + 3) * HH + h];
    }
    float bv = 1.f / (1.f + expf(-s));
    int b = row >> 12, l = row & (LL - 1);
    beta[((size_t)b * HH + h) * LL + l] = bv;
}

// ---------------------------------------------------------------------------
// conv v2: 16 tokens per block, sliding register window (4.75x less re-read)
// in [B,L,D] -> out [B,H,L,HD]
// ---------------------------------------------------------------------------
template <int NORM>
__global__ __launch_bounds__(256) void conv_silu2(const float* __restrict__ X,
                                                  const float* __restrict__ cw,
                                                  float* __restrict__ out) {
    const int l0 = blockIdx.x * 16, b = blockIdx.y;
    const int tid = threadIdx.x;
    const int d0 = tid * 4;
    const float4 w0 = *(const float4*)&cw[(d0 + 0) * 4];
    const float4 w1 = *(const float4*)&cw[(d0 + 1) * 4];
    const float4 w2 = *(const float4*)&cw[(d0 + 2) * 4];
    const float4 w3 = *(const float4*)&cw[(d0 + 3) * 4];
    const float* Xb = X + (size_t)b * LL * DD;
    float4 xm3 = make_float4(0, 0, 0, 0), xm2 = xm3, xm1 = xm3;
    if (l0 > 0) {
        xm3 = *(const float4*)&Xb[(size_t)(l0 - 3) * DD + d0];
        xm2 = *(const float4*)&Xb[(size_t)(l0 - 2) * DD + d0];
        xm1 = *(const float4*)&Xb[(size_t)(l0 - 1) * DD + d0];
    }
    const int h = d0 >> 6, hd = d0 & 63;
#pragma unroll
    for (int t = 0; t < 16; ++t) {
        const int l = l0 + t;
        float4 xc = *(const float4*)&Xb[(size_t)l * DD + d0];
        float a0 = xm3.x * w0.x + xm2.x * w0.y + xm1.x * w0.z + xc.x * w0.w;
        float a1 = xm3.y * w1.x + xm2.y * w1.y + xm1.y * w1.z + xc.y * w1.w;
        float a2 = xm3.z * w2.x + xm2.z * w2.y + xm1.z * w2.z + xc.z * w2.w;
        float a3 = xm3.w * w3.x + xm2.w * w3.y + xm1.w * w3.z + xc.w * w3.w;
        a0 = a0 / (1.f + expf(-a0));
        a1 = a1 / (1.f + expf(-a1));
        a2 = a2 / (1.f + expf(-a2));
        a3 = a3 / (1.f + expf(-a3));
        if (NORM) {
            float s = a0 * a0 + a1 * a1 + a2 * a2 + a3 * a3;
            s += __shfl_xor(s, 1);
            s += __shfl_xor(s, 2);
            s += __shfl_xor(s, 4);
            s += __shfl_xor(s, 8);
            float sc = rsqrtf(s);
            a0 *= sc; a1 *= sc; a2 *= sc; a3 *= sc;
        }
        *(float4*)&out[(((size_t)b * HH + h) * LL + l) * 64 + hd] =
            make_float4(a0, a1, a2, a3);
        xm3 = xm2; xm2 = xm1; xm1 = xc;
    }
}

// ---------------------------------------------------------------------------
// Phase A v2 (absorbs phaseS1):
//   A = strict_tril(diag(beta) K K^T)        [swizzled-K Gram, conflict-free]
//   solve (I+A)[W|U] = [bK|bV]               [blocked substitution, 16-panels]
//   P = I - K^T W ; Bc = K^T U               [outer-product, row-major]
// ---------------------------------------------------------------------------
__global__ __launch_bounds__(256) void phaseA2(const float* __restrict__ kg,
                                               const float* __restrict__ vg,
                                               const float* __restrict__ betag,
                                               float* __restrict__ Wg,
                                               float* __restrict__ Ug,
                                               float* __restrict__ Pall,
                                               float* __restrict__ Ball) {
    __shared__ float Kt[4096];        // swizzled
    __shared__ float At[64][64];      // strict lower A, row-major
    __shared__ float WU[64][128];
    __shared__ float betas[64];
    const int c = blockIdx.x, bh = blockIdx.y;
    const int tid = threadIdx.x;
    const int tx = tid & 15, ty = tid >> 4;
    const size_t base = ((size_t)bh * LL + (size_t)c * 64) * 64;
#pragma unroll
    for (int p = 0; p < 4; ++p) {
        int flat = p * 1024 + tid * 4;
        int r = flat >> 6, col = flat & 63;
        *(float4*)&Kt[swz(r, col)] = *(const float4*)&kg[base + flat];
    }
    if (tid < 64) betas[tid] = betag[(size_t)bh * LL + (size_t)c * 64 + tid];
    __syncthreads();
    // RHS: WU[t][j] = beta_t * (j<64 ? K[t][j] : V[t][j-64])
#pragma unroll
    for (int p = 0; p < 8; ++p) {
        int flat = p * 1024 + tid * 4;
        int t = flat >> 7, j = flat & 127;
        float4 src;
        if (j < 64) src = *(const float4*)&Kt[swz(t, j)];
        else        src = *(const float4*)&vg[base + (size_t)t * 64 + (j - 64)];
        float bt = betas[t];
        src.x *= bt; src.y *= bt; src.z *= bt; src.w *= bt;
        *(float4*)&WU[t][j] = src;
    }
    // A = strict_tril(beta * K K^T)  (dot-Gram over x, swizzled b-reads)
    {
        float acc[4][4] = {};
        for (int x0 = 0; x0 < 64; x0 += 4) {
            float4 a[4], b[4];
#pragma unroll
            for (int i = 0; i < 4; ++i) a[i] = *(const float4*)&Kt[swz(ty * 4 + i, x0)];
#pragma unroll
            for (int j = 0; j < 4; ++j) b[j] = *(const float4*)&Kt[swz(tx * 4 + j, x0)];
#pragma unroll
            for (int i = 0; i < 4; ++i)
#pragma unroll
                for (int j = 0; j < 4; ++j)
                    acc[i][j] += a[i].x * b[j].x + a[i].y * b[j].y
                               + a[i].z * b[j].z + a[i].w * b[j].w;
        }
#pragma unroll
        for (int i = 0; i < 4; ++i) {
            int t = ty * 4 + i;
            float bt = betas[t];
            float4 w;
            w.x = (tx * 4 + 0 < t) ? bt * acc[i][0] : 0.f;
            w.y = (tx * 4 + 1 < t) ? bt * acc[i][1] : 0.f;
            w.z = (tx * 4 + 2 < t) ? bt * acc[i][2] : 0.f;
            w.w = (tx * 4 + 3 < t) ? bt * acc[i][3] : 0.f;
            *(float4*)&At[t][tx * 4] = w;
        }
    }
    __syncthreads();
    // blocked forward substitution, panels of 16
#pragma unroll
    for (int pb = 0; pb < 4; ++pb) {
        const int r0 = pb * 16;
        if (pb > 0) {
            const int col = tid & 127;
            const int rbase = r0 + (tid >> 7) * 8;
            float acc[8] = {};
            for (int r = 0; r < r0; r += 4) {
                float u0 = WU[r + 0][col], u1 = WU[r + 1][col];
                float u2 = WU[r + 2][col], u3 = WU[r + 3][col];
#pragma unroll
                for (int i = 0; i < 8; ++i) {
                    float4 a4 = *(const float4*)&At[rbase + i][r];
                    acc[i] += a4.x * u0 + a4.y * u1 + a4.z * u2 + a4.w * u3;
                }
            }
#pragma unroll
            for (int i = 0; i < 8; ++i) WU[rbase + i][col] -= acc[i];
            __syncthreads();
        }
        if (tid < 128) {
            const int col = tid;
            float w[16];
            w[0] = WU[r0][col];
#pragma unroll
            for (int t = 1; t < 16; ++t) {
                float a = WU[r0 + t][col];
#pragma unroll
                for (int r = 0; r < t; ++r) a -= At[r0 + t][r0 + r] * w[r];
                w[t] = a;
            }
#pragma unroll
            for (int t = 1; t < 16; ++t) WU[r0 + t][col] = w[t];
        }
        __syncthreads();
    }
    // write W, U
    const size_t obase = ((size_t)bh * NC + c) * 4096;
#pragma unroll
    for (int p = 0; p < 8; ++p) {
        int flat = p * 1024 + tid * 4;
        int t = flat >> 7, j = flat & 127;
        float4 v4 = *(const float4*)&WU[t][j];
        if (j < 64) *(float4*)&Wg[obase + (size_t)t * 64 + j] = v4;
        else        *(float4*)&Ug[obase + (size_t)t * 64 + (j - 64)] = v4;
    }
    // P = I - K^T W ; B = K^T U  (outer-product over t, all row-major)
    {
        float aP[4][4] = {}, aB[4][4] = {};
        for (int t = 0; t < 64; ++t) {
            float4 a = *(const float4*)&Kt[swz(t, ty * 4)];
            float4 bw = *(const float4*)&WU[t][tx * 4];
            float4 bu = *(const float4*)&WU[t][64 + tx * 4];
#pragma unroll
            for (int i = 0; i < 4; ++i) {
                float av = ((const float*)&a)[i];
                aP[i][0] += av * bw.x; aP[i][1] += av * bw.y;
                aP[i][2] += av * bw.z; aP[i][3] += av * bw.w;
                aB[i][0] += av * bu.x; aB[i][1] += av * bu.y;
                aB[i][2] += av * bu.z; aB[i][3] += av * bu.w;
            }
        }
#pragma unroll
        for (int i = 0; i < 4; ++i) {
            int d = ty * 4 + i;
            float4 pv;
            pv.x = ((d == tx * 4 + 0) ? 1.f : 0.f) - aP[i][0];
            pv.y = ((d == tx * 4 + 1) ? 1.f : 0.f) - aP[i][1];
            pv.z = ((d == tx * 4 + 2) ? 1.f : 0.f) - aP[i][2];
            pv.w = ((d == tx * 4 + 3) ? 1.f : 0.f) - aP[i][3];
            *(float4*)&Pall[obase + (size_t)d * 64 + tx * 4] = pv;
            *(float4*)&Ball[obase + (size_t)d * 64 + tx * 4] =
                make_float4(aB[i][0], aB[i][1], aB[i][2], aB[i][3]);
        }
    }
}

// ---------------------------------------------------------------------------
// compose: per group of 8 chunks, composed affine map. grid (GG, BH)
// ---------------------------------------------------------------------------
__global__ __launch_bounds__(256) void composeK2(const float* __restrict__ Pall,
                                                 const float* __restrict__ Ball,
                                                 float* __restrict__ Pg,
                                                 float* __restrict__ Bg) {
    __shared__ float cP[4096], cB[4096], nP[4096], nB[4096];
    const int g = blockIdx.x, bh = blockIdx.y;
    const int tid = threadIdx.x;
    const int tx4 = (tid & 15) * 4, ty4 = (tid >> 4) * 4;
    const size_t base0 = ((size_t)bh * NC + (size_t)g * GS) * 4096;
#pragma unroll
    for (int p = 0; p < 4; ++p) {
        int flat = p * 1024 + tid * 4;
        *(float4*)&cP[flat] = *(const float4*)&Pall[base0 + flat];
        *(float4*)&cB[flat] = *(const float4*)&Ball[base0 + flat];
    }
    for (int s = 1; s < GS; ++s) {
#pragma unroll
        for (int p = 0; p < 4; ++p) {
            int flat = p * 1024 + tid * 4;
            *(float4*)&nP[flat] = *(const float4*)&Pall[base0 + (size_t)s * 4096 + flat];
            *(float4*)&nB[flat] = *(const float4*)&Ball[base0 + (size_t)s * 4096 + flat];
        }
        __syncthreads();
        float aP[4][4] = {}, aB[4][4] = {};
        for (int k0 = 0; k0 < 64; k0 += 4) {
            float4 a[4], bp[4], bb[4];
#pragma unroll
            for (int i = 0; i < 4; ++i) a[i] = *(const float4*)&nP[(ty4 + i) * 64 + k0];
#pragma unroll
            for (int m = 0; m < 4; ++m) {
                bp[m] = *(const float4*)&cP[(k0 + m) * 64 + tx4];
                bb[m] = *(const float4*)&cB[(k0 + m) * 64 + tx4];
            }
#pragma unroll
            for (int i = 0; i < 4; ++i) {
                const float* af = (const float*)&a[i];
#pragma unroll
                for (int m = 0; m < 4; ++m) {
                    float av = af[m];
                    const float* pf = (const float*)&bp[m];
                    const float* bf = (const float*)&bb[m];
                    aP[i][0] += av * pf[0]; aP[i][1] += av * pf[1];
                    aP[i][2] += av * pf[2]; aP[i][3] += av * pf[3];
                    aB[i][0] += av * bf[0]; aB[i][1] += av * bf[1];
                    aB[i][2] += av * bf[2]; aB[i][3] += av * bf[3];
                }
            }
        }
        __syncthreads();
#pragma unroll
        for (int i = 0; i < 4; ++i) {
            float4 nb = *(const float4*)&nB[(ty4 + i) * 64 + tx4];
            float4 np = make_float4(aP[i][0], aP[i][1], aP[i][2], aP[i][3]);
            float4 nbb = make_float4(aB[i][0] + nb.x, aB[i][1] + nb.y,
                                     aB[i][2] + nb.z, aB[i][3] + nb.w);
            *(float4*)&cP[(ty4 + i) * 64 + tx4] = np;
            *(float4*)&cB[(ty4 + i) * 64 + tx4] = nbb;
            if (s == GS - 1) {
                const size_t gbase = ((size_t)bh * GG + g) * 4096;
                *(float4*)&Pg[gbase + (size_t)(ty4 + i) * 64 + tx4] = np;
                *(float4*)&Bg[gbase + (size_t)(ty4 + i) * 64 + tx4] = nbb;
            }
        }
        __syncthreads();
    }
}

// ---------------------------------------------------------------------------
// scanG: sequential over 8 groups; writes group-entry states. grid (BH)
// ---------------------------------------------------------------------------
__global__ __launch_bounds__(256) void scanG2(const float* __restrict__ Pg,
                                              const float* __restrict__ Bg,
                                              float* __restrict__ Sall) {
    __shared__ float Ss[4096], nP[4096], nB[4096];
    const int bh = blockIdx.x;
    const int tid = threadIdx.x;
    const int tx4 = (tid & 15) * 4, ty4 = (tid >> 4) * 4;
#pragma unroll
    for (int p = 0; p < 4; ++p) {
        int flat = p * 1024 + tid * 4;
        *(float4*)&Ss[flat] = make_float4(0, 0, 0, 0);
    }
    __syncthreads();
    for (int g = 0; g < GG; ++g) {
        const size_t sbase = ((size_t)bh * NC + (size_t)g * GS) * 4096;
#pragma unroll
        for (int p = 0; p < 4; ++p) {
            int flat = p * 1024 + tid * 4;
            *(float4*)&Sall[sbase + flat] = *(const float4*)&Ss[flat];
        }
        if (g == GG - 1) break;
        const size_t gbase = ((size_t)bh * GG + g) * 4096;
#pragma unroll
        for (int p = 0; p < 4; ++p) {
            int flat = p * 1024 + tid * 4;
            *(float4*)&nP[flat] = *(const float4*)&Pg[gbase + flat];
            *(float4*)&nB[flat] = *(const float4*)&Bg[gbase + flat];
        }
        __syncthreads();
        float aS[4][4] = {};
        for (int k0 = 0; k0 < 64; k0 += 4) {
            float4 a[4], bm[4];
#pragma unroll
            for (int i = 0; i < 4; ++i) a[i] = *(const float4*)&nP[(ty4 + i) * 64 + k0];
#pragma unroll
            for (int m = 0; m < 4; ++m) bm[m] = *(const float4*)&Ss[(k0 + m) * 64 + tx4];
#pragma unroll
            for (int i = 0; i < 4; ++i) {
                const float* af = (const float*)&a[i];
#pragma unroll
                for (int m = 0; m < 4; ++m) {
                    float av = af[m];
                    const float* bf = (const float*)&bm[m];
                    aS[i][0] += av * bf[0]; aS[i][1] += av * bf[1];
                    aS[i][2] += av * bf[2]; aS[i][3] += av * bf[3];
                }
            }
        }
        __syncthreads();
#pragma unroll
        for (int i = 0; i < 4; ++i) {
            float4 nb = *(const float4*)&nB[(ty4 + i) * 64 + tx4];
            *(float4*)&Ss[(ty4 + i) * 64 + tx4] =
                make_float4(aS[i][0] + nb.x, aS[i][1] + nb.y,
                            aS[i][2] + nb.z, aS[i][3] + nb.w);
        }
        __syncthreads();
    }
}

// ---------------------------------------------------------------------------
// rollout: fill chunk-entry states within each group. grid (GG, BH)
// ---------------------------------------------------------------------------
__global__ __launch_bounds__(256) void rolloutK2(const float* __restrict__ Pall,
                                                 const float* __restrict__ Ball,
                                                 float* __restrict__ Sall) {
    __shared__ float Ss[4096], nP[4096], nB[4096];
    const int g = blockIdx.x, bh = blockIdx.y;
    const int tid = threadIdx.x;
    const int tx4 = (tid & 15) * 4, ty4 = (tid >> 4) * 4;
    const size_t base0 = ((size_t)bh * NC + (size_t)g * GS) * 4096;
#pragma unroll
    for (int p = 0; p < 4; ++p) {
        int flat = p * 1024 + tid * 4;
        *(float4*)&Ss[flat] = *(const float4*)&Sall[base0 + flat];
    }
    for (int j = 1; j < GS; ++j) {
        const size_t pbase = base0 + (size_t)(j - 1) * 4096;
#pragma unroll
        for (int p = 0; p < 4; ++p) {
            int flat = p * 1024 + tid * 4;
            *(float4*)&nP[flat] = *(const float4*)&Pall[pbase + flat];
            *(float4*)&nB[flat] = *(const float4*)&Ball[pbase + flat];
        }
        __syncthreads();
        float aS[4][4] = {};
        for (int k0 = 0; k0 < 64; k0 += 4) {
            float4 a[4], bm[4];
#pragma unroll
            for (int i = 0; i < 4; ++i) a[i] = *(const float4*)&nP[(ty4 + i) * 64 + k0];
#pragma unroll
            for (int m = 0; m < 4; ++m) bm[m] = *(const float4*)&Ss[(k0 + m) * 64 + tx4];
#pragma unroll
            for (int i = 0; i < 4; ++i) {
                const float* af = (const float*)&a[i];
#pragma unroll
                for (int m = 0; m < 4; ++m) {
                    float av = af[m];
                    const float* bf = (const float*)&bm[m];
                    aS[i][0] += av * bf[0]; aS[i][1] += av * bf[1];
                    aS[i][2] += av * bf[2]; aS[i][3] += av * bf[3];
                }
            }
        }
        __syncthreads();
        const size_t sbase = base0 + (size_t)j * 4096;
#pragma unroll
        for (int i = 0; i < 4; ++i) {
            float4 nb = *(const float4*)&nB[(ty4 + i) * 64 + tx4];
            float4 sv = make_float4(aS[i][0] + nb.x, aS[i][1] + nb.y,
                                    aS[i][2] + nb.z, aS[i][3] + nb.w);
            *(float4*)&Ss[(ty4 + i) * 64 + tx4] = sv;
            *(float4*)&Sall[sbase + (size_t)(ty4 + i) * 64 + tx4] = sv;
        }
        __syncthreads();
    }
}

// ---------------------------------------------------------------------------
// phaseO v2 (absorbs qkT_M): M = causal(QK^T); Delta = U - W S;
// O = Q S + M Delta; fused RMSNorm + bf16 cast.  grid (NC, BH).
// LDS: 5 x 16KB slots = 81920 B.
// ---------------------------------------------------------------------------
__global__ __launch_bounds__(256) void phaseO2(const float* __restrict__ Wg,
                                               const float* __restrict__ Ug,
                                               const float* __restrict__ qg,
                                               const float* __restrict__ kg,
                                               const float* __restrict__ Sall,
                                               const float* __restrict__ nw,
                                               unsigned short* __restrict__ ob) {
    __shared__ float KD[4096];   // K swizzled, later Delta (plain)
    __shared__ float Qt[4096];
    __shared__ float Wt[4096];
    __shared__ float Ss[4096];
    __shared__ float Mt[4096];
    const int c = blockIdx.x, bh = blockIdx.y;
    const int b = bh >> 4, h = bh & 15;
    const int tid = threadIdx.x;
    const int tx = tid & 15, ty = tid >> 4;
    const int tx4 = tx * 4, ty4 = ty * 4;
    const size_t tbase = ((size_t)bh * NC + c) * 4096;
    const size_t qkbase = ((size_t)bh * LL + (size_t)c * 64) * 64;
#pragma unroll
    for (int p = 0; p < 4; ++p) {
        int flat = p * 1024 + tid * 4;
        int r = flat >> 6, col = flat & 63;
        *(float4*)&KD[swz(r, col)] = *(const float4*)&kg[qkbase + flat];
        *(float4*)&Qt[flat] = *(const float4*)&qg[qkbase + flat];
        *(float4*)&Wt[flat] = *(const float4*)&Wg[tbase + flat];
        *(float4*)&Ss[flat] = *(const float4*)&Sall[tbase + flat];
    }
    __syncthreads();
    // M = causal(Q K^T)  (dot over x; swizzled K b-reads)
    {
        float acc[4][4] = {};
        for (int x0 = 0; x0 < 64; x0 += 4) {
            float4 a[4], bq[4];
#pragma unroll
            for (int i = 0; i < 4; ++i) a[i] = *(const float4*)&Qt[(ty4 + i) * 64 + x0];
#pragma unroll
            for (int j = 0; j < 4; ++j) bq[j] = *(const float4*)&KD[swz(tx4 + j, x0)];
#pragma unroll
            for (int i = 0; i < 4; ++i)
#pragma unroll
                for (int j = 0; j < 4; ++j)
                    acc[i][j] += a[i].x * bq[j].x + a[i].y * bq[j].y
                               + a[i].z * bq[j].z + a[i].w * bq[j].w;
        }
#pragma unroll
        for (int i = 0; i < 4; ++i) {
            int t = ty4 + i;
            float4 w;
            w.x = (tx4 + 0 <= t) ? acc[i][0] : 0.f;
            w.y = (tx4 + 1 <= t) ? acc[i][1] : 0.f;
            w.z = (tx4 + 2 <= t) ? acc[i][2] : 0.f;
            w.w = (tx4 + 3 <= t) ? acc[i][3] : 0.f;
            *(float4*)&Mt[t * 64 + tx4] = w;
        }
    }
    __syncthreads();   // all K reads done; KD may be overwritten with Delta
    // Delta = U - W*S
    {
        float aD[4][4] = {};
        for (int k0 = 0; k0 < 64; k0 += 4) {
            float4 a[4], bm[4];
#pragma unroll
            for (int i = 0; i < 4; ++i) a[i] = *(const float4*)&Wt[(ty4 + i) * 64 + k0];
#pragma unroll
            for (int m = 0; m < 4; ++m) bm[m] = *(const float4*)&Ss[(k0 + m) * 64 + tx4];
#pragma unroll
            for (int i = 0; i < 4; ++i) {
                const float* af = (const float*)&a[i];
#pragma unroll
                for (int m = 0; m < 4; ++m) {
                    float av = af[m];
                    const float* bf = (const float*)&bm[m];
                    aD[i][0] += av * bf[0]; aD[i][1] += av * bf[1];
                    aD[i][2] += av * bf[2]; aD[i][3] += av * bf[3];
                }
            }
        }
#pragma unroll
        for (int i = 0; i < 4; ++i) {
            float4 u4 = *(const float4*)&Ug[tbase + (size_t)(ty4 + i) * 64 + tx4];
            *(float4*)&KD[(ty4 + i) * 64 + tx4] =
                make_float4(u4.x - aD[i][0], u4.y - aD[i][1],
                            u4.z - aD[i][2], u4.w - aD[i][3]);
        }
    }
    __syncthreads();
    // O = Q*S + M*Delta
    float aO[4][4] = {};
    for (int k0 = 0; k0 < 64; k0 += 4) {
        float4 aq[4], am[4], sm[4], dm[4];
#pragma unroll
        for (int i = 0; i < 4; ++i) {
            aq[i] = *(const float4*)&Qt[(ty4 + i) * 64 + k0];
            am[i] = *(const float4*)&Mt[(ty4 + i) * 64 + k0];
        }
#pragma unroll
        for (int m = 0; m < 4; ++m) {
            sm[m] = *(const float4*)&Ss[(k0 + m) * 64 + tx4];
            dm[m] = *(const float4*)&KD[(k0 + m) * 64 + tx4];
        }
#pragma unroll
        for (int i = 0; i < 4; ++i) {
            const float* qf = (const float*)&aq[i];
            const float* mf = (const float*)&am[i];
#pragma unroll
            for (int m = 0; m < 4; ++m) {
                float qv = qf[m], mv = mf[m];
                const float* sf = (const float*)&sm[m];
                const float* df = (const float*)&dm[m];
                aO[i][0] += qv * sf[0] + mv * df[0];
                aO[i][1] += qv * sf[1] + mv * df[1];
                aO[i][2] += qv * sf[2] + mv * df[2];
                aO[i][3] += qv * sf[3] + mv * df[3];
            }
        }
    }
    // fused per-head RMSNorm + bf16 cast
    const float4 nwv = *(const float4*)&nw[tx4];
#pragma unroll
    for (int i = 0; i < 4; ++i) {
        float ss = aO[i][0] * aO[i][0] + aO[i][1] * aO[i][1]
                 + aO[i][2] * aO[i][2] + aO[i][3] * aO[i][3];
        ss += __shfl_xor(ss, 1);
        ss += __shfl_xor(ss, 2);
        ss += __shfl_xor(ss, 4);
        ss += __shfl_xor(ss, 8);
        float rms = rsqrtf(ss * (1.f / 64.f) + 1e-5f);
        unsigned short o0 = f2bf(aO[i][0] * rms * nwv.x);
        unsigned short o1 = f2bf(aO[i][1] * rms * nwv.y);
        unsigned short o2 = f2bf(aO[i][2] * rms * nwv.z);
        unsigned short o3 = f2bf(aO[i][3] * rms * nwv.w);
        uint2 wv;
        wv.x = (unsigned)o0 | ((unsigned)o1 << 16);
        wv.y = (unsigned)o2 | ((unsigned)o3 << 16);
        size_t row = (size_t)b * LL + (size_t)c * 64 + ty4 + i;
        *(uint2*)&ob[row * DD + h * 64 + tx4] = wv;
    }
}

// ---------------------------------------------------------------------------
extern "C" void kernel_launch(void* const* d_in, const int* in_sizes, int n_in,
                              void* d_out, int out_size, void* d_ws, size_t ws_size,
                              hipStream_t stream) {
    const float* x  = (const float*)d_in[0];
    const float* Wq = (const float*)d_in[1];
    const float* Wk = (const float*)d_in[2];
    const float* Wv = (const float*)d_in[3];
    const float* Wb = (const float*)d_in[4];
    const float* cq = (const float*)d_in[5];
    const float* ck = (const float*)d_in[6];
    const float* cv = (const float*)d_in[7];
    const float* nw = (const float*)d_in[8];
    const float* Wo = (const float*)d_in[9];
    float* out = (float*)d_out;
    float* ws = (float*)d_ws;

    const size_t SZ = (size_t)BB * LL * DD;   // 8388608
    float* xq   = ws;            // -> Wg
    float* xk   = ws + SZ;       // -> Ug
    float* xv   = ws + 2 * SZ;   // -> Pall
    float* q    = ws + 3 * SZ;   // xb first, then q
    float* k    = ws + 4 * SZ;
    float* v    = ws + 5 * SZ;   // -> ob
    float* beta = ws + 6 * SZ;                       // 131072 floats
    unsigned short* wqT = (unsigned short*)(beta + (size_t)BH * LL);  // 4M shorts
    float* Sall = (float*)wqT + 2097152;             // SZ floats
    float* PgB  = Sall + SZ;                         // 1M floats
    float* BgB  = PgB + 1048576;                     // 1M floats

    unsigned short* xb = (unsigned short*)q;
    unsigned short* ob = (unsigned short*)v;
    unsigned short* woT = wqT + (size_t)3 * 1048576;
    float* Wg = xq;
    float* Ug = xk;
    float* Pall = xv;
    float* Ball = out;   // d_out used as scratch; fully overwritten by final GEMM

    dim3 blk(256);
    dim3 gt(32, 32);

    cast_bf16_k<<<dim3(4096), blk, 0, stream>>>(x, xb);
    transW_k<<<gt, blk, 0, stream>>>(Wq, wqT);
    transW_k<<<gt, blk, 0, stream>>>(Wk, wqT + 1048576);
    transW_k<<<gt, blk, 0, stream>>>(Wv, wqT + 2097152);
    transW_k<<<gt, blk, 0, stream>>>(Wo, woT);
    gemm_qkv<<<dim3(24, 64), blk, 0, stream>>>(xb, wqT, xq);
    beta_k<<<dim3(512), blk, 0, stream>>>(x, Wb, beta);
    conv_silu2<1><<<dim3(LL / 16, BB), blk, 0, stream>>>(xq, cq, q);
    conv_silu2<1><<<dim3(LL / 16, BB), blk, 0, stream>>>(xk, ck, k);
    conv_silu2<0><<<dim3(LL / 16, BB), blk, 0, stream>>>(xv, cv, v);
    phaseA2<<<dim3(NC, BH), blk, 0, stream>>>(k, v, beta, Wg, Ug, Pall, Ball);
    composeK2<<<dim3(GG, BH), blk, 0, stream>>>(Pall, Ball, PgB, BgB);
    scanG2<<<dim3(BH), blk, 0, stream>>>(PgB, BgB, Sall);
    rolloutK2<<<dim3(GG, BH), blk, 0, stream>>>(Pall, Ball, Sall);
    phaseO2<<<dim3(NC, BH), blk, 0, stream>>>(Wg, Ug, q, k, Sall, nw, ob);
    gemm_bf16<<<dim3(8, 64), blk, 0, stream>>>(ob, woT, out);
}

// Round 5
// 422.694 us; speedup vs baseline: 4.5224x; 1.1504x over previous
//
#include <hip/hip_runtime.h>
#include <hip/hip_bf16.h>
#include <math.h>

#define BB 2
#define LL 4096
#define DD 1024
#define HH 16
#define HDIM 64
#define CC 64
#define NC 64   // LL/CC
#define BH 32   // BB*HH
#define GG 8    // chunk groups
#define GS 8    // chunks per group

typedef __attribute__((ext_vector_type(8))) short short8;
typedef __attribute__((ext_vector_type(4))) float f32x4;
typedef unsigned short u16;

__device__ __forceinline__ u16 f2bf(float f) {
    unsigned int u = __float_as_uint(f);
    unsigned int r = (u + 0x7fffu + ((u >> 16) & 1u)) >> 16;
    return (u16)r;
}
__device__ __forceinline__ float bf2f(u16 h) {
    return __uint_as_float((unsigned)h << 16);
}
__device__ __forceinline__ void split2(float x, u16& h, u16& l) {
    h = f2bf(x);
    l = f2bf(x - bf2f(h));
}

__device__ __forceinline__ void gld_lds16(const void* g, void* l) {
    __builtin_amdgcn_global_load_lds(
        (const __attribute__((address_space(1))) void*)g,
        (__attribute__((address_space(3))) void*)l, 16, 0, 0);
}

// fp32 [64][64] tile swizzle (4-elem chunks XOR'd by row>>2) — column reads conflict-free
__device__ __forceinline__ int swz(int r, int c) {
    return (r << 6) + ((((c >> 2) ^ (r >> 2)) & 15) << 2) + (c & 3);
}
// bf16 [64][64] tile swizzle (8-elem chunks XOR'd by row&7) — 16-row b128 reads 2-way (free)
__device__ __forceinline__ int swze(int r, int c) {
    return (r << 6) + (c ^ ((r & 7) << 3));
}

// ---------------------------------------------------------------------------
// mm64: acc[4] (C rows w*16..w*16+16, all 64 cols) += A(64x64) x B(64x64)
// A stored hi/lo bf16 LDS row-major-swizzled; B given as BT (row=out-col, k contig).
// split precision: Ah*Bh + Ah*Bl + Al*Bh  (fp32-class accuracy)
// ---------------------------------------------------------------------------
__device__ __forceinline__ void mm64(const u16* __restrict__ Ah, const u16* __restrict__ Al,
                                     const u16* __restrict__ Bh, const u16* __restrict__ Bl,
                                     f32x4* acc, int w, int lane) {
    const int ln = lane & 15, kg = (lane >> 4) * 8;
#pragma unroll
    for (int kb = 0; kb < 2; ++kb) {
        const int k0 = kb * 32 + kg;
        short8 ah = *(const short8*)&Ah[swze(w * 16 + ln, k0)];
        short8 al = *(const short8*)&Al[swze(w * 16 + ln, k0)];
#pragma unroll
        for (int j = 0; j < 4; ++j) {
            short8 bh = *(const short8*)&Bh[swze(j * 16 + ln, k0)];
            short8 bl = *(const short8*)&Bl[swze(j * 16 + ln, k0)];
            acc[j] = __builtin_amdgcn_mfma_f32_16x16x32_bf16(ah, bh, acc[j], 0, 0, 0);
            acc[j] = __builtin_amdgcn_mfma_f32_16x16x32_bf16(ah, bl, acc[j], 0, 0, 0);
            acc[j] = __builtin_amdgcn_mfma_f32_16x16x32_bf16(al, bh, acc[j], 0, 0, 0);
        }
    }
}

// global fp32 [64][64] -> hi/lo bf16 LDS (A-layout, swizzled)
__device__ __forceinline__ void g_to_ls(const float* __restrict__ G, u16* Ah, u16* Al, int tid) {
#pragma unroll
    for (int p = 0; p < 4; ++p) {
        int flat = p * 1024 + tid * 4;
        int r = flat >> 6, c = flat & 63;
        float4 v = *(const float4*)&G[flat];
        u16 h0, l0, h1, l1, h2, l2, h3, l3;
        split2(v.x, h0, l0); split2(v.y, h1, l1);
        split2(v.z, h2, l2); split2(v.w, h3, l3);
        int idx = swze(r, c);
        uint2 hv, lv;
        hv.x = (unsigned)h0 | ((unsigned)h1 << 16); hv.y = (unsigned)h2 | ((unsigned)h3 << 16);
        lv.x = (unsigned)l0 | ((unsigned)l1 << 16); lv.y = (unsigned)l2 | ((unsigned)l3 << 16);
        *(uint2*)&Ah[idx] = hv;
        *(uint2*)&Al[idx] = lv;
    }
}

// register frag -> hi/lo bf16 LDS (A-layout)
__device__ __forceinline__ void frag_to_ls(const f32x4* acc, u16* Ah, u16* Al, int w, int lane) {
    const int g = lane >> 4, ln = lane & 15;
#pragma unroll
    for (int j = 0; j < 4; ++j)
#pragma unroll
        for (int r = 0; r < 4; ++r) {
            int row = w * 16 + g * 4 + r, col = j * 16 + ln;
            u16 h, l; split2(acc[j][r], h, l);
            Ah[swze(row, col)] = h;
            Al[swze(row, col)] = l;
        }
}

// frag-aligned global fp32 read / add / write
__device__ __forceinline__ void g_to_frag(const float* __restrict__ G, f32x4* acc, int w, int lane) {
    const int g = lane >> 4, ln = lane & 15;
#pragma unroll
    for (int j = 0; j < 4; ++j)
#pragma unroll
        for (int r = 0; r < 4; ++r)
            acc[j][r] = G[(w * 16 + g * 4 + r) * 64 + j * 16 + ln];
}
__device__ __forceinline__ void g_add_frag(const float* __restrict__ G, f32x4* acc, int w, int lane) {
    const int g = lane >> 4, ln = lane & 15;
#pragma unroll
    for (int j = 0; j < 4; ++j)
#pragma unroll
        for (int r = 0; r < 4; ++r)
            acc[j][r] += G[(w * 16 + g * 4 + r) * 64 + j * 16 + ln];
}
__device__ __forceinline__ void frag_to_g(const f32x4* acc, float* __restrict__ G, int w, int lane) {
    const int g = lane >> 4, ln = lane & 15;
#pragma unroll
    for (int j = 0; j < 4; ++j)
#pragma unroll
        for (int r = 0; r < 4; ++r)
            G[(w * 16 + g * 4 + r) * 64 + j * 16 + ln] = acc[j][r];
}

// ---------------------------------------------------------------------------
// fp32 -> bf16 cast
// ---------------------------------------------------------------------------
__global__ __launch_bounds__(256) void cast_bf16_k(const float* __restrict__ in,
                                                   u16* __restrict__ out) {
    int i = (blockIdx.x * 256 + threadIdx.x) * 8;
    float4 a = *(const float4*)&in[i];
    float4 b = *(const float4*)&in[i + 4];
    uint4 o;
    o.x = (unsigned)f2bf(a.x) | ((unsigned)f2bf(a.y) << 16);
    o.y = (unsigned)f2bf(a.z) | ((unsigned)f2bf(a.w) << 16);
    o.z = (unsigned)f2bf(b.x) | ((unsigned)f2bf(b.y) << 16);
    o.w = (unsigned)f2bf(b.z) | ((unsigned)f2bf(b.w) << 16);
    *(uint4*)&out[i] = o;
}

// ---------------------------------------------------------------------------
// W [K][N] fp32 -> WT [N][K] bf16
// ---------------------------------------------------------------------------
__global__ __launch_bounds__(256) void transW_k(const float* __restrict__ W,
                                                u16* __restrict__ WT) {
    __shared__ float t[32][33];
    const int bx = blockIdx.x * 32, by = blockIdx.y * 32;
#pragma unroll
    for (int p = 0; p < 4; ++p) {
        int idx = p * 256 + threadIdx.x;
        int r = idx >> 5, cc = idx & 31;
        t[r][cc] = W[(size_t)(by + r) * 1024 + bx + cc];
    }
    __syncthreads();
#pragma unroll
    for (int p = 0; p < 4; ++p) {
        int idx = p * 256 + threadIdx.x;
        int r = idx >> 5, cc = idx & 31;
        WT[(size_t)(bx + r) * 1024 + by + cc] = f2bf(t[cc][r]);
    }
}

// ---------------------------------------------------------------------------
// bf16 MFMA GEMM body (m97 structure)
// ---------------------------------------------------------------------------
__device__ __forceinline__ void gemm_body(const u16* A, const u16* BT,
                                          float* C, int m0, int n0) {
    __shared__ __align__(16) short As[128 * 32];
    __shared__ __align__(16) short Bs[128 * 32];
    const int tid = threadIdx.x;
    const int lane = tid & 63, w = tid >> 6;
    const int wr = w >> 1, wc = w & 1;
    const int ln15 = lane & 15, kg8 = (lane >> 4) * 8;
    f32x4 acc[4][4] = {};
    const int erow = tid >> 2;
    const int ecol = (tid & 3) * 8;
    for (int k0 = 0; k0 < 1024; k0 += 32) {
#pragma unroll
        for (int r = 0; r < 2; ++r) {
            gld_lds16(A  + (size_t)(m0 + erow + r * 64) * 1024 + k0 + ecol,
                      (short*)As + r * 2048 + tid * 8);
            gld_lds16(BT + (size_t)(n0 + erow + r * 64) * 1024 + k0 + ecol,
                      (short*)Bs + r * 2048 + tid * 8);
        }
        __syncthreads();
        short8 af[4], bf[4];
#pragma unroll
        for (int i = 0; i < 4; ++i)
            af[i] = *(const short8*)&As[(wr * 64 + i * 16 + ln15) * 32 + kg8];
#pragma unroll
        for (int j = 0; j < 4; ++j)
            bf[j] = *(const short8*)&Bs[(wc * 64 + j * 16 + ln15) * 32 + kg8];
#pragma unroll
        for (int i = 0; i < 4; ++i)
#pragma unroll
            for (int j = 0; j < 4; ++j)
                acc[i][j] = __builtin_amdgcn_mfma_f32_16x16x32_bf16(af[i], bf[j], acc[i][j], 0, 0, 0);
        __syncthreads();
    }
    const int crow0 = m0 + wr * 64 + (lane >> 4) * 4;
    const int ccol0 = n0 + wc * 64 + ln15;
#pragma unroll
    for (int i = 0; i < 4; ++i)
#pragma unroll
        for (int j = 0; j < 4; ++j)
#pragma unroll
            for (int r = 0; r < 4; ++r)
                C[(size_t)(crow0 + i * 16 + r) * 1024 + ccol0 + j * 16] = acc[i][j][r];
}

__global__ __launch_bounds__(256) void gemm_bf16(const u16* __restrict__ A,
                                                 const u16* __restrict__ BT,
                                                 float* __restrict__ C) {
    gemm_body(A, BT, C, blockIdx.y * 128, blockIdx.x * 128);
}

__global__ __launch_bounds__(256) void gemm_qkv(const u16* __restrict__ A,
                                                const u16* __restrict__ WT0,
                                                float* __restrict__ C0) {
    const int which = blockIdx.x >> 3;
    const int n0 = (blockIdx.x & 7) * 128;
    const u16* BT = WT0 + (size_t)which * 1048576;
    float* C = C0 + (size_t)which * ((size_t)BB * LL * DD);
    gemm_body(A, BT, C, blockIdx.y * 128, n0);
}

// ---------------------------------------------------------------------------
// beta = sigmoid(x @ Wb) stored [B,H,L]
// ---------------------------------------------------------------------------
__global__ __launch_bounds__(256) void beta_k(const float* __restrict__ X,
                                              const float* __restrict__ Wb,
                                              float* __restrict__ beta) {
    int idx = blockIdx.x * 256 + threadIdx.x;
    int row = idx >> 4, h = idx & 15;
    const float* xr = X + (size_t)row * DD;
    float s = 0.f;
    for (int k4 = 0; k4 < DD; k4 += 4) {
        float4 xv = *(const float4*)&xr[k4];
        s += xv.x * Wb[(k4 + 0) * HH + h];
        s += xv.y * Wb[(k4 + 1) * HH + h];
        s += xv.z * Wb[(k4 + 2) * HH + h];
        s += xv.w * Wb[(k4 + 3) * HH + h];
    }
    float bv = 1.f / (1.f + expf(-s));
    int b = row >> 12, l = row & (LL - 1);
    beta[((size_t)b * HH + h) * LL + l] = bv;
}

// ---------------------------------------------------------------------------
// conv: 16 tokens per block, sliding register window
// ---------------------------------------------------------------------------
template <int NORM>
__global__ __launch_bounds__(256) void conv_silu2(const float* __restrict__ X,
                                                  const float* __restrict__ cw,
                                                  float* __restrict__ out) {
    const int l0 = blockIdx.x * 16, b = blockIdx.y;
    const int tid = threadIdx.x;
    const int d0 = tid * 4;
    const float4 w0 = *(const float4*)&cw[(d0 + 0) * 4];
    const float4 w1 = *(const float4*)&cw[(d0 + 1) * 4];
    const float4 w2 = *(const float4*)&cw[(d0 + 2) * 4];
    const float4 w3 = *(const float4*)&cw[(d0 + 3) * 4];
    const float* Xb = X + (size_t)b * LL * DD;
    float4 xm3 = make_float4(0, 0, 0, 0), xm2 = xm3, xm1 = xm3;
    if (l0 > 0) {
        xm3 = *(const float4*)&Xb[(size_t)(l0 - 3) * DD + d0];
        xm2 = *(const float4*)&Xb[(size_t)(l0 - 2) * DD + d0];
        xm1 = *(const float4*)&Xb[(size_t)(l0 - 1) * DD + d0];
    }
    const int h = d0 >> 6, hd = d0 & 63;
#pragma unroll
    for (int t = 0; t < 16; ++t) {
        const int l = l0 + t;
        float4 xc = *(const float4*)&Xb[(size_t)l * DD + d0];
        float a0 = xm3.x * w0.x + xm2.x * w0.y + xm1.x * w0.z + xc.x * w0.w;
        float a1 = xm3.y * w1.x + xm2.y * w1.y + xm1.y * w1.z + xc.y * w1.w;
        float a2 = xm3.z * w2.x + xm2.z * w2.y + xm1.z * w2.z + xc.z * w2.w;
        float a3 = xm3.w * w3.x + xm2.w * w3.y + xm1.w * w3.z + xc.w * w3.w;
        a0 = a0 / (1.f + expf(-a0));
        a1 = a1 / (1.f + expf(-a1));
        a2 = a2 / (1.f + expf(-a2));
        a3 = a3 / (1.f + expf(-a3));
        if (NORM) {
            float s = a0 * a0 + a1 * a1 + a2 * a2 + a3 * a3;
            s += __shfl_xor(s, 1);
            s += __shfl_xor(s, 2);
            s += __shfl_xor(s, 4);
            s += __shfl_xor(s, 8);
            float sc = rsqrtf(s);
            a0 *= sc; a1 *= sc; a2 *= sc; a3 *= sc;
        }
        *(float4*)&out[(((size_t)b * HH + h) * LL + l) * 64 + hd] =
            make_float4(a0, a1, a2, a3);
        xm3 = xm2; xm2 = xm1; xm1 = xc;
    }
}

// ---------------------------------------------------------------------------
// Phase A v3 (MFMA): Gram via MFMA, VALU solve, P/B via MFMA.
// Outputs: Wg (plain), UgT (U^T), Pall (plain), BallT (B^T).
// ---------------------------------------------------------------------------
__global__ __launch_bounds__(256) void phaseA3(const float* __restrict__ kg,
                                               const float* __restrict__ vg,
                                               const float* __restrict__ betag,
                                               float* __restrict__ Wg,
                                               float* __restrict__ UgT,
                                               float* __restrict__ Pall,
                                               float* __restrict__ BallT) {
    __shared__ __align__(16) char pool[81920];
    u16* Kh  = (u16*)pool;              // 8K   (later WTh)
    u16* Kl  = (u16*)(pool + 8192);     //      (later WTl)
    u16* KTh = (u16*)(pool + 16384);
    u16* KTl = (u16*)(pool + 24576);
    float* At = (float*)(pool + 32768); // [64][64]  (later UTh/UTl)
    float* WU = (float*)(pool + 49152); // [64][128] (later scr/scr2)
    u16* WTh = (u16*)pool;
    u16* WTl = (u16*)(pool + 8192);
    u16* UTh = (u16*)(pool + 32768);
    u16* UTl = (u16*)(pool + 40960);
    float* scr = (float*)(pool + 49152);

    const int c = blockIdx.x, bh = blockIdx.y;
    const int tid = threadIdx.x, lane = tid & 63, w = tid >> 6;
    const int g = lane >> 4, ln = lane & 15;
    const size_t base = ((size_t)bh * LL + (size_t)c * 64) * 64;
    const size_t obase = ((size_t)bh * NC + c) * 4096;
    const float* bet = betag + (size_t)bh * LL + (size_t)c * 64;

    // 1. load K -> Kh/Kl (plain) + KTh/KTl (transposed)
#pragma unroll
    for (int p = 0; p < 4; ++p) {
        int flat = p * 1024 + tid * 4;
        int r = flat >> 6, c4 = flat & 63;
        float4 v = *(const float4*)&kg[base + flat];
        u16 h[4], l[4];
        split2(v.x, h[0], l[0]); split2(v.y, h[1], l[1]);
        split2(v.z, h[2], l[2]); split2(v.w, h[3], l[3]);
        int idx = swze(r, c4);
        uint2 hv, lv;
        hv.x = (unsigned)h[0] | ((unsigned)h[1] << 16); hv.y = (unsigned)h[2] | ((unsigned)h[3] << 16);
        lv.x = (unsigned)l[0] | ((unsigned)l[1] << 16); lv.y = (unsigned)l[2] | ((unsigned)l[3] << 16);
        *(uint2*)&Kh[idx] = hv;
        *(uint2*)&Kl[idx] = lv;
#pragma unroll
        for (int e = 0; e < 4; ++e) {
            KTh[swze(c4 + e, r)] = h[e];
            KTl[swze(c4 + e, r)] = l[e];
        }
    }
    __syncthreads();
    // 2. Gram A = strict_tril(beta * K K^T)
    {
        f32x4 acc[4] = {};
        mm64(Kh, Kl, Kh, Kl, acc, w, lane);
#pragma unroll
        for (int r = 0; r < 4; ++r) {
            int t = w * 16 + g * 4 + r;
            float bt = bet[t];
#pragma unroll
            for (int j = 0; j < 4; ++j) {
                int s = j * 16 + ln;
                At[t * 64 + s] = (s < t) ? bt * acc[j][r] : 0.f;
            }
        }
    }
    // 3. RHS: WU[t][j] = beta_t * (j<64 ? K[t][j] : V[t][j-64])
#pragma unroll
    for (int p = 0; p < 8; ++p) {
        int flat = p * 1024 + tid * 4;
        int t = flat >> 7, j = flat & 127;
        float bt = bet[t];
        float4 src;
        if (j < 64) {
            int idx = swze(t, j);
            uint2 hh = *(const uint2*)&Kh[idx];
            uint2 ll2 = *(const uint2*)&Kl[idx];
            src.x = bf2f((u16)hh.x) + bf2f((u16)ll2.x);
            src.y = bf2f((u16)(hh.x >> 16)) + bf2f((u16)(ll2.x >> 16));
            src.z = bf2f((u16)hh.y) + bf2f((u16)ll2.y);
            src.w = bf2f((u16)(hh.y >> 16)) + bf2f((u16)(ll2.y >> 16));
        } else {
            src = *(const float4*)&vg[base + (size_t)t * 64 + (j - 64)];
        }
        src.x *= bt; src.y *= bt; src.z *= bt; src.w *= bt;
        *(float4*)&WU[t * 128 + j] = src;
    }
    __syncthreads();
    // 4. blocked forward substitution (panels of 16)
#pragma unroll
    for (int pb = 0; pb < 4; ++pb) {
        const int r0 = pb * 16;
        if (pb > 0) {
            const int col = tid & 127;
            const int rbase = r0 + (tid >> 7) * 8;
            float acc8[8] = {};
            for (int r = 0; r < r0; r += 4) {
                float u0 = WU[(r + 0) * 128 + col], u1 = WU[(r + 1) * 128 + col];
                float u2 = WU[(r + 2) * 128 + col], u3 = WU[(r + 3) * 128 + col];
#pragma unroll
                for (int i = 0; i < 8; ++i) {
                    float4 a4 = *(const float4*)&At[(rbase + i) * 64 + r];
                    acc8[i] += a4.x * u0 + a4.y * u1 + a4.z * u2 + a4.w * u3;
                }
            }
#pragma unroll
            for (int i = 0; i < 8; ++i) WU[(rbase + i) * 128 + col] -= acc8[i];
            __syncthreads();
        }
        if (tid < 128) {
            const int col = tid;
            float wv[16];
            wv[0] = WU[r0 * 128 + col];
#pragma unroll
            for (int t = 1; t < 16; ++t) {
                float a = WU[(r0 + t) * 128 + col];
#pragma unroll
                for (int r = 0; r < t; ++r) a -= At[(r0 + t) * 64 + r0 + r] * wv[r];
                wv[t] = a;
            }
#pragma unroll
            for (int t = 1; t < 16; ++t) WU[(r0 + t) * 128 + col] = wv[t];
        }
        __syncthreads();
    }
    // 5. write Wg; convert W->WTh/WTl (Kh space), U->UTh/UTl (At space)
#pragma unroll
    for (int p = 0; p < 8; ++p) {
        int flat = p * 1024 + tid * 4;
        int t = flat >> 7, j = flat & 127;
        float4 v4 = *(const float4*)&WU[t * 128 + j];
        u16 h[4], l[4];
        split2(v4.x, h[0], l[0]); split2(v4.y, h[1], l[1]);
        split2(v4.z, h[2], l[2]); split2(v4.w, h[3], l[3]);
        if (j < 64) {
            *(float4*)&Wg[obase + (size_t)t * 64 + j] = v4;
#pragma unroll
            for (int e = 0; e < 4; ++e) { WTh[swze(j + e, t)] = h[e]; WTl[swze(j + e, t)] = l[e]; }
        } else {
            int n = j - 64;
#pragma unroll
            for (int e = 0; e < 4; ++e) { UTh[swze(n + e, t)] = h[e]; UTl[swze(n + e, t)] = l[e]; }
        }
    }
    __syncthreads();
    // 6. UgT (coalesced, reconstructed from UT buffers)
#pragma unroll
    for (int p = 0; p < 4; ++p) {
        int flat = p * 1024 + tid * 4;
        int n = flat >> 6, t0 = flat & 63;
        int idx = swze(n, t0);
        uint2 hh = *(const uint2*)&UTh[idx];
        uint2 ll2 = *(const uint2*)&UTl[idx];
        float4 o;
        o.x = bf2f((u16)hh.x) + bf2f((u16)ll2.x);
        o.y = bf2f((u16)(hh.x >> 16)) + bf2f((u16)(ll2.x >> 16));
        o.z = bf2f((u16)hh.y) + bf2f((u16)ll2.y);
        o.w = bf2f((u16)(hh.y >> 16)) + bf2f((u16)(ll2.y >> 16));
        *(float4*)&UgT[obase + flat] = o;
    }
    // 7. P = I - K^T W ; B = K^T U   (MFMA)
    f32x4 aP[4] = {}, aB[4] = {};
    mm64(KTh, KTl, WTh, WTl, aP, w, lane);
    mm64(KTh, KTl, UTh, UTl, aB, w, lane);
#pragma unroll
    for (int j = 0; j < 4; ++j)
#pragma unroll
        for (int r = 0; r < 4; ++r) {
            int row = w * 16 + g * 4 + r, col = j * 16 + ln;
            float pv = ((row == col) ? 1.f : 0.f) - aP[j][r];
            Pall[obase + (size_t)row * 64 + col] = pv;
            scr[swz(row, col)] = aB[j][r];
        }
    __syncthreads();
    // 8. BallT (coalesced via swizzled transpose)
#pragma unroll
    for (int p = 0; p < 4; ++p) {
        int flat = p * 1024 + tid * 4;
        int n = flat >> 6, d0 = flat & 63;
        float4 o;
        o.x = scr[swz(d0 + 0, n)];
        o.y = scr[swz(d0 + 1, n)];
        o.z = scr[swz(d0 + 2, n)];
        o.w = scr[swz(d0 + 3, n)];
        *(float4*)&BallT[obase + flat] = o;
    }
}

// ---------------------------------------------------------------------------
// compose3 (MFMA): per group of 8 chunks, composed affine map (transposed state).
// Outputs: Pg (plain), BgT.
// ---------------------------------------------------------------------------
__global__ __launch_bounds__(256) void compose3(const float* __restrict__ Pall,
                                                const float* __restrict__ BallT,
                                                float* __restrict__ Pg,
                                                float* __restrict__ BgT) {
    __shared__ __align__(16) char pool[81920];
    u16* Ph = (u16*)pool;
    u16* Pl = (u16*)(pool + 8192);
    u16* Bh = (u16*)(pool + 16384);
    u16* Bl = (u16*)(pool + 24576);
    u16* nh = (u16*)(pool + 32768);
    u16* nl = (u16*)(pool + 40960);
    float* scr = (float*)(pool + 49152);
    const int g = blockIdx.x, bh = blockIdx.y;
    const int tid = threadIdx.x, lane = tid & 63, w = tid >> 6;
    const int gi = lane >> 4, ln = lane & 15;
    const size_t base0 = ((size_t)bh * NC + (size_t)g * GS) * 4096;
    f32x4 mP[4], mB[4];
    // init: mB = B^T_{c0} (frag-direct); mP = P^T_{c0} via scr transpose
#pragma unroll
    for (int p = 0; p < 4; ++p) {
        int flat = p * 1024 + tid * 4;
        int r = flat >> 6, c4 = flat & 63;
        *(float4*)&scr[swz(r, c4)] = *(const float4*)&Pall[base0 + flat];
    }
    g_to_frag(BallT + base0, mB, w, lane);
    __syncthreads();
#pragma unroll
    for (int j = 0; j < 4; ++j)
#pragma unroll
        for (int r = 0; r < 4; ++r) {
            int row = w * 16 + gi * 4 + r, col = j * 16 + ln;
            mP[j][r] = scr[swz(col, row)];
        }
    for (int s = 1; s < GS; ++s) {
        __syncthreads();
        frag_to_ls(mP, Ph, Pl, w, lane);
        frag_to_ls(mB, Bh, Bl, w, lane);
        g_to_ls(&Pall[base0 + (size_t)s * 4096], nh, nl, tid);
        __syncthreads();
        f32x4 aP[4] = {}, aB[4] = {};
        mm64(Ph, Pl, nh, nl, aP, w, lane);
        mm64(Bh, Bl, nh, nl, aB, w, lane);
        g_add_frag(&BallT[base0 + (size_t)s * 4096], aB, w, lane);
#pragma unroll
        for (int j = 0; j < 4; ++j) { mP[j] = aP[j]; mB[j] = aB[j]; }
    }
    const size_t gbase = ((size_t)bh * GG + g) * 4096;
    frag_to_g(mB, BgT + gbase, w, lane);
    __syncthreads();
#pragma unroll
    for (int j = 0; j < 4; ++j)
#pragma unroll
        for (int r = 0; r < 4; ++r) {
            int row = w * 16 + gi * 4 + r, col = j * 16 + ln;
            scr[swz(row, col)] = mP[j][r];
        }
    __syncthreads();
#pragma unroll
    for (int p = 0; p < 4; ++p) {
        int flat = p * 1024 + tid * 4;
        int a = flat >> 6, b0 = flat & 63;
        float4 o;
        o.x = scr[swz(b0 + 0, a)];
        o.y = scr[swz(b0 + 1, a)];
        o.z = scr[swz(b0 + 2, a)];
        o.w = scr[swz(b0 + 3, a)];
        *(float4*)&Pg[gbase + flat] = o;   // Pg[a][b] = cPT[b][a]
    }
}

// ---------------------------------------------------------------------------
// scanG3 (MFMA): sequential over 8 groups; writes group-entry states SallT.
// ---------------------------------------------------------------------------
__global__ __launch_bounds__(256) void scanG3(const float* __restrict__ Pg,
                                              const float* __restrict__ BgT,
                                              float* __restrict__ SallT) {
    __shared__ __align__(16) char pool[32768];
    u16* Sh = (u16*)pool;
    u16* Sl = (u16*)(pool + 8192);
    u16* nh = (u16*)(pool + 16384);
    u16* nl = (u16*)(pool + 24576);
    const int bh = blockIdx.x;
    const int tid = threadIdx.x, lane = tid & 63, w = tid >> 6;
    f32x4 mS[4] = {};
    for (int g = 0; g < GG; ++g) {
        const size_t sbase = ((size_t)bh * NC + (size_t)g * GS) * 4096;
        frag_to_g(mS, SallT + sbase, w, lane);
        if (g == GG - 1) break;
        __syncthreads();
        frag_to_ls(mS, Sh, Sl, w, lane);
        g_to_ls(&Pg[((size_t)bh * GG + g) * 4096], nh, nl, tid);
        __syncthreads();
        f32x4 a[4] = {};
        mm64(Sh, Sl, nh, nl, a, w, lane);
        g_add_frag(&BgT[((size_t)bh * GG + g) * 4096], a, w, lane);
#pragma unroll
        for (int j = 0; j < 4; ++j) mS[j] = a[j];
    }
}

// ---------------------------------------------------------------------------
// rollout3 (MFMA): fill chunk-entry states within each group (SallT).
// ---------------------------------------------------------------------------
__global__ __launch_bounds__(256) void rollout3(const float* __restrict__ Pall,
                                                const float* __restrict__ BallT,
                                                float* __restrict__ SallT) {
    __shared__ __align__(16) char pool[32768];
    u16* Sh = (u16*)pool;
    u16* Sl = (u16*)(pool + 8192);
    u16* nh = (u16*)(pool + 16384);
    u16* nl = (u16*)(pool + 24576);
    const int g = blockIdx.x, bh = blockIdx.y;
    const int tid = threadIdx.x, lane = tid & 63, w = tid >> 6;
    const size_t base0 = ((size_t)bh * NC + (size_t)g * GS) * 4096;
    f32x4 mS[4];
    g_to_frag(SallT + base0, mS, w, lane);
    for (int j = 1; j < GS; ++j) {
        __syncthreads();
        frag_to_ls(mS, Sh, Sl, w, lane);
        g_to_ls(&Pall[base0 + (size_t)(j - 1) * 4096], nh, nl, tid);
        __syncthreads();
        f32x4 a[4] = {};
        mm64(Sh, Sl, nh, nl, a, w, lane);
        g_add_frag(&BallT[base0 + (size_t)(j - 1) * 4096], a, w, lane);
#pragma unroll
        for (int jj = 0; jj < 4; ++jj) mS[jj] = a[jj];
        frag_to_g(mS, SallT + base0 + (size_t)j * 4096, w, lane);
    }
}

// ---------------------------------------------------------------------------
// phaseO3 (MFMA): M = causal(QK^T); Delta^T = U^T - S^T W^T;
// O = Q S + M Delta; fused RMSNorm + bf16 cast.
// ---------------------------------------------------------------------------
__global__ __launch_bounds__(256) void phaseO3(const float* __restrict__ Wg,
                                               const float* __restrict__ UgT,
                                               const float* __restrict__ qg,
                                               const float* __restrict__ kg,
                                               const float* __restrict__ SallT,
                                               const float* __restrict__ nw,
                                               u16* __restrict__ ob) {
    __shared__ __align__(16) char pool[65536];
    u16* Qh = (u16*)pool;
    u16* Ql = (u16*)(pool + 8192);
    u16* Kh = (u16*)(pool + 16384);   // later DeltaT hi
    u16* Kl = (u16*)(pool + 24576);   // later DeltaT lo
    u16* Wh = (u16*)(pool + 32768);   // later M hi
    u16* Wl = (u16*)(pool + 40960);   // later M lo
    u16* Sh = (u16*)(pool + 49152);
    u16* Sl = (u16*)(pool + 57344);
    u16* Dh = Kh; u16* Dl = Kl;
    u16* Mh = Wh; u16* Ml = Wl;
    const int c = blockIdx.x, bh = blockIdx.y;
    const int b = bh >> 4, h = bh & 15;
    const int tid = threadIdx.x, lane = tid & 63, w = tid >> 6;
    const int gi = lane >> 4, ln = lane & 15;
    const size_t tbase = ((size_t)bh * NC + c) * 4096;
    const size_t qkbase = ((size_t)bh * LL + (size_t)c * 64) * 64;
    g_to_ls(&qg[qkbase], Qh, Ql, tid);
    g_to_ls(&kg[qkbase], Kh, Kl, tid);
    g_to_ls(&Wg[tbase], Wh, Wl, tid);
    g_to_ls(&SallT[tbase], Sh, Sl, tid);
    __syncthreads();
    f32x4 aM[4] = {}, aD[4] = {};
    mm64(Qh, Ql, Kh, Kl, aM, w, lane);   // Q K^T
    mm64(Sh, Sl, Wh, Wl, aD, w, lane);   // S^T W^T = (W S)^T
    __syncthreads();                     // all K/W reads done
#pragma unroll
    for (int j = 0; j < 4; ++j)
#pragma unroll
        for (int r = 0; r < 4; ++r) {
            int row = w * 16 + gi * 4 + r, col = j * 16 + ln;
            float mv = (col <= row) ? aM[j][r] : 0.f;
            u16 mh_, ml_; split2(mv, mh_, ml_);
            Mh[swze(row, col)] = mh_;
            Ml[swze(row, col)] = ml_;
            float dv = UgT[tbase + (size_t)row * 64 + col] - aD[j][r];
            u16 dh_, dl_; split2(dv, dh_, dl_);
            Dh[swze(row, col)] = dh_;
            Dl[swze(row, col)] = dl_;
        }
    __syncthreads();
    f32x4 aO[4] = {};
    mm64(Qh, Ql, Sh, Sl, aO, w, lane);   // Q S   (B-side = S^T)
    mm64(Mh, Ml, Dh, Dl, aO, w, lane);   // + M Delta (B-side = Delta^T)
    float nwv[4];
#pragma unroll
    for (int j = 0; j < 4; ++j) nwv[j] = nw[j * 16 + ln];
#pragma unroll
    for (int r = 0; r < 4; ++r) {
        float ss = 0.f;
#pragma unroll
        for (int j = 0; j < 4; ++j) ss += aO[j][r] * aO[j][r];
        ss += __shfl_xor(ss, 1);
        ss += __shfl_xor(ss, 2);
        ss += __shfl_xor(ss, 4);
        ss += __shfl_xor(ss, 8);
        float rms = rsqrtf(ss * (1.f / 64.f) + 1e-5f);
        int row = w * 16 + gi * 4 + r;
        size_t orow = ((size_t)b * LL + (size_t)c * 64 + row) * DD + (size_t)h * 64;
#pragma unroll
        for (int j = 0; j < 4; ++j)
            ob[orow + j * 16 + ln] = f2bf(aO[j][r] * rms * nwv[j]);
    }
}

// ---------------------------------------------------------------------------
extern "C" void kernel_launch(void* const* d_in, const int* in_sizes, int n_in,
                              void* d_out, int out_size, void* d_ws, size_t ws_size,
                              hipStream_t stream) {
    const float* x  = (const float*)d_in[0];
    const float* Wq = (const float*)d_in[1];
    const float* Wk = (const float*)d_in[2];
    const float* Wv = (const float*)d_in[3];
    const float* Wb = (const float*)d_in[4];
    const float* cq = (const float*)d_in[5];
    const float* ck = (const float*)d_in[6];
    const float* cv = (const float*)d_in[7];
    const float* nw = (const float*)d_in[8];
    const float* Wo = (const float*)d_in[9];
    float* out = (float*)d_out;
    float* ws = (float*)d_ws;

    const size_t SZ = (size_t)BB * LL * DD;   // 8388608
    float* xq   = ws;            // -> Wg
    float* xk   = ws + SZ;       // -> UgT
    float* xv   = ws + 2 * SZ;   // -> Pall
    float* q    = ws + 3 * SZ;   // xb first, then q
    float* k    = ws + 4 * SZ;
    float* v    = ws + 5 * SZ;   // -> ob
    float* beta = ws + 6 * SZ;                       // 131072 floats
    u16* wqT = (u16*)(beta + (size_t)BH * LL);       // 4M u16
    float* SallT = (float*)wqT + 2097152;            // SZ floats
    float* PgB  = SallT + SZ;                        // 1M floats
    float* BgT  = PgB + 1048576;                     // 1M floats

    u16* xb = (u16*)q;
    u16* ob = (u16*)v;
    u16* woT = wqT + (size_t)3 * 1048576;
    float* Wg = xq;
    float* UgT = xk;
    float* Pall = xv;
    float* BallT = out;   // d_out as scratch; fully overwritten by final GEMM

    dim3 blk(256);
    dim3 gt(32, 32);

    cast_bf16_k<<<dim3(4096), blk, 0, stream>>>(x, xb);
    transW_k<<<gt, blk, 0, stream>>>(Wq, wqT);
    transW_k<<<gt, blk, 0, stream>>>(Wk, wqT + 1048576);
    transW_k<<<gt, blk, 0, stream>>>(Wv, wqT + 2097152);
    transW_k<<<gt, blk, 0, stream>>>(Wo, woT);
    gemm_qkv<<<dim3(24, 64), blk, 0, stream>>>(xb, wqT, xq);
    beta_k<<<dim3(512), blk, 0, stream>>>(x, Wb, beta);
    conv_silu2<1><<<dim3(LL / 16, BB), blk, 0, stream>>>(xq, cq, q);
    conv_silu2<1><<<dim3(LL / 16, BB), blk, 0, stream>>>(xk, ck, k);
    conv_silu2<0><<<dim3(LL / 16, BB), blk, 0, stream>>>(xv, cv, v);
    phaseA3<<<dim3(NC, BH), blk, 0, stream>>>(k, v, beta, Wg, UgT, Pall, BallT);
    compose3<<<dim3(GG, BH), blk, 0, stream>>>(Pall, BallT, PgB, BgT);
    scanG3<<<dim3(BH), blk, 0, stream>>>(PgB, BgT, SallT);
    rollout3<<<dim3(GG, BH), blk, 0, stream>>>(Pall, BallT, SallT);
    phaseO3<<<dim3(NC, BH), blk, 0, stream>>>(Wg, UgT, q, k, SallT, nw, ob);
    gemm_bf16<<<dim3(8, 64), blk, 0, stream>>>(ob, woT, out);
}

// Round 6
// 386.997 us; speedup vs baseline: 4.9396x; 1.0922x over previous
//
#include <hip/hip_runtime.h>
#include <hip/hip_bf16.h>
#include <math.h>

#define BB 2
#define LL 4096
#define DD 1024
#define HH 16
#define HDIM 64
#define CC 64
#define NC 64   // LL/CC
#define BH 32   // BB*HH
#define GG 8    // chunk groups
#define GS 8    // chunks per group

typedef __attribute__((ext_vector_type(8))) short short8;
typedef __attribute__((ext_vector_type(4))) float f32x4;
typedef unsigned short u16;

__device__ __forceinline__ u16 f2bf(float f) {
    unsigned int u = __float_as_uint(f);
    unsigned int r = (u + 0x7fffu + ((u >> 16) & 1u)) >> 16;
    return (u16)r;
}
__device__ __forceinline__ float bf2f(u16 h) {
    return __uint_as_float((unsigned)h << 16);
}
__device__ __forceinline__ void split2(float x, u16& h, u16& l) {
    h = f2bf(x);
    l = f2bf(x - bf2f(h));
}

__device__ __forceinline__ void gld_lds16(const void* g, void* l) {
    __builtin_amdgcn_global_load_lds(
        (const __attribute__((address_space(1))) void*)g,
        (__attribute__((address_space(3))) void*)l, 16, 0, 0);
}

// fp32 [64][64] tile swizzle (4-elem chunks XOR'd by row>>2)
__device__ __forceinline__ int swz(int r, int c) {
    return (r << 6) + ((((c >> 2) ^ (r >> 2)) & 15) << 2) + (c & 3);
}
// bf16 [64][64] tile swizzle. Key (r ^ r>>3)&7 spreads BOTH 16-consecutive-row
// reads AND stride-4-row transposed writes across all 8 16B slots (2-way, free).
__device__ __forceinline__ int swze(int r, int c) {
    return (r << 6) + (c ^ (((r ^ (r >> 3)) & 7) << 3));
}

// ---------------------------------------------------------------------------
// mm64: acc[4] (C rows w*16..+16, all 64 cols) += A(64x64) x B(64x64)^T-stored
// split precision: Ah*Bh + Ah*Bl + Al*Bh
// ---------------------------------------------------------------------------
__device__ __forceinline__ void mm64(const u16* __restrict__ Ah, const u16* __restrict__ Al,
                                     const u16* __restrict__ Bh, const u16* __restrict__ Bl,
                                     f32x4* acc, int w, int lane) {
    const int ln = lane & 15, kg = (lane >> 4) * 8;
#pragma unroll
    for (int kb = 0; kb < 2; ++kb) {
        const int k0 = kb * 32 + kg;
        short8 ah = *(const short8*)&Ah[swze(w * 16 + ln, k0)];
        short8 al = *(const short8*)&Al[swze(w * 16 + ln, k0)];
#pragma unroll
        for (int j = 0; j < 4; ++j) {
            short8 bh = *(const short8*)&Bh[swze(j * 16 + ln, k0)];
            short8 bl = *(const short8*)&Bl[swze(j * 16 + ln, k0)];
            acc[j] = __builtin_amdgcn_mfma_f32_16x16x32_bf16(ah, bh, acc[j], 0, 0, 0);
            acc[j] = __builtin_amdgcn_mfma_f32_16x16x32_bf16(ah, bl, acc[j], 0, 0, 0);
            acc[j] = __builtin_amdgcn_mfma_f32_16x16x32_bf16(al, bh, acc[j], 0, 0, 0);
        }
    }
}

// global fp32 [64][64] -> hi/lo bf16 LDS (swizzled, vectorized)
__device__ __forceinline__ void g_to_ls(const float* __restrict__ G, u16* Ah, u16* Al, int tid) {
#pragma unroll
    for (int p = 0; p < 4; ++p) {
        int flat = p * 1024 + tid * 4;
        int r = flat >> 6, c = flat & 63;
        float4 v = *(const float4*)&G[flat];
        u16 h0, l0, h1, l1, h2, l2, h3, l3;
        split2(v.x, h0, l0); split2(v.y, h1, l1);
        split2(v.z, h2, l2); split2(v.w, h3, l3);
        int idx = swze(r, c);
        uint2 hv, lv;
        hv.x = (unsigned)h0 | ((unsigned)h1 << 16); hv.y = (unsigned)h2 | ((unsigned)h3 << 16);
        lv.x = (unsigned)l0 | ((unsigned)l1 << 16); lv.y = (unsigned)l2 | ((unsigned)l3 << 16);
        *(uint2*)&Ah[idx] = hv;
        *(uint2*)&Al[idx] = lv;
    }
}

// register frag -> hi/lo bf16 LDS
__device__ __forceinline__ void frag_to_ls(const f32x4* acc, u16* Ah, u16* Al, int w, int lane) {
    const int g = lane >> 4, ln = lane & 15;
#pragma unroll
    for (int j = 0; j < 4; ++j)
#pragma unroll
        for (int r = 0; r < 4; ++r) {
            int row = w * 16 + g * 4 + r, col = j * 16 + ln;
            u16 h, l; split2(acc[j][r], h, l);
            Ah[swze(row, col)] = h;
            Al[swze(row, col)] = l;
        }
}

__device__ __forceinline__ void g_to_frag(const float* __restrict__ G, f32x4* acc, int w, int lane) {
    const int g = lane >> 4, ln = lane & 15;
#pragma unroll
    for (int j = 0; j < 4; ++j)
#pragma unroll
        for (int r = 0; r < 4; ++r)
            acc[j][r] = G[(w * 16 + g * 4 + r) * 64 + j * 16 + ln];
}
__device__ __forceinline__ void g_add_frag(const float* __restrict__ G, f32x4* acc, int w, int lane) {
    const int g = lane >> 4, ln = lane & 15;
#pragma unroll
    for (int j = 0; j < 4; ++j)
#pragma unroll
        for (int r = 0; r < 4; ++r)
            acc[j][r] += G[(w * 16 + g * 4 + r) * 64 + j * 16 + ln];
}
__device__ __forceinline__ void frag_to_g(const f32x4* acc, float* __restrict__ G, int w, int lane) {
    const int g = lane >> 4, ln = lane & 15;
#pragma unroll
    for (int j = 0; j < 4; ++j)
#pragma unroll
        for (int r = 0; r < 4; ++r)
            G[(w * 16 + g * 4 + r) * 64 + j * 16 + ln] = acc[j][r];
}

// ---------------------------------------------------------------------------
// fp32 -> bf16 cast
// ---------------------------------------------------------------------------
__global__ __launch_bounds__(256) void cast_bf16_k(const float* __restrict__ in,
                                                   u16* __restrict__ out) {
    int i = (blockIdx.x * 256 + threadIdx.x) * 8;
    float4 a = *(const float4*)&in[i];
    float4 b = *(const float4*)&in[i + 4];
    uint4 o;
    o.x = (unsigned)f2bf(a.x) | ((unsigned)f2bf(a.y) << 16);
    o.y = (unsigned)f2bf(a.z) | ((unsigned)f2bf(a.w) << 16);
    o.z = (unsigned)f2bf(b.x) | ((unsigned)f2bf(b.y) << 16);
    o.w = (unsigned)f2bf(b.z) | ((unsigned)f2bf(b.w) << 16);
    *(uint4*)&out[i] = o;
}

// ---------------------------------------------------------------------------
// 4x fused: W [K][N] fp32 -> WT [N][K] bf16  (grid.z selects matrix)
// ---------------------------------------------------------------------------
__global__ __launch_bounds__(256) void transW4_k(const float* __restrict__ W0,
                                                 const float* __restrict__ W1,
                                                 const float* __restrict__ W2,
                                                 const float* __restrict__ W3,
                                                 u16* __restrict__ WT0) {
    __shared__ float t[32][33];
    const int which = blockIdx.z;
    const float* W = (which == 0) ? W0 : (which == 1) ? W1 : (which == 2) ? W2 : W3;
    u16* WT = WT0 + (size_t)which * 1048576;
    const int bx = blockIdx.x * 32, by = blockIdx.y * 32;
#pragma unroll
    for (int p = 0; p < 4; ++p) {
        int idx = p * 256 + threadIdx.x;
        int r = idx >> 5, cc = idx & 31;
        t[r][cc] = W[(size_t)(by + r) * 1024 + bx + cc];
    }
    __syncthreads();
#pragma unroll
    for (int p = 0; p < 4; ++p) {
        int idx = p * 256 + threadIdx.x;
        int r = idx >> 5, cc = idx & 31;
        WT[(size_t)(bx + r) * 1024 + by + cc] = f2bf(t[cc][r]);
    }
}

// ---------------------------------------------------------------------------
// bf16 MFMA GEMM body (m97 structure)
// ---------------------------------------------------------------------------
__device__ __forceinline__ void gemm_body(const u16* A, const u16* BT,
                                          float* C, int m0, int n0) {
    __shared__ __align__(16) short As[128 * 32];
    __shared__ __align__(16) short Bs[128 * 32];
    const int tid = threadIdx.x;
    const int lane = tid & 63, w = tid >> 6;
    const int wr = w >> 1, wc = w & 1;
    const int ln15 = lane & 15, kg8 = (lane >> 4) * 8;
    f32x4 acc[4][4] = {};
    const int erow = tid >> 2;
    const int ecol = (tid & 3) * 8;
    for (int k0 = 0; k0 < 1024; k0 += 32) {
#pragma unroll
        for (int r = 0; r < 2; ++r) {
            gld_lds16(A  + (size_t)(m0 + erow + r * 64) * 1024 + k0 + ecol,
                      (short*)As + r * 2048 + tid * 8);
            gld_lds16(BT + (size_t)(n0 + erow + r * 64) * 1024 + k0 + ecol,
                      (short*)Bs + r * 2048 + tid * 8);
        }
        __syncthreads();
        short8 af[4], bf[4];
#pragma unroll
        for (int i = 0; i < 4; ++i)
            af[i] = *(const short8*)&As[(wr * 64 + i * 16 + ln15) * 32 + kg8];
#pragma unroll
        for (int j = 0; j < 4; ++j)
            bf[j] = *(const short8*)&Bs[(wc * 64 + j * 16 + ln15) * 32 + kg8];
#pragma unroll
        for (int i = 0; i < 4; ++i)
#pragma unroll
            for (int j = 0; j < 4; ++j)
                acc[i][j] = __builtin_amdgcn_mfma_f32_16x16x32_bf16(af[i], bf[j], acc[i][j], 0, 0, 0);
        __syncthreads();
    }
    const int crow0 = m0 + wr * 64 + (lane >> 4) * 4;
    const int ccol0 = n0 + wc * 64 + ln15;
#pragma unroll
    for (int i = 0; i < 4; ++i)
#pragma unroll
        for (int j = 0; j < 4; ++j)
#pragma unroll
            for (int r = 0; r < 4; ++r)
                C[(size_t)(crow0 + i * 16 + r) * 1024 + ccol0 + j * 16] = acc[i][j][r];
}

__global__ __launch_bounds__(256) void gemm_bf16(const u16* __restrict__ A,
                                                 const u16* __restrict__ BT,
                                                 float* __restrict__ C) {
    gemm_body(A, BT, C, blockIdx.y * 128, blockIdx.x * 128);
}

__global__ __launch_bounds__(256) void gemm_qkv(const u16* __restrict__ A,
                                                const u16* __restrict__ WT0,
                                                float* __restrict__ C0) {
    const int which = blockIdx.x >> 3;
    const int n0 = (blockIdx.x & 7) * 128;
    const u16* BT = WT0 + (size_t)which * 1048576;
    float* C = C0 + (size_t)which * ((size_t)BB * LL * DD);
    gemm_body(A, BT, C, blockIdx.y * 128, n0);
}

// ---------------------------------------------------------------------------
// beta = sigmoid(x @ Wb) stored [B,H,L]
// ---------------------------------------------------------------------------
__global__ __launch_bounds__(256) void beta_k(const float* __restrict__ X,
                                              const float* __restrict__ Wb,
                                              float* __restrict__ beta) {
    int idx = blockIdx.x * 256 + threadIdx.x;
    int row = idx >> 4, h = idx & 15;
    const float* xr = X + (size_t)row * DD;
    float s = 0.f;
    for (int k4 = 0; k4 < DD; k4 += 4) {
        float4 xv = *(const float4*)&xr[k4];
        s += xv.x * Wb[(k4 + 0) * HH + h];
        s += xv.y * Wb[(k4 + 1) * HH + h];
        s += xv.z * Wb[(k4 + 2) * HH + h];
        s += xv.w * Wb[(k4 + 3) * HH + h];
    }
    float bv = 1.f / (1.f + expf(-s));
    int b = row >> 12, l = row & (LL - 1);
    beta[((size_t)b * HH + h) * LL + l] = bv;
}

// ---------------------------------------------------------------------------
// 3x fused conv: grid (LL/16, BB, 3); which 0=q(norm) 1=k(norm) 2=v
// ---------------------------------------------------------------------------
__global__ __launch_bounds__(256) void conv3_k(const float* __restrict__ Xq,
                                               const float* __restrict__ Xk,
                                               const float* __restrict__ Xv,
                                               const float* __restrict__ cwq,
                                               const float* __restrict__ cwk,
                                               const float* __restrict__ cwv,
                                               float* __restrict__ oq,
                                               float* __restrict__ ok,
                                               float* __restrict__ ov) {
    const int which = blockIdx.z;
    const float* X  = (which == 0) ? Xq  : (which == 1) ? Xk  : Xv;
    const float* cw = (which == 0) ? cwq : (which == 1) ? cwk : cwv;
    float* out      = (which == 0) ? oq  : (which == 1) ? ok  : ov;
    const bool NORM = (which < 2);
    const int l0 = blockIdx.x * 16, b = blockIdx.y;
    const int tid = threadIdx.x;
    const int d0 = tid * 4;
    const float4 w0 = *(const float4*)&cw[(d0 + 0) * 4];
    const float4 w1 = *(const float4*)&cw[(d0 + 1) * 4];
    const float4 w2 = *(const float4*)&cw[(d0 + 2) * 4];
    const float4 w3 = *(const float4*)&cw[(d0 + 3) * 4];
    const float* Xb = X + (size_t)b * LL * DD;
    float4 xm3 = make_float4(0, 0, 0, 0), xm2 = xm3, xm1 = xm3;
    if (l0 > 0) {
        xm3 = *(const float4*)&Xb[(size_t)(l0 - 3) * DD + d0];
        xm2 = *(const float4*)&Xb[(size_t)(l0 - 2) * DD + d0];
        xm1 = *(const float4*)&Xb[(size_t)(l0 - 1) * DD + d0];
    }
    const int h = d0 >> 6, hd = d0 & 63;
#pragma unroll
    for (int t = 0; t < 16; ++t) {
        const int l = l0 + t;
        float4 xc = *(const float4*)&Xb[(size_t)l * DD + d0];
        float a0 = xm3.x * w0.x + xm2.x * w0.y + xm1.x * w0.z + xc.x * w0.w;
        float a1 = xm3.y * w1.x + xm2.y * w1.y + xm1.y * w1.z + xc.y * w1.w;
        float a2 = xm3.z * w2.x + xm2.z * w2.y + xm1.z * w2.z + xc.z * w2.w;
        float a3 = xm3.w * w3.x + xm2.w * w3.y + xm1.w * w3.z + xc.w * w3.w;
        a0 = a0 / (1.f + expf(-a0));
        a1 = a1 / (1.f + expf(-a1));
        a2 = a2 / (1.f + expf(-a2));
        a3 = a3 / (1.f + expf(-a3));
        if (NORM) {
            float s = a0 * a0 + a1 * a1 + a2 * a2 + a3 * a3;
            s += __shfl_xor(s, 1);
            s += __shfl_xor(s, 2);
            s += __shfl_xor(s, 4);
            s += __shfl_xor(s, 8);
            float sc = rsqrtf(s);
            a0 *= sc; a1 *= sc; a2 *= sc; a3 *= sc;
        }
        *(float4*)&out[(((size_t)b * HH + h) * LL + l) * 64 + hd] =
            make_float4(a0, a1, a2, a3);
        xm3 = xm2; xm2 = xm1; xm1 = xc;
    }
}

// ---------------------------------------------------------------------------
// Phase A v4: all transposed tile builds vectorized (uint2 stores, 2-way max).
// ---------------------------------------------------------------------------
__global__ __launch_bounds__(256) void phaseA4(const float* __restrict__ kg,
                                               const float* __restrict__ vg,
                                               const float* __restrict__ betag,
                                               float* __restrict__ Wg,
                                               float* __restrict__ UgT,
                                               float* __restrict__ Pall,
                                               float* __restrict__ BallT) {
    __shared__ __align__(16) char pool[81920];
    u16* Kh  = (u16*)pool;              // plain K hi  (later WTh)
    u16* Kl  = (u16*)(pool + 8192);     // plain K lo  (later WTl)
    u16* KTh = (u16*)(pool + 16384);
    u16* KTl = (u16*)(pool + 24576);
    float* At = (float*)(pool + 32768); // [64][64]   (later UTh/UTl)
    float* WU = (float*)(pool + 49152); // [64][128]  (later scr)
    u16* WTh = (u16*)pool;
    u16* WTl = (u16*)(pool + 8192);
    u16* UTh = (u16*)(pool + 32768);
    u16* UTl = (u16*)(pool + 40960);
    float* scr = (float*)(pool + 49152);

    const int c = blockIdx.x, bh = blockIdx.y;
    const int tid = threadIdx.x, lane = tid & 63, w = tid >> 6;
    const int g = lane >> 4, ln = lane & 15;
    const int t0 = (tid >> 4) * 4, d4 = (tid & 15) * 4;
    const size_t base = ((size_t)bh * LL + (size_t)c * 64) * 64;
    const size_t obase = ((size_t)bh * NC + c) * 4096;
    const float* bet = betag + (size_t)bh * LL + (size_t)c * 64;

    // 1a. plain K -> Kh/Kl (vectorized)
    g_to_ls(&kg[base], Kh, Kl, tid);
    // 1b. K^T -> KTh/KTl via global re-read of 4x4 block, vectorized uint2 stores
    {
        u16 h4[4][4], l4[4][4];
#pragma unroll
        for (int i = 0; i < 4; ++i) {
            float4 v = *(const float4*)&kg[base + (size_t)(t0 + i) * 64 + d4];
            split2(v.x, h4[i][0], l4[i][0]); split2(v.y, h4[i][1], l4[i][1]);
            split2(v.z, h4[i][2], l4[i][2]); split2(v.w, h4[i][3], l4[i][3]);
        }
#pragma unroll
        for (int j = 0; j < 4; ++j) {
            uint2 hv, lv;
            hv.x = (unsigned)h4[0][j] | ((unsigned)h4[1][j] << 16);
            hv.y = (unsigned)h4[2][j] | ((unsigned)h4[3][j] << 16);
            lv.x = (unsigned)l4[0][j] | ((unsigned)l4[1][j] << 16);
            lv.y = (unsigned)l4[2][j] | ((unsigned)l4[3][j] << 16);
            *(uint2*)&KTh[swze(d4 + j, t0)] = hv;
            *(uint2*)&KTl[swze(d4 + j, t0)] = lv;
        }
    }
    __syncthreads();
    // 2. Gram A = strict_tril(beta * K K^T)
    {
        f32x4 acc[4] = {};
        mm64(Kh, Kl, Kh, Kl, acc, w, lane);
#pragma unroll
        for (int r = 0; r < 4; ++r) {
            int t = w * 16 + g * 4 + r;
            float bt = bet[t];
#pragma unroll
            for (int j = 0; j < 4; ++j) {
                int s = j * 16 + ln;
                At[t * 64 + s] = (s < t) ? bt * acc[j][r] : 0.f;
            }
        }
    }
    // 3. RHS: WU[t][j] = beta_t * (j<64 ? K[t][j] : V[t][j-64])
#pragma unroll
    for (int p = 0; p < 8; ++p) {
        int flat = p * 1024 + tid * 4;
        int t = flat >> 7, j = flat & 127;
        float bt = bet[t];
        float4 src;
        if (j < 64) {
            int idx = swze(t, j);
            uint2 hh = *(const uint2*)&Kh[idx];
            uint2 ll2 = *(const uint2*)&Kl[idx];
            src.x = bf2f((u16)hh.x) + bf2f((u16)ll2.x);
            src.y = bf2f((u16)(hh.x >> 16)) + bf2f((u16)(ll2.x >> 16));
            src.z = bf2f((u16)hh.y) + bf2f((u16)ll2.y);
            src.w = bf2f((u16)(hh.y >> 16)) + bf2f((u16)(ll2.y >> 16));
        } else {
            src = *(const float4*)&vg[base + (size_t)t * 64 + (j - 64)];
        }
        src.x *= bt; src.y *= bt; src.z *= bt; src.w *= bt;
        *(float4*)&WU[t * 128 + j] = src;
    }
    __syncthreads();
    // 4. blocked forward substitution (panels of 16)
#pragma unroll
    for (int pb = 0; pb < 4; ++pb) {
        const int r0 = pb * 16;
        if (pb > 0) {
            const int col = tid & 127;
            const int rbase = r0 + (tid >> 7) * 8;
            float acc8[8] = {};
            for (int r = 0; r < r0; r += 4) {
                float u0 = WU[(r + 0) * 128 + col], u1 = WU[(r + 1) * 128 + col];
                float u2 = WU[(r + 2) * 128 + col], u3 = WU[(r + 3) * 128 + col];
#pragma unroll
                for (int i = 0; i < 8; ++i) {
                    float4 a4 = *(const float4*)&At[(rbase + i) * 64 + r];
                    acc8[i] += a4.x * u0 + a4.y * u1 + a4.z * u2 + a4.w * u3;
                }
            }
#pragma unroll
            for (int i = 0; i < 8; ++i) WU[(rbase + i) * 128 + col] -= acc8[i];
            __syncthreads();
        }
        if (tid < 128) {
            const int col = tid;
            float wv[16];
            wv[0] = WU[r0 * 128 + col];
#pragma unroll
            for (int t = 1; t < 16; ++t) {
                float a = WU[(r0 + t) * 128 + col];
#pragma unroll
                for (int r = 0; r < t; ++r) a -= At[(r0 + t) * 64 + r0 + r] * wv[r];
                wv[t] = a;
            }
#pragma unroll
            for (int t = 1; t < 16; ++t) WU[(r0 + t) * 128 + col] = wv[t];
        }
        __syncthreads();
    }
    // 5a. Wg global write (vectorized row reads of WU)
#pragma unroll
    for (int p = 0; p < 4; ++p) {
        int flat = p * 1024 + tid * 4;
        int t = flat >> 6, j = flat & 63;
        *(float4*)&Wg[obase + flat] = *(const float4*)&WU[t * 128 + j];
    }
    // 5b. W^T, U^T builds from WU (vectorized reads + uint2 transposed stores)
    {
        u16 h4[4][4], l4[4][4];
#pragma unroll
        for (int i = 0; i < 4; ++i) {
            float4 v = *(const float4*)&WU[(t0 + i) * 128 + d4];
            split2(v.x, h4[i][0], l4[i][0]); split2(v.y, h4[i][1], l4[i][1]);
            split2(v.z, h4[i][2], l4[i][2]); split2(v.w, h4[i][3], l4[i][3]);
        }
#pragma unroll
        for (int j = 0; j < 4; ++j) {
            uint2 hv, lv;
            hv.x = (unsigned)h4[0][j] | ((unsigned)h4[1][j] << 16);
            hv.y = (unsigned)h4[2][j] | ((unsigned)h4[3][j] << 16);
            lv.x = (unsigned)l4[0][j] | ((unsigned)l4[1][j] << 16);
            lv.y = (unsigned)l4[2][j] | ((unsigned)l4[3][j] << 16);
            *(uint2*)&WTh[swze(d4 + j, t0)] = hv;
            *(uint2*)&WTl[swze(d4 + j, t0)] = lv;
        }
#pragma unroll
        for (int i = 0; i < 4; ++i) {
            float4 v = *(const float4*)&WU[(t0 + i) * 128 + 64 + d4];
            split2(v.x, h4[i][0], l4[i][0]); split2(v.y, h4[i][1], l4[i][1]);
            split2(v.z, h4[i][2], l4[i][2]); split2(v.w, h4[i][3], l4[i][3]);
        }
#pragma unroll
        for (int j = 0; j < 4; ++j) {
            uint2 hv, lv;
            hv.x = (unsigned)h4[0][j] | ((unsigned)h4[1][j] << 16);
            hv.y = (unsigned)h4[2][j] | ((unsigned)h4[3][j] << 16);
            lv.x = (unsigned)l4[0][j] | ((unsigned)l4[1][j] << 16);
            lv.y = (unsigned)l4[2][j] | ((unsigned)l4[3][j] << 16);
            *(uint2*)&UTh[swze(d4 + j, t0)] = hv;
            *(uint2*)&UTl[swze(d4 + j, t0)] = lv;
        }
    }
    __syncthreads();
    // 6. UgT global write (reconstructed from UT tiles)
#pragma unroll
    for (int p = 0; p < 4; ++p) {
        int flat = p * 1024 + tid * 4;
        int n = flat >> 6, tt = flat & 63;
        int idx = swze(n, tt);
        uint2 hh = *(const uint2*)&UTh[idx];
        uint2 ll2 = *(const uint2*)&UTl[idx];
        float4 o;
        o.x = bf2f((u16)hh.x) + bf2f((u16)ll2.x);
        o.y = bf2f((u16)(hh.x >> 16)) + bf2f((u16)(ll2.x >> 16));
        o.z = bf2f((u16)hh.y) + bf2f((u16)ll2.y);
        o.w = bf2f((u16)(hh.y >> 16)) + bf2f((u16)(ll2.y >> 16));
        *(float4*)&UgT[obase + flat] = o;
    }
    // 7. P = I - K^T W ; B = K^T U   (MFMA)
    f32x4 aP[4] = {}, aB[4] = {};
    mm64(KTh, KTl, WTh, WTl, aP, w, lane);
    mm64(KTh, KTl, UTh, UTl, aB, w, lane);
#pragma unroll
    for (int j = 0; j < 4; ++j)
#pragma unroll
        for (int r = 0; r < 4; ++r) {
            int row = w * 16 + g * 4 + r, col = j * 16 + ln;
            float pv = ((row == col) ? 1.f : 0.f) - aP[j][r];
            Pall[obase + (size_t)row * 64 + col] = pv;
            scr[swz(row, col)] = aB[j][r];
        }
    __syncthreads();
    // 8. BallT (coalesced via swizzled transpose)
#pragma unroll
    for (int p = 0; p < 4; ++p) {
        int flat = p * 1024 + tid * 4;
        int n = flat >> 6, dd = flat & 63;
        float4 o;
        o.x = scr[swz(dd + 0, n)];
        o.y = scr[swz(dd + 1, n)];
        o.z = scr[swz(dd + 2, n)];
        o.w = scr[swz(dd + 3, n)];
        *(float4*)&BallT[obase + flat] = o;
    }
}

// ---------------------------------------------------------------------------
// compose3 (MFMA): per group of 8 chunks, composed affine map (transposed state).
// ---------------------------------------------------------------------------
__global__ __launch_bounds__(256) void compose3(const float* __restrict__ Pall,
                                                const float* __restrict__ BallT,
                                                float* __restrict__ Pg,
                                                float* __restrict__ BgT) {
    __shared__ __align__(16) char pool[81920];
    u16* Ph = (u16*)pool;
    u16* Pl = (u16*)(pool + 8192);
    u16* Bh = (u16*)(pool + 16384);
    u16* Bl = (u16*)(pool + 24576);
    u16* nh = (u16*)(pool + 32768);
    u16* nl = (u16*)(pool + 40960);
    float* scr = (float*)(pool + 49152);
    const int g = blockIdx.x, bh = blockIdx.y;
    const int tid = threadIdx.x, lane = tid & 63, w = tid >> 6;
    const int gi = lane >> 4, ln = lane & 15;
    const size_t base0 = ((size_t)bh * NC + (size_t)g * GS) * 4096;
    f32x4 mP[4], mB[4];
#pragma unroll
    for (int p = 0; p < 4; ++p) {
        int flat = p * 1024 + tid * 4;
        int r = flat >> 6, c4 = flat & 63;
        *(float4*)&scr[swz(r, c4)] = *(const float4*)&Pall[base0 + flat];
    }
    g_to_frag(BallT + base0, mB, w, lane);
    __syncthreads();
#pragma unroll
    for (int j = 0; j < 4; ++j)
#pragma unroll
        for (int r = 0; r < 4; ++r) {
            int row = w * 16 + gi * 4 + r, col = j * 16 + ln;
            mP[j][r] = scr[swz(col, row)];
        }
    for (int s = 1; s < GS; ++s) {
        __syncthreads();
        frag_to_ls(mP, Ph, Pl, w, lane);
        frag_to_ls(mB, Bh, Bl, w, lane);
        g_to_ls(&Pall[base0 + (size_t)s * 4096], nh, nl, tid);
        __syncthreads();
        f32x4 aP[4] = {}, aB[4] = {};
        mm64(Ph, Pl, nh, nl, aP, w, lane);
        mm64(Bh, Bl, nh, nl, aB, w, lane);
        g_add_frag(&BallT[base0 + (size_t)s * 4096], aB, w, lane);
#pragma unroll
        for (int j = 0; j < 4; ++j) { mP[j] = aP[j]; mB[j] = aB[j]; }
    }
    const size_t gbase = ((size_t)bh * GG + g) * 4096;
    frag_to_g(mB, BgT + gbase, w, lane);
    __syncthreads();
#pragma unroll
    for (int j = 0; j < 4; ++j)
#pragma unroll
        for (int r = 0; r < 4; ++r) {
            int row = w * 16 + gi * 4 + r, col = j * 16 + ln;
            scr[swz(row, col)] = mP[j][r];
        }
    __syncthreads();
#pragma unroll
    for (int p = 0; p < 4; ++p) {
        int flat = p * 1024 + tid * 4;
        int a = flat >> 6, b0 = flat & 63;
        float4 o;
        o.x = scr[swz(b0 + 0, a)];
        o.y = scr[swz(b0 + 1, a)];
        o.z = scr[swz(b0 + 2, a)];
        o.w = scr[swz(b0 + 3, a)];
        *(float4*)&Pg[gbase + flat] = o;
    }
}

// ---------------------------------------------------------------------------
// scanG3 (MFMA): sequential over 8 groups; writes group-entry states SallT.
// ---------------------------------------------------------------------------
__global__ __launch_bounds__(256) void scanG3(const float* __restrict__ Pg,
                                              const float* __restrict__ BgT,
                                              float* __restrict__ SallT) {
    __shared__ __align__(16) char pool[32768];
    u16* Sh = (u16*)pool;
    u16* Sl = (u16*)(pool + 8192);
    u16* nh = (u16*)(pool + 16384);
    u16* nl = (u16*)(pool + 24576);
    const int bh = blockIdx.x;
    const int tid = threadIdx.x, lane = tid & 63, w = tid >> 6;
    f32x4 mS[4] = {};
    for (int g = 0; g < GG; ++g) {
        const size_t sbase = ((size_t)bh * NC + (size_t)g * GS) * 4096;
        frag_to_g(mS, SallT + sbase, w, lane);
        if (g == GG - 1) break;
        __syncthreads();
        frag_to_ls(mS, Sh, Sl, w, lane);
        g_to_ls(&Pg[((size_t)bh * GG + g) * 4096], nh, nl, tid);
        __syncthreads();
        f32x4 a[4] = {};
        mm64(Sh, Sl, nh, nl, a, w, lane);
        g_add_frag(&BgT[((size_t)bh * GG + g) * 4096], a, w, lane);
#pragma unroll
        for (int j = 0; j < 4; ++j) mS[j] = a[j];
    }
}

// ---------------------------------------------------------------------------
// rollout3 (MFMA): fill chunk-entry states within each group (SallT).
// ---------------------------------------------------------------------------
__global__ __launch_bounds__(256) void rollout3(const float* __restrict__ Pall,
                                                const float* __restrict__ BallT,
                                                float* __restrict__ SallT) {
    __shared__ __align__(16) char pool[32768];
    u16* Sh = (u16*)pool;
    u16* Sl = (u16*)(pool + 8192);
    u16* nh = (u16*)(pool + 16384);
    u16* nl = (u16*)(pool + 24576);
    const int g = blockIdx.x, bh = blockIdx.y;
    const int tid = threadIdx.x, lane = tid & 63, w = tid >> 6;
    const size_t base0 = ((size_t)bh * NC + (size_t)g * GS) * 4096;
    f32x4 mS[4];
    g_to_frag(SallT + base0, mS, w, lane);
    for (int j = 1; j < GS; ++j) {
        __syncthreads();
        frag_to_ls(mS, Sh, Sl, w, lane);
        g_to_ls(&Pall[base0 + (size_t)(j - 1) * 4096], nh, nl, tid);
        __syncthreads();
        f32x4 a[4] = {};
        mm64(Sh, Sl, nh, nl, a, w, lane);
        g_add_frag(&BallT[base0 + (size_t)(j - 1) * 4096], a, w, lane);
#pragma unroll
        for (int jj = 0; jj < 4; ++jj) mS[jj] = a[jj];
        frag_to_g(mS, SallT + base0 + (size_t)j * 4096, w, lane);
    }
}

// ---------------------------------------------------------------------------
// phaseO3 (MFMA): M = causal(QK^T); Delta^T = U^T - S^T W^T;
// O = Q S + M Delta; fused RMSNorm + bf16 cast.
// ---------------------------------------------------------------------------
__global__ __launch_bounds__(256) void phaseO3(const float* __restrict__ Wg,
                                               const float* __restrict__ UgT,
                                               const float* __restrict__ qg,
                                               const float* __restrict__ kg,
                                               const float* __restrict__ SallT,
                                               const float* __restrict__ nw,
                                               u16* __restrict__ ob) {
    __shared__ __align__(16) char pool[65536];
    u16* Qh = (u16*)pool;
    u16* Ql = (u16*)(pool + 8192);
    u16* Kh = (u16*)(pool + 16384);
    u16* Kl = (u16*)(pool + 24576);
    u16* Wh = (u16*)(pool + 32768);
    u16* Wl = (u16*)(pool + 40960);
    u16* Sh = (u16*)(pool + 49152);
    u16* Sl = (u16*)(pool + 57344);
    u16* Dh = Kh; u16* Dl = Kl;
    u16* Mh = Wh; u16* Ml = Wl;
    const int c = blockIdx.x, bh = blockIdx.y;
    const int b = bh >> 4, h = bh & 15;
    const int tid = threadIdx.x, lane = tid & 63, w = tid >> 6;
    const int gi = lane >> 4, ln = lane & 15;
    const size_t tbase = ((size_t)bh * NC + c) * 4096;
    const size_t qkbase = ((size_t)bh * LL + (size_t)c * 64) * 64;
    g_to_ls(&qg[qkbase], Qh, Ql, tid);
    g_to_ls(&kg[qkbase], Kh, Kl, tid);
    g_to_ls(&Wg[tbase], Wh, Wl, tid);
    g_to_ls(&SallT[tbase], Sh, Sl, tid);
    __syncthreads();
    f32x4 aM[4] = {}, aD[4] = {};
    mm64(Qh, Ql, Kh, Kl, aM, w, lane);   // Q K^T
    mm64(Sh, Sl, Wh, Wl, aD, w, lane);   // (W S)^T
    __syncthreads();
#pragma unroll
    for (int j = 0; j < 4; ++j)
#pragma unroll
        for (int r = 0; r < 4; ++r) {
            int row = w * 16 + gi * 4 + r, col = j * 16 + ln;
            float mv = (col <= row) ? aM[j][r] : 0.f;
            u16 mh_, ml_; split2(mv, mh_, ml_);
            Mh[swze(row, col)] = mh_;
            Ml[swze(row, col)] = ml_;
            float dv = UgT[tbase + (size_t)row * 64 + col] - aD[j][r];
            u16 dh_, dl_; split2(dv, dh_, dl_);
            Dh[swze(row, col)] = dh_;
            Dl[swze(row, col)] = dl_;
        }
    __syncthreads();
    f32x4 aO[4] = {};
    mm64(Qh, Ql, Sh, Sl, aO, w, lane);   // Q S
    mm64(Mh, Ml, Dh, Dl, aO, w, lane);   // + M Delta
    float nwv[4];
#pragma unroll
    for (int j = 0; j < 4; ++j) nwv[j] = nw[j * 16 + ln];
#pragma unroll
    for (int r = 0; r < 4; ++r) {
        float ss = 0.f;
#pragma unroll
        for (int j = 0; j < 4; ++j) ss += aO[j][r] * aO[j][r];
        ss += __shfl_xor(ss, 1);
        ss += __shfl_xor(ss, 2);
        ss += __shfl_xor(ss, 4);
        ss += __shfl_xor(ss, 8);
        float rms = rsqrtf(ss * (1.f / 64.f) + 1e-5f);
        int row = w * 16 + gi * 4 + r;
        size_t orow = ((size_t)b * LL + (size_t)c * 64 + row) * DD + (size_t)h * 64;
#pragma unroll
        for (int j = 0; j < 4; ++j)
            ob[orow + j * 16 + ln] = f2bf(aO[j][r] * rms * nwv[j]);
    }
}

// ---------------------------------------------------------------------------
extern "C" void kernel_launch(void* const* d_in, const int* in_sizes, int n_in,
                              void* d_out, int out_size, void* d_ws, size_t ws_size,
                              hipStream_t stream) {
    const float* x  = (const float*)d_in[0];
    const float* Wq = (const float*)d_in[1];
    const float* Wk = (const float*)d_in[2];
    const float* Wv = (const float*)d_in[3];
    const float* Wb = (const float*)d_in[4];
    const float* cq = (const float*)d_in[5];
    const float* ck = (const float*)d_in[6];
    const float* cv = (const float*)d_in[7];
    const float* nw = (const float*)d_in[8];
    const float* Wo = (const float*)d_in[9];
    float* out = (float*)d_out;
    float* ws = (float*)d_ws;

    const size_t SZ = (size_t)BB * LL * DD;   // 8388608
    float* xq   = ws;            // -> Wg
    float* xk   = ws + SZ;       // -> UgT
    float* xv   = ws + 2 * SZ;   // -> Pall
    float* q    = ws + 3 * SZ;   // xb first, then q
    float* k    = ws + 4 * SZ;
    float* v    = ws + 5 * SZ;   // -> ob
    float* beta = ws + 6 * SZ;                       // 131072 floats
    u16* wqT = (u16*)(beta + (size_t)BH * LL);       // 4M u16
    float* SallT = (float*)wqT + 2097152;            // SZ floats
    float* PgB  = SallT + SZ;                        // 1M floats
    float* BgT  = PgB + 1048576;                     // 1M floats

    u16* xb = (u16*)q;
    u16* ob = (u16*)v;
    u16* woT = wqT + (size_t)3 * 1048576;
    float* Wg = xq;
    float* UgT = xk;
    float* Pall = xv;
    float* BallT = out;   // d_out as scratch; fully overwritten by final GEMM

    dim3 blk(256);

    cast_bf16_k<<<dim3(4096), blk, 0, stream>>>(x, xb);
    transW4_k<<<dim3(32, 32, 4), blk, 0, stream>>>(Wq, Wk, Wv, Wo, wqT);
    gemm_qkv<<<dim3(24, 64), blk, 0, stream>>>(xb, wqT, xq);
    beta_k<<<dim3(512), blk, 0, stream>>>(x, Wb, beta);
    conv3_k<<<dim3(LL / 16, BB, 3), blk, 0, stream>>>(xq, xk, xv, cq, ck, cv, q, k, v);
    phaseA4<<<dim3(NC, BH), blk, 0, stream>>>(k, v, beta, Wg, UgT, Pall, BallT);
    compose3<<<dim3(GG, BH), blk, 0, stream>>>(Pall, BallT, PgB, BgT);
    scanG3<<<dim3(BH), blk, 0, stream>>>(PgB, BgT, SallT);
    rollout3<<<dim3(GG, BH), blk, 0, stream>>>(Pall, BallT, SallT);
    phaseO3<<<dim3(NC, BH), blk, 0, stream>>>(Wg, UgT, q, k, SallT, nw, ob);
    gemm_bf16<<<dim3(8, 64), blk, 0, stream>>>(ob, woT, out);
}

// Round 7
// 363.074 us; speedup vs baseline: 5.2650x; 1.0659x over previous
//
#include <hip/hip_runtime.h>
#include <hip/hip_bf16.h>
#include <math.h>

#define BB 2
#define LL 4096
#define DD 1024
#define HH 16
#define HDIM 64
#define CC 64
#define NC 64   // LL/CC
#define BH 32   // BB*HH
#define GG 8    // chunk groups
#define GS 8    // chunks per group

typedef __attribute__((ext_vector_type(8))) short short8;
typedef __attribute__((ext_vector_type(4))) float f32x4;
typedef unsigned short u16;

__device__ __forceinline__ u16 f2bf(float f) {
    unsigned int u = __float_as_uint(f);
    unsigned int r = (u + 0x7fffu + ((u >> 16) & 1u)) >> 16;
    return (u16)r;
}
__device__ __forceinline__ float bf2f(u16 h) {
    return __uint_as_float((unsigned)h << 16);
}
__device__ __forceinline__ void split2(float x, u16& h, u16& l) {
    h = f2bf(x);
    l = f2bf(x - bf2f(h));
}
__device__ __forceinline__ float4 ld_bf4(const u16* p) {
    uint2 v = *(const uint2*)p;
    return make_float4(bf2f((u16)v.x), bf2f((u16)(v.x >> 16)),
                       bf2f((u16)v.y), bf2f((u16)(v.y >> 16)));
}

__device__ __forceinline__ void gld_lds16(const void* g, void* l) {
    __builtin_amdgcn_global_load_lds(
        (const __attribute__((address_space(1))) void*)g,
        (__attribute__((address_space(3))) void*)l, 16, 0, 0);
}

// fp32 [64][64] tile swizzle (4-elem chunks XOR'd by row>>2)
__device__ __forceinline__ int swz(int r, int c) {
    return (r << 6) + ((((c >> 2) ^ (r >> 2)) & 15) << 2) + (c & 3);
}
// bf16 [64][64] tile swizzle (reads + stride-4 transposed writes both 2-way)
__device__ __forceinline__ int swze(int r, int c) {
    return (r << 6) + (c ^ (((r ^ (r >> 3)) & 7) << 3));
}

// ---------------------------------------------------------------------------
// mm64 variants: C[a][b] += sum_k A[a][k]*B[b][k]; A,B in swizzled LDS tiles.
// ---------------------------------------------------------------------------
__device__ __forceinline__ void mm64(const u16* __restrict__ Ah, const u16* __restrict__ Al,
                                     const u16* __restrict__ Bh, const u16* __restrict__ Bl,
                                     f32x4* acc, int w, int lane) {
    const int ln = lane & 15, kg = (lane >> 4) * 8;
#pragma unroll
    for (int kb = 0; kb < 2; ++kb) {
        const int k0 = kb * 32 + kg;
        short8 ah = *(const short8*)&Ah[swze(w * 16 + ln, k0)];
        short8 al = *(const short8*)&Al[swze(w * 16 + ln, k0)];
#pragma unroll
        for (int j = 0; j < 4; ++j) {
            short8 bh = *(const short8*)&Bh[swze(j * 16 + ln, k0)];
            short8 bl = *(const short8*)&Bl[swze(j * 16 + ln, k0)];
            acc[j] = __builtin_amdgcn_mfma_f32_16x16x32_bf16(ah, bh, acc[j], 0, 0, 0);
            acc[j] = __builtin_amdgcn_mfma_f32_16x16x32_bf16(ah, bl, acc[j], 0, 0, 0);
            acc[j] = __builtin_amdgcn_mfma_f32_16x16x32_bf16(al, bh, acc[j], 0, 0, 0);
        }
    }
}
// both operands exact bf16
__device__ __forceinline__ void mm64_bb(const u16* __restrict__ Ah,
                                        const u16* __restrict__ Bh,
                                        f32x4* acc, int w, int lane) {
    const int ln = lane & 15, kg = (lane >> 4) * 8;
#pragma unroll
    for (int kb = 0; kb < 2; ++kb) {
        const int k0 = kb * 32 + kg;
        short8 ah = *(const short8*)&Ah[swze(w * 16 + ln, k0)];
#pragma unroll
        for (int j = 0; j < 4; ++j) {
            short8 bh = *(const short8*)&Bh[swze(j * 16 + ln, k0)];
            acc[j] = __builtin_amdgcn_mfma_f32_16x16x32_bf16(ah, bh, acc[j], 0, 0, 0);
        }
    }
}
// A exact bf16, B split
__device__ __forceinline__ void mm64_ab(const u16* __restrict__ Ah,
                                        const u16* __restrict__ Bh, const u16* __restrict__ Bl,
                                        f32x4* acc, int w, int lane) {
    const int ln = lane & 15, kg = (lane >> 4) * 8;
#pragma unroll
    for (int kb = 0; kb < 2; ++kb) {
        const int k0 = kb * 32 + kg;
        short8 ah = *(const short8*)&Ah[swze(w * 16 + ln, k0)];
#pragma unroll
        for (int j = 0; j < 4; ++j) {
            short8 bh = *(const short8*)&Bh[swze(j * 16 + ln, k0)];
            short8 bl = *(const short8*)&Bl[swze(j * 16 + ln, k0)];
            acc[j] = __builtin_amdgcn_mfma_f32_16x16x32_bf16(ah, bh, acc[j], 0, 0, 0);
            acc[j] = __builtin_amdgcn_mfma_f32_16x16x32_bf16(ah, bl, acc[j], 0, 0, 0);
        }
    }
}

// global fp32 [64][64] -> hi/lo bf16 LDS (swizzled)
__device__ __forceinline__ void g_to_ls(const float* __restrict__ G, u16* Ah, u16* Al, int tid) {
#pragma unroll
    for (int p = 0; p < 4; ++p) {
        int flat = p * 1024 + tid * 4;
        int r = flat >> 6, c = flat & 63;
        float4 v = *(const float4*)&G[flat];
        u16 h0, l0, h1, l1, h2, l2, h3, l3;
        split2(v.x, h0, l0); split2(v.y, h1, l1);
        split2(v.z, h2, l2); split2(v.w, h3, l3);
        int idx = swze(r, c);
        uint2 hv, lv;
        hv.x = (unsigned)h0 | ((unsigned)h1 << 16); hv.y = (unsigned)h2 | ((unsigned)h3 << 16);
        lv.x = (unsigned)l0 | ((unsigned)l1 << 16); lv.y = (unsigned)l2 | ((unsigned)l3 << 16);
        *(uint2*)&Ah[idx] = hv;
        *(uint2*)&Al[idx] = lv;
    }
}
// global bf16 [64][64] -> swizzled LDS copy
__device__ __forceinline__ void g_to_ls_b(const u16* __restrict__ G16, u16* Ah, int tid) {
#pragma unroll
    for (int p = 0; p < 2; ++p) {
        int flat = p * 2048 + tid * 8;
        int r = flat >> 6, c = flat & 63;
        *(short8*)&Ah[swze(r, c)] = *(const short8*)&G16[flat];
    }
}

// register frag -> hi/lo bf16 LDS
__device__ __forceinline__ void frag_to_ls(const f32x4* acc, u16* Ah, u16* Al, int w, int lane) {
    const int g = lane >> 4, ln = lane & 15;
#pragma unroll
    for (int j = 0; j < 4; ++j)
#pragma unroll
        for (int r = 0; r < 4; ++r) {
            int row = w * 16 + g * 4 + r, col = j * 16 + ln;
            u16 h, l; split2(acc[j][r], h, l);
            Ah[swze(row, col)] = h;
            Al[swze(row, col)] = l;
        }
}

__device__ __forceinline__ void g_to_frag(const float* __restrict__ G, f32x4* acc, int w, int lane) {
    const int g = lane >> 4, ln = lane & 15;
#pragma unroll
    for (int j = 0; j < 4; ++j)
#pragma unroll
        for (int r = 0; r < 4; ++r)
            acc[j][r] = G[(w * 16 + g * 4 + r) * 64 + j * 16 + ln];
}
__device__ __forceinline__ void g_add_frag(const float* __restrict__ G, f32x4* acc, int w, int lane) {
    const int g = lane >> 4, ln = lane & 15;
#pragma unroll
    for (int j = 0; j < 4; ++j)
#pragma unroll
        for (int r = 0; r < 4; ++r)
            acc[j][r] += G[(w * 16 + g * 4 + r) * 64 + j * 16 + ln];
}
__device__ __forceinline__ void frag_to_g(const f32x4* acc, float* __restrict__ G, int w, int lane) {
    const int g = lane >> 4, ln = lane & 15;
#pragma unroll
    for (int j = 0; j < 4; ++j)
#pragma unroll
        for (int r = 0; r < 4; ++r)
            G[(w * 16 + g * 4 + r) * 64 + j * 16 + ln] = acc[j][r];
}

// ---------------------------------------------------------------------------
// fp32 -> bf16 cast
// ---------------------------------------------------------------------------
__global__ __launch_bounds__(256) void cast_bf16_k(const float* __restrict__ in,
                                                   u16* __restrict__ out) {
    int i = (blockIdx.x * 256 + threadIdx.x) * 8;
    float4 a = *(const float4*)&in[i];
    float4 b = *(const float4*)&in[i + 4];
    uint4 o;
    o.x = (unsigned)f2bf(a.x) | ((unsigned)f2bf(a.y) << 16);
    o.y = (unsigned)f2bf(a.z) | ((unsigned)f2bf(a.w) << 16);
    o.z = (unsigned)f2bf(b.x) | ((unsigned)f2bf(b.y) << 16);
    o.w = (unsigned)f2bf(b.z) | ((unsigned)f2bf(b.w) << 16);
    *(uint4*)&out[i] = o;
}

// ---------------------------------------------------------------------------
// 4x fused: W [K][N] fp32 -> WT [N][K] bf16
// ---------------------------------------------------------------------------
__global__ __launch_bounds__(256) void transW4_k(const float* __restrict__ W0,
                                                 const float* __restrict__ W1,
                                                 const float* __restrict__ W2,
                                                 const float* __restrict__ W3,
                                                 u16* __restrict__ WT0) {
    __shared__ float t[32][33];
    const int which = blockIdx.z;
    const float* W = (which == 0) ? W0 : (which == 1) ? W1 : (which == 2) ? W2 : W3;
    u16* WT = WT0 + (size_t)which * 1048576;
    const int bx = blockIdx.x * 32, by = blockIdx.y * 32;
#pragma unroll
    for (int p = 0; p < 4; ++p) {
        int idx = p * 256 + threadIdx.x;
        int r = idx >> 5, cc = idx & 31;
        t[r][cc] = W[(size_t)(by + r) * 1024 + bx + cc];
    }
    __syncthreads();
#pragma unroll
    for (int p = 0; p < 4; ++p) {
        int idx = p * 256 + threadIdx.x;
        int r = idx >> 5, cc = idx & 31;
        WT[(size_t)(bx + r) * 1024 + by + cc] = f2bf(t[cc][r]);
    }
}

// ---------------------------------------------------------------------------
// GEMM core: 128x128 tile, BK=32, swizzled LDS (pre-swizzled global source)
// ---------------------------------------------------------------------------
__device__ __forceinline__ void gemm_core(const u16* A, const u16* BT,
                                          int m0, int n0, f32x4 acc[4][4]) {
    __shared__ __align__(16) short As[128 * 32];
    __shared__ __align__(16) short Bs[128 * 32];
    const int tid = threadIdx.x;
    const int lane = tid & 63, w = tid >> 6;
    const int wr = w >> 1, wc = w & 1;
    const int ln15 = lane & 15;
    const int erow = tid >> 2;
    // pre-swizzled global chunk: LDS slot (row, chunk) holds global chunk^key(row)
    const int ecol = (((tid & 3) ^ ((erow >> 1) & 3)) << 3);
    const int kch = lane >> 4;   // k-chunk this lane's fragment needs
    for (int k0 = 0; k0 < 1024; k0 += 32) {
#pragma unroll
        for (int r = 0; r < 2; ++r) {
            gld_lds16(A  + (size_t)(m0 + erow + r * 64) * 1024 + k0 + ecol,
                      (short*)As + r * 2048 + tid * 8);
            gld_lds16(BT + (size_t)(n0 + erow + r * 64) * 1024 + k0 + ecol,
                      (short*)Bs + r * 2048 + tid * 8);
        }
        __syncthreads();
        short8 af[4], bf[4];
#pragma unroll
        for (int i = 0; i < 4; ++i) {
            int row = wr * 64 + i * 16 + ln15;
            af[i] = *(const short8*)&As[row * 32 + ((kch ^ ((row >> 1) & 3)) << 3)];
        }
#pragma unroll
        for (int j = 0; j < 4; ++j) {
            int row = wc * 64 + j * 16 + ln15;
            bf[j] = *(const short8*)&Bs[row * 32 + ((kch ^ ((row >> 1) & 3)) << 3)];
        }
#pragma unroll
        for (int i = 0; i < 4; ++i)
#pragma unroll
            for (int j = 0; j < 4; ++j)
                acc[i][j] = __builtin_amdgcn_mfma_f32_16x16x32_bf16(af[i], bf[j], acc[i][j], 0, 0, 0);
        __syncthreads();
    }
}

__global__ __launch_bounds__(256) void gemm_bf16(const u16* __restrict__ A,
                                                 const u16* __restrict__ BT,
                                                 float* __restrict__ C) {
    const int m0 = blockIdx.y * 128, n0 = blockIdx.x * 128;
    f32x4 acc[4][4] = {};
    gemm_core(A, BT, m0, n0, acc);
    const int lane = threadIdx.x & 63, w = threadIdx.x >> 6;
    const int crow0 = m0 + (w >> 1) * 64 + (lane >> 4) * 4;
    const int ccol0 = n0 + (w & 1) * 64 + (lane & 15);
#pragma unroll
    for (int i = 0; i < 4; ++i)
#pragma unroll
        for (int j = 0; j < 4; ++j)
#pragma unroll
            for (int r = 0; r < 4; ++r)
                C[(size_t)(crow0 + i * 16 + r) * 1024 + ccol0 + j * 16] = acc[i][j][r];
}

// q/k written bf16, v written fp32
__global__ __launch_bounds__(256) void gemm_qkv(const u16* __restrict__ A,
                                                const u16* __restrict__ WT0,
                                                u16* __restrict__ xq16,
                                                u16* __restrict__ xk16,
                                                float* __restrict__ xv) {
    const int which = blockIdx.x >> 3;
    const int n0 = (blockIdx.x & 7) * 128;
    const int m0 = blockIdx.y * 128;
    const u16* BT = WT0 + (size_t)which * 1048576;
    f32x4 acc[4][4] = {};
    gemm_core(A, BT, m0, n0, acc);
    const int lane = threadIdx.x & 63, w = threadIdx.x >> 6;
    const int crow0 = m0 + (w >> 1) * 64 + (lane >> 4) * 4;
    const int ccol0 = n0 + (w & 1) * 64 + (lane & 15);
    if (which == 2) {
#pragma unroll
        for (int i = 0; i < 4; ++i)
#pragma unroll
            for (int j = 0; j < 4; ++j)
#pragma unroll
                for (int r = 0; r < 4; ++r)
                    xv[(size_t)(crow0 + i * 16 + r) * 1024 + ccol0 + j * 16] = acc[i][j][r];
    } else {
        u16* C16 = (which == 0) ? xq16 : xk16;
#pragma unroll
        for (int i = 0; i < 4; ++i)
#pragma unroll
            for (int j = 0; j < 4; ++j)
#pragma unroll
                for (int r = 0; r < 4; ++r)
                    C16[(size_t)(crow0 + i * 16 + r) * 1024 + ccol0 + j * 16] = f2bf(acc[i][j][r]);
    }
}

// ---------------------------------------------------------------------------
// beta = sigmoid(x @ Wb) stored [B,H,L]
// ---------------------------------------------------------------------------
__global__ __launch_bounds__(256) void beta_k(const float* __restrict__ X,
                                              const float* __restrict__ Wb,
                                              float* __restrict__ beta) {
    int idx = blockIdx.x * 256 + threadIdx.x;
    int row = idx >> 4, h = idx & 15;
    const float* xr = X + (size_t)row * DD;
    float s = 0.f;
    for (int k4 = 0; k4 < DD; k4 += 4) {
        float4 xv = *(const float4*)&xr[k4];
        s += xv.x * Wb[(k4 + 0) * HH + h];
        s += xv.y * Wb[(k4 + 1) * HH + h];
        s += xv.z * Wb[(k4 + 2) * HH + h];
        s += xv.w * Wb[(k4 + 3) * HH + h];
    }
    float bv = 1.f / (1.f + expf(-s));
    int b = row >> 12, l = row & (LL - 1);
    beta[((size_t)b * HH + h) * LL + l] = bv;
}

// ---------------------------------------------------------------------------
// 3x fused conv: which 0=q(bf16,norm) 1=k(bf16,norm) 2=v(fp32)
// ---------------------------------------------------------------------------
__global__ __launch_bounds__(256) void conv3_k(const u16* __restrict__ xq16,
                                               const u16* __restrict__ xk16,
                                               const float* __restrict__ xv,
                                               const float* __restrict__ cwq,
                                               const float* __restrict__ cwk,
                                               const float* __restrict__ cwv,
                                               u16* __restrict__ q16,
                                               u16* __restrict__ k16,
                                               float* __restrict__ vout) {
    const int which = blockIdx.z;
    const float* cw = (which == 0) ? cwq : (which == 1) ? cwk : cwv;
    const int l0 = blockIdx.x * 16, b = blockIdx.y;
    const int tid = threadIdx.x;
    const int d0 = tid * 4;
    const float4 w0 = *(const float4*)&cw[(d0 + 0) * 4];
    const float4 w1 = *(const float4*)&cw[(d0 + 1) * 4];
    const float4 w2 = *(const float4*)&cw[(d0 + 2) * 4];
    const float4 w3 = *(const float4*)&cw[(d0 + 3) * 4];
    const int h = d0 >> 6, hd = d0 & 63;
    if (which < 2) {
        const u16* Xb = ((which == 0) ? xq16 : xk16) + (size_t)b * LL * DD;
        u16* O16 = (which == 0) ? q16 : k16;
        float4 xm3 = make_float4(0, 0, 0, 0), xm2 = xm3, xm1 = xm3;
        if (l0 > 0) {
            xm3 = ld_bf4(&Xb[(size_t)(l0 - 3) * DD + d0]);
            xm2 = ld_bf4(&Xb[(size_t)(l0 - 2) * DD + d0]);
            xm1 = ld_bf4(&Xb[(size_t)(l0 - 1) * DD + d0]);
        }
#pragma unroll
        for (int t = 0; t < 16; ++t) {
            const int l = l0 + t;
            float4 xc = ld_bf4(&Xb[(size_t)l * DD + d0]);
            float a0 = xm3.x * w0.x + xm2.x * w0.y + xm1.x * w0.z + xc.x * w0.w;
            float a1 = xm3.y * w1.x + xm2.y * w1.y + xm1.y * w1.z + xc.y * w1.w;
            float a2 = xm3.z * w2.x + xm2.z * w2.y + xm1.z * w2.z + xc.z * w2.w;
            float a3 = xm3.w * w3.x + xm2.w * w3.y + xm1.w * w3.z + xc.w * w3.w;
            a0 = a0 / (1.f + expf(-a0));
            a1 = a1 / (1.f + expf(-a1));
            a2 = a2 / (1.f + expf(-a2));
            a3 = a3 / (1.f + expf(-a3));
            float s = a0 * a0 + a1 * a1 + a2 * a2 + a3 * a3;
            s += __shfl_xor(s, 1);
            s += __shfl_xor(s, 2);
            s += __shfl_xor(s, 4);
            s += __shfl_xor(s, 8);
            float sc = rsqrtf(s);
            a0 *= sc; a1 *= sc; a2 *= sc; a3 *= sc;
            uint2 o;
            o.x = (unsigned)f2bf(a0) | ((unsigned)f2bf(a1) << 16);
            o.y = (unsigned)f2bf(a2) | ((unsigned)f2bf(a3) << 16);
            *(uint2*)&O16[(((size_t)b * HH + h) * LL + l) * 64 + hd] = o;
            xm3 = xm2; xm2 = xm1; xm1 = xc;
        }
    } else {
        const float* Xb = xv + (size_t)b * LL * DD;
        float4 xm3 = make_float4(0, 0, 0, 0), xm2 = xm3, xm1 = xm3;
        if (l0 > 0) {
            xm3 = *(const float4*)&Xb[(size_t)(l0 - 3) * DD + d0];
            xm2 = *(const float4*)&Xb[(size_t)(l0 - 2) * DD + d0];
            xm1 = *(const float4*)&Xb[(size_t)(l0 - 1) * DD + d0];
        }
#pragma unroll
        for (int t = 0; t < 16; ++t) {
            const int l = l0 + t;
            float4 xc = *(const float4*)&Xb[(size_t)l * DD + d0];
            float a0 = xm3.x * w0.x + xm2.x * w0.y + xm1.x * w0.z + xc.x * w0.w;
            float a1 = xm3.y * w1.x + xm2.y * w1.y + xm1.y * w1.z + xc.y * w1.w;
            float a2 = xm3.z * w2.x + xm2.z * w2.y + xm1.z * w2.z + xc.z * w2.w;
            float a3 = xm3.w * w3.x + xm2.w * w3.y + xm1.w * w3.z + xc.w * w3.w;
            a0 = a0 / (1.f + expf(-a0));
            a1 = a1 / (1.f + expf(-a1));
            a2 = a2 / (1.f + expf(-a2));
            a3 = a3 / (1.f + expf(-a3));
            *(float4*)&vout[(((size_t)b * HH + h) * LL + l) * 64 + hd] =
                make_float4(a0, a1, a2, a3);
            xm3 = xm2; xm2 = xm1; xm1 = xc;
        }
    }
}

// ---------------------------------------------------------------------------
// Phase A v5: K is exact bf16. Gram 1-term, P/B 2-term MFMA. VALU solve.
// ---------------------------------------------------------------------------
__global__ __launch_bounds__(256) void phaseA5(const u16* __restrict__ kg16,
                                               const float* __restrict__ vg,
                                               const float* __restrict__ betag,
                                               float* __restrict__ Wg,
                                               float* __restrict__ UgT,
                                               float* __restrict__ Pall,
                                               float* __restrict__ BallT) {
    __shared__ __align__(16) char pool[73728];
    u16* Kh   = (u16*)pool;              // 8K; later WTh
    u16* KTh  = (u16*)(pool + 8192);     // 8K (persists)
    float* At = (float*)(pool + 16384);  // 16K; later WTl/UTh
    float* WU = (float*)(pool + 32768);  // 32K; later scr
    u16* WTh  = (u16*)pool;
    u16* WTl  = (u16*)(pool + 16384);
    u16* UTh  = (u16*)(pool + 24576);
    u16* UTl  = (u16*)(pool + 65536);    // 8K fresh
    float* scr = (float*)(pool + 32768);

    const int c = blockIdx.x, bh = blockIdx.y;
    const int tid = threadIdx.x, lane = tid & 63, w = tid >> 6;
    const int g = lane >> 4, ln = lane & 15;
    const int t0 = (tid >> 4) * 4, d4 = (tid & 15) * 4;
    const size_t base = ((size_t)bh * LL + (size_t)c * 64) * 64;
    const size_t obase = ((size_t)bh * NC + c) * 4096;
    const float* bet = betag + (size_t)bh * LL + (size_t)c * 64;

    // 1a. K (bf16) -> Kh swizzled
    g_to_ls_b(kg16 + base, Kh, tid);
    // 1b. K^T -> KTh (global re-read 4x4, packed transposed stores)
    {
        u16 kv[4][4];
#pragma unroll
        for (int i = 0; i < 4; ++i) {
            uint2 v = *(const uint2*)&kg16[base + (size_t)(t0 + i) * 64 + d4];
            kv[i][0] = (u16)v.x; kv[i][1] = (u16)(v.x >> 16);
            kv[i][2] = (u16)v.y; kv[i][3] = (u16)(v.y >> 16);
        }
#pragma unroll
        for (int j = 0; j < 4; ++j) {
            uint2 hv;
            hv.x = (unsigned)kv[0][j] | ((unsigned)kv[1][j] << 16);
            hv.y = (unsigned)kv[2][j] | ((unsigned)kv[3][j] << 16);
            *(uint2*)&KTh[swze(d4 + j, t0)] = hv;
        }
    }
    __syncthreads();
    // 2. Gram A = strict_tril(beta * K K^T)  (exact bf16 operands)
    {
        f32x4 acc[4] = {};
        mm64_bb(Kh, Kh, acc, w, lane);
#pragma unroll
        for (int r = 0; r < 4; ++r) {
            int t = w * 16 + g * 4 + r;
            float bt = bet[t];
#pragma unroll
            for (int j = 0; j < 4; ++j) {
                int s = j * 16 + ln;
                At[t * 64 + s] = (s < t) ? bt * acc[j][r] : 0.f;
            }
        }
    }
    // 3. RHS: WU[t][j] = beta_t * (j<64 ? K[t][j] : V[t][j-64])
#pragma unroll
    for (int p = 0; p < 8; ++p) {
        int flat = p * 1024 + tid * 4;
        int t = flat >> 7, j = flat & 127;
        float bt = bet[t];
        float4 src;
        if (j < 64) src = ld_bf4(&Kh[swze(t, j)]);
        else        src = *(const float4*)&vg[base + (size_t)t * 64 + (j - 64)];
        src.x *= bt; src.y *= bt; src.z *= bt; src.w *= bt;
        *(float4*)&WU[t * 128 + j] = src;
    }
    __syncthreads();
    // 4. blocked forward substitution (panels of 16)
#pragma unroll
    for (int pb = 0; pb < 4; ++pb) {
        const int r0 = pb * 16;
        if (pb > 0) {
            const int col = tid & 127;
            const int rbase = r0 + (tid >> 7) * 8;
            float acc8[8] = {};
            for (int r = 0; r < r0; r += 4) {
                float u0 = WU[(r + 0) * 128 + col], u1 = WU[(r + 1) * 128 + col];
                float u2 = WU[(r + 2) * 128 + col], u3 = WU[(r + 3) * 128 + col];
#pragma unroll
                for (int i = 0; i < 8; ++i) {
                    float4 a4 = *(const float4*)&At[(rbase + i) * 64 + r];
                    acc8[i] += a4.x * u0 + a4.y * u1 + a4.z * u2 + a4.w * u3;
                }
            }
#pragma unroll
            for (int i = 0; i < 8; ++i) WU[(rbase + i) * 128 + col] -= acc8[i];
            __syncthreads();
        }
        if (tid < 128) {
            const int col = tid;
            float wv[16];
            wv[0] = WU[r0 * 128 + col];
#pragma unroll
            for (int t = 1; t < 16; ++t) {
                float a = WU[(r0 + t) * 128 + col];
#pragma unroll
                for (int r = 0; r < t; ++r) a -= At[(r0 + t) * 64 + r0 + r] * wv[r];
                wv[t] = a;
            }
#pragma unroll
            for (int t = 1; t < 16; ++t) WU[(r0 + t) * 128 + col] = wv[t];
        }
        __syncthreads();
    }
    // 5a. Wg global write
#pragma unroll
    for (int p = 0; p < 4; ++p) {
        int flat = p * 1024 + tid * 4;
        int t = flat >> 6, j = flat & 63;
        *(float4*)&Wg[obase + flat] = *(const float4*)&WU[t * 128 + j];
    }
    // 5b. W^T (split) and U^T (split) builds (vectorized reads + packed stores)
    {
        u16 h4[4][4], l4[4][4];
#pragma unroll
        for (int i = 0; i < 4; ++i) {
            float4 v = *(const float4*)&WU[(t0 + i) * 128 + d4];
            split2(v.x, h4[i][0], l4[i][0]); split2(v.y, h4[i][1], l4[i][1]);
            split2(v.z, h4[i][2], l4[i][2]); split2(v.w, h4[i][3], l4[i][3]);
        }
#pragma unroll
        for (int j = 0; j < 4; ++j) {
            uint2 hv, lv;
            hv.x = (unsigned)h4[0][j] | ((unsigned)h4[1][j] << 16);
            hv.y = (unsigned)h4[2][j] | ((unsigned)h4[3][j] << 16);
            lv.x = (unsigned)l4[0][j] | ((unsigned)l4[1][j] << 16);
            lv.y = (unsigned)l4[2][j] | ((unsigned)l4[3][j] << 16);
            *(uint2*)&WTh[swze(d4 + j, t0)] = hv;
            *(uint2*)&WTl[swze(d4 + j, t0)] = lv;
        }
#pragma unroll
        for (int i = 0; i < 4; ++i) {
            float4 v = *(const float4*)&WU[(t0 + i) * 128 + 64 + d4];
            split2(v.x, h4[i][0], l4[i][0]); split2(v.y, h4[i][1], l4[i][1]);
            split2(v.z, h4[i][2], l4[i][2]); split2(v.w, h4[i][3], l4[i][3]);
        }
#pragma unroll
        for (int j = 0; j < 4; ++j) {
            uint2 hv, lv;
            hv.x = (unsigned)h4[0][j] | ((unsigned)h4[1][j] << 16);
            hv.y = (unsigned)h4[2][j] | ((unsigned)h4[3][j] << 16);
            lv.x = (unsigned)l4[0][j] | ((unsigned)l4[1][j] << 16);
            lv.y = (unsigned)l4[2][j] | ((unsigned)l4[3][j] << 16);
            *(uint2*)&UTh[swze(d4 + j, t0)] = hv;
            *(uint2*)&UTl[swze(d4 + j, t0)] = lv;
        }
    }
    __syncthreads();
    // 6. UgT global write (reconstructed)
#pragma unroll
    for (int p = 0; p < 4; ++p) {
        int flat = p * 1024 + tid * 4;
        int n = flat >> 6, tt = flat & 63;
        int idx = swze(n, tt);
        uint2 hh = *(const uint2*)&UTh[idx];
        uint2 ll2 = *(const uint2*)&UTl[idx];
        float4 o;
        o.x = bf2f((u16)hh.x) + bf2f((u16)ll2.x);
        o.y = bf2f((u16)(hh.x >> 16)) + bf2f((u16)(ll2.x >> 16));
        o.z = bf2f((u16)hh.y) + bf2f((u16)ll2.y);
        o.w = bf2f((u16)(hh.y >> 16)) + bf2f((u16)(ll2.y >> 16));
        *(float4*)&UgT[obase + flat] = o;
    }
    // 7. P = I - K^T W ; B = K^T U
    f32x4 aP[4] = {}, aB[4] = {};
    mm64_ab(KTh, WTh, WTl, aP, w, lane);
    mm64_ab(KTh, UTh, UTl, aB, w, lane);
#pragma unroll
    for (int j = 0; j < 4; ++j)
#pragma unroll
        for (int r = 0; r < 4; ++r) {
            int row = w * 16 + g * 4 + r, col = j * 16 + ln;
            float pv = ((row == col) ? 1.f : 0.f) - aP[j][r];
            Pall[obase + (size_t)row * 64 + col] = pv;
            scr[swz(row, col)] = aB[j][r];
        }
    __syncthreads();
    // 8. BallT (coalesced via swizzled transpose)
#pragma unroll
    for (int p = 0; p < 4; ++p) {
        int flat = p * 1024 + tid * 4;
        int n = flat >> 6, dd = flat & 63;
        float4 o;
        o.x = scr[swz(dd + 0, n)];
        o.y = scr[swz(dd + 1, n)];
        o.z = scr[swz(dd + 2, n)];
        o.w = scr[swz(dd + 3, n)];
        *(float4*)&BallT[obase + flat] = o;
    }
}

// ---------------------------------------------------------------------------
// compose3 (split MFMA): per group of 8 chunks.
// ---------------------------------------------------------------------------
__global__ __launch_bounds__(256) void compose3(const float* __restrict__ Pall,
                                                const float* __restrict__ BallT,
                                                float* __restrict__ Pg,
                                                float* __restrict__ BgT) {
    __shared__ __align__(16) char pool[81920];
    u16* Ph = (u16*)pool;
    u16* Pl = (u16*)(pool + 8192);
    u16* Bh = (u16*)(pool + 16384);
    u16* Bl = (u16*)(pool + 24576);
    u16* nh = (u16*)(pool + 32768);
    u16* nl = (u16*)(pool + 40960);
    float* scr = (float*)(pool + 49152);
    const int g = blockIdx.x, bh = blockIdx.y;
    const int tid = threadIdx.x, lane = tid & 63, w = tid >> 6;
    const int gi = lane >> 4, ln = lane & 15;
    const size_t base0 = ((size_t)bh * NC + (size_t)g * GS) * 4096;
    f32x4 mP[4], mB[4];
#pragma unroll
    for (int p = 0; p < 4; ++p) {
        int flat = p * 1024 + tid * 4;
        int r = flat >> 6, c4 = flat & 63;
        *(float4*)&scr[swz(r, c4)] = *(const float4*)&Pall[base0 + flat];
    }
    g_to_frag(BallT + base0, mB, w, lane);
    __syncthreads();
#pragma unroll
    for (int j = 0; j < 4; ++j)
#pragma unroll
        for (int r = 0; r < 4; ++r) {
            int row = w * 16 + gi * 4 + r, col = j * 16 + ln;
            mP[j][r] = scr[swz(col, row)];
        }
    for (int s = 1; s < GS; ++s) {
        __syncthreads();
        frag_to_ls(mP, Ph, Pl, w, lane);
        frag_to_ls(mB, Bh, Bl, w, lane);
        g_to_ls(&Pall[base0 + (size_t)s * 4096], nh, nl, tid);
        __syncthreads();
        f32x4 aP[4] = {}, aB[4] = {};
        mm64(Ph, Pl, nh, nl, aP, w, lane);
        mm64(Bh, Bl, nh, nl, aB, w, lane);
        g_add_frag(&BallT[base0 + (size_t)s * 4096], aB, w, lane);
#pragma unroll
        for (int j = 0; j < 4; ++j) { mP[j] = aP[j]; mB[j] = aB[j]; }
    }
    const size_t gbase = ((size_t)bh * GG + g) * 4096;
    frag_to_g(mB, BgT + gbase, w, lane);
    __syncthreads();
#pragma unroll
    for (int j = 0; j < 4; ++j)
#pragma unroll
        for (int r = 0; r < 4; ++r) {
            int row = w * 16 + gi * 4 + r, col = j * 16 + ln;
            scr[swz(row, col)] = mP[j][r];
        }
    __syncthreads();
#pragma unroll
    for (int p = 0; p < 4; ++p) {
        int flat = p * 1024 + tid * 4;
        int a = flat >> 6, b0 = flat & 63;
        float4 o;
        o.x = scr[swz(b0 + 0, a)];
        o.y = scr[swz(b0 + 1, a)];
        o.z = scr[swz(b0 + 2, a)];
        o.w = scr[swz(b0 + 3, a)];
        *(float4*)&Pg[gbase + flat] = o;
    }
}

// ---------------------------------------------------------------------------
// scanG3: sequential over 8 groups; writes group-entry states SallT.
// ---------------------------------------------------------------------------
__global__ __launch_bounds__(256) void scanG3(const float* __restrict__ Pg,
                                              const float* __restrict__ BgT,
                                              float* __restrict__ SallT) {
    __shared__ __align__(16) char pool[32768];
    u16* Sh = (u16*)pool;
    u16* Sl = (u16*)(pool + 8192);
    u16* nh = (u16*)(pool + 16384);
    u16* nl = (u16*)(pool + 24576);
    const int bh = blockIdx.x;
    const int tid = threadIdx.x, lane = tid & 63, w = tid >> 6;
    f32x4 mS[4] = {};
    for (int g = 0; g < GG; ++g) {
        const size_t sbase = ((size_t)bh * NC + (size_t)g * GS) * 4096;
        frag_to_g(mS, SallT + sbase, w, lane);
        if (g == GG - 1) break;
        __syncthreads();
        frag_to_ls(mS, Sh, Sl, w, lane);
        g_to_ls(&Pg[((size_t)bh * GG + g) * 4096], nh, nl, tid);
        __syncthreads();
        f32x4 a[4] = {};
        mm64(Sh, Sl, nh, nl, a, w, lane);
        g_add_frag(&BgT[((size_t)bh * GG + g) * 4096], a, w, lane);
#pragma unroll
        for (int j = 0; j < 4; ++j) mS[j] = a[j];
    }
}

// ---------------------------------------------------------------------------
// rollout3: fill chunk-entry states within each group (SallT).
// ---------------------------------------------------------------------------
__global__ __launch_bounds__(256) void rollout3(const float* __restrict__ Pall,
                                                const float* __restrict__ BallT,
                                                float* __restrict__ SallT) {
    __shared__ __align__(16) char pool[32768];
    u16* Sh = (u16*)pool;
    u16* Sl = (u16*)(pool + 8192);
    u16* nh = (u16*)(pool + 16384);
    u16* nl = (u16*)(pool + 24576);
    const int g = blockIdx.x, bh = blockIdx.y;
    const int tid = threadIdx.x, lane = tid & 63, w = tid >> 6;
    const size_t base0 = ((size_t)bh * NC + (size_t)g * GS) * 4096;
    f32x4 mS[4];
    g_to_frag(SallT + base0, mS, w, lane);
    for (int j = 1; j < GS; ++j) {
        __syncthreads();
        frag_to_ls(mS, Sh, Sl, w, lane);
        g_to_ls(&Pall[base0 + (size_t)(j - 1) * 4096], nh, nl, tid);
        __syncthreads();
        f32x4 a[4] = {};
        mm64(Sh, Sl, nh, nl, a, w, lane);
        g_add_frag(&BallT[base0 + (size_t)(j - 1) * 4096], a, w, lane);
#pragma unroll
        for (int jj = 0; jj < 4; ++jj) mS[jj] = a[jj];
        frag_to_g(mS, SallT + base0 + (size_t)j * 4096, w, lane);
    }
}

// ---------------------------------------------------------------------------
// phaseO4: Q,K exact bf16. M = causal(QK^T) 1-term; (WS)^T 3-term;
// QS 2-term; M*Delta 3-term; fused RMSNorm + bf16 cast.
// ---------------------------------------------------------------------------
__global__ __launch_bounds__(256) void phaseO4(const float* __restrict__ Wg,
                                               const float* __restrict__ UgT,
                                               const u16* __restrict__ qg16,
                                               const u16* __restrict__ kg16,
                                               const float* __restrict__ SallT,
                                               const float* __restrict__ nw,
                                               u16* __restrict__ ob) {
    __shared__ __align__(16) char pool[57344];
    u16* Qh = (u16*)pool;               // 8K
    u16* Kh = (u16*)(pool + 8192);      // 8K; later Dh
    u16* Wh = (u16*)(pool + 16384);     // 8K; later Mh
    u16* Wl = (u16*)(pool + 24576);     // 8K; later Ml
    u16* Sh = (u16*)(pool + 32768);
    u16* Sl = (u16*)(pool + 40960);
    u16* Dl = (u16*)(pool + 49152);     // 8K fresh
    u16* Dh = Kh;
    u16* Mh = Wh; u16* Ml = Wl;
    const int c = blockIdx.x, bh = blockIdx.y;
    const int b = bh >> 4, h = bh & 15;
    const int tid = threadIdx.x, lane = tid & 63, w = tid >> 6;
    const int gi = lane >> 4, ln = lane & 15;
    const size_t tbase = ((size_t)bh * NC + c) * 4096;
    const size_t qkbase = ((size_t)bh * LL + (size_t)c * 64) * 64;
    g_to_ls_b(qg16 + qkbase, Qh, tid);
    g_to_ls_b(kg16 + qkbase, Kh, tid);
    g_to_ls(&Wg[tbase], Wh, Wl, tid);
    g_to_ls(&SallT[tbase], Sh, Sl, tid);
    __syncthreads();
    f32x4 aM[4] = {}, aD[4] = {};
    mm64_bb(Qh, Kh, aM, w, lane);        // Q K^T
    mm64(Sh, Sl, Wh, Wl, aD, w, lane);   // (W S)^T
    __syncthreads();                     // all K/W reads done
#pragma unroll
    for (int j = 0; j < 4; ++j)
#pragma unroll
        for (int r = 0; r < 4; ++r) {
            int row = w * 16 + gi * 4 + r, col = j * 16 + ln;
            float mv = (col <= row) ? aM[j][r] : 0.f;
            u16 mh_, ml_; split2(mv, mh_, ml_);
            Mh[swze(row, col)] = mh_;
            Ml[swze(row, col)] = ml_;
            float dv = UgT[tbase + (size_t)row * 64 + col] - aD[j][r];
            u16 dh_, dl_; split2(dv, dh_, dl_);
            Dh[swze(row, col)] = dh_;
            Dl[swze(row, col)] = dl_;
        }
    __syncthreads();
    f32x4 aO[4] = {};
    mm64_ab(Qh, Sh, Sl, aO, w, lane);    // Q S
    mm64(Mh, Ml, Dh, Dl, aO, w, lane);   // + M Delta
    float nwv[4];
#pragma unroll
    for (int j = 0; j < 4; ++j) nwv[j] = nw[j * 16 + ln];
#pragma unroll
    for (int r = 0; r < 4; ++r) {
        float ss = 0.f;
#pragma unroll
        for (int j = 0; j < 4; ++j) ss += aO[j][r] * aO[j][r];
        ss += __shfl_xor(ss, 1);
        ss += __shfl_xor(ss, 2);
        ss += __shfl_xor(ss, 4);
        ss += __shfl_xor(ss, 8);
        float rms = rsqrtf(ss * (1.f / 64.f) + 1e-5f);
        int row = w * 16 + gi * 4 + r;
        size_t orow = ((size_t)b * LL + (size_t)c * 64 + row) * DD + (size_t)h * 64;
#pragma unroll
        for (int j = 0; j < 4; ++j)
            ob[orow + j * 16 + ln] = f2bf(aO[j][r] * rms * nwv[j]);
    }
}

// ---------------------------------------------------------------------------
extern "C" void kernel_launch(void* const* d_in, const int* in_sizes, int n_in,
                              void* d_out, int out_size, void* d_ws, size_t ws_size,
                              hipStream_t stream) {
    const float* x  = (const float*)d_in[0];
    const float* Wq = (const float*)d_in[1];
    const float* Wk = (const float*)d_in[2];
    const float* Wv = (const float*)d_in[3];
    const float* Wb = (const float*)d_in[4];
    const float* cq = (const float*)d_in[5];
    const float* ck = (const float*)d_in[6];
    const float* cv = (const float*)d_in[7];
    const float* nw = (const float*)d_in[8];
    const float* Wo = (const float*)d_in[9];
    float* out = (float*)d_out;
    float* ws = (float*)d_ws;

    const size_t SZ = (size_t)BB * LL * DD;   // 8388608
    float* xv    = ws;              // gemm v out -> Pall after conv
    float* v     = ws + SZ;         // conv v out -> ob after phaseA5
    float* Wg    = ws + 2 * SZ;
    float* UgT   = ws + 3 * SZ;
    float* SallT = ws + 4 * SZ;
    u16* xb   = (u16*)(ws + 5 * SZ);          // x bf16; dead after gemm_qkv
    u16* q16  = xb;                           // conv q out (reuses xb)
    u16* xq16 = (u16*)(ws + 5 * SZ) + SZ;
    u16* xk16 = (u16*)(ws + 5 * SZ) + 2 * SZ;
    u16* k16  = (u16*)(ws + 5 * SZ) + 3 * SZ;
    float* beta = ws + 7 * SZ;                        // 131072 floats
    u16* wqT  = (u16*)(beta + (size_t)BH * LL);       // 4M u16 (q,k,v,o)
    float* PgB = (float*)(wqT + (size_t)4 * 1048576); // 1M floats
    float* BgT = PgB + 1048576;                       // 1M floats

    float* Pall  = xv;
    float* BallT = out;   // d_out as scratch; fully overwritten by final GEMM
    u16* ob   = (u16*)v;
    u16* woT  = wqT + (size_t)3 * 1048576;

    dim3 blk(256);

    cast_bf16_k<<<dim3(4096), blk, 0, stream>>>(x, xb);
    transW4_k<<<dim3(32, 32, 4), blk, 0, stream>>>(Wq, Wk, Wv, Wo, wqT);
    gemm_qkv<<<dim3(24, 64), blk, 0, stream>>>(xb, wqT, xq16, xk16, xv);
    beta_k<<<dim3(512), blk, 0, stream>>>(x, Wb, beta);
    conv3_k<<<dim3(LL / 16, BB, 3), blk, 0, stream>>>(xq16, xk16, xv, cq, ck, cv, q16, k16, v);
    phaseA5<<<dim3(NC, BH), blk, 0, stream>>>(k16, v, beta, Wg, UgT, Pall, BallT);
    compose3<<<dim3(GG, BH), blk, 0, stream>>>(Pall, BallT, PgB, BgT);
    scanG3<<<dim3(BH), blk, 0, stream>>>(PgB, BgT, SallT);
    rollout3<<<dim3(GG, BH), blk, 0, stream>>>(Pall, BallT, SallT);
    phaseO4<<<dim3(NC, BH), blk, 0, stream>>>(Wg, UgT, q16, k16, SallT, nw, ob);
    gemm_bf16<<<dim3(8, 64), blk, 0, stream>>>(ob, woT, out);
}